// Round 15
// baseline (857.406 us; speedup 1.0000x reference)
//
#include <hip/hip_runtime.h>
#include <math.h>

#define BN 8
#define HW 4096
#define NH 128
#define SNC 35
#define SD 512

typedef __attribute__((ext_vector_type(8))) short short8v;
typedef __attribute__((ext_vector_type(4))) short short4v;
typedef __attribute__((ext_vector_type(4))) float float4v;
typedef __attribute__((ext_vector_type(4))) unsigned int uint4v;

__device__ __forceinline__ short f2bf(float f) {
  unsigned u = __float_as_uint(f);
  unsigned r = (u + 0x7fffu + ((u >> 16) & 1u)) >> 16;
  return (short)r;
}
__device__ __forceinline__ float bf2f(short h) {
  return __uint_as_float(((unsigned)(unsigned short)h) << 16);
}

// ---------------- per-(b,c) instance-norm stats ----------------
__global__ __launch_bounds__(256) void stats_kernel(const float* __restrict__ x,
                                                    float* __restrict__ mu,
                                                    float* __restrict__ rstd) {
  int row = blockIdx.x;
  const float* p = x + (size_t)row * HW;
  float s = 0.f, s2 = 0.f;
  for (int i = threadIdx.x; i < HW; i += 256) {
    float v = p[i];
    s += v; s2 += v * v;
  }
  #pragma unroll
  for (int off = 32; off > 0; off >>= 1) {
    s  += __shfl_down(s, off);
    s2 += __shfl_down(s2, off);
  }
  __shared__ float as[4], as2[4];
  int wid = threadIdx.x >> 6;
  if ((threadIdx.x & 63) == 0) { as[wid] = s; as2[wid] = s2; }
  __syncthreads();
  if (threadIdx.x == 0) {
    float t  = as[0] + as[1] + as[2] + as[3];
    float t2 = as2[0] + as2[1] + as2[2] + as2[3];
    float m = t * (1.f / HW);
    float var = t2 * (1.f / HW) - m * m;
    mu[row] = m;
    rstd[row] = rsqrtf(var + 1e-5f);
  }
}

// ---------------- merged style modulation (3 segments) ----------------
__global__ __launch_bounds__(256) void modscale_all_kernel(
    const float* __restrict__ style,
    const float* __restrict__ m0w, const float* __restrict__ m0b,
    const float* __restrict__ m1w, const float* __restrict__ m1b,
    const float* __restrict__ msw, const float* __restrict__ msb,
    float* __restrict__ s0, float* __restrict__ s1, float* __restrict__ ss) {
  int idx = blockIdx.x * 256 + threadIdx.x;
  const float *mw, *mb; float* o; int I;
  if (idx < 4096) { mw = m0w; mb = m0b; o = s0; I = 512; }
  else if (idx < 6144) { idx -= 4096; mw = m1w; mb = m1b; o = s1; I = 256; }
  else if (idx < 10240) { idx -= 6144; mw = msw; mb = msb; o = ss; I = 512; }
  else return;
  int b = idx / I, i = idx - b * I;
  const float* st = style + (size_t)b * SD;
  const float* w  = mw + (size_t)i * SD;
  float acc = 0.f;
  for (int d = 0; d < SD; ++d) acc += st[d] * w[d];
  o[idx] = acc * 0.044194173824159216f + mb[i];
}

// ---------------- merged sum of w^2 (3 segments) ----------------
__global__ __launch_bounds__(256) void wsq_all_kernel(
    const float* __restrict__ w0, const float* __restrict__ w1,
    const float* __restrict__ wss,
    float* __restrict__ wsq0, float* __restrict__ wsq1, float* __restrict__ wsqs) {
  int idx = blockIdx.x * 256 + threadIdx.x;
  const float* w; float* o; int KK;
  if (idx < 131072) { w = w0; o = wsq0; KK = 9; }
  else if (idx < 196608) { idx -= 131072; w = w1; o = wsq1; KK = 9; }
  else if (idx < 327680) { idx -= 196608; w = wss; o = wsqs; KK = 1; }
  else return;
  const float* p = w + (size_t)idx * KK;
  float a = 0.f;
  for (int t = 0; t < KK; ++t) a += p[t] * p[t];
  o[idx] = a;
}

// ---------------- merged demod (3 segments) ----------------
__global__ __launch_bounds__(256) void demod_all_kernel(
    const float* __restrict__ wsq0, const float* __restrict__ s0, float* __restrict__ d0,
    const float* __restrict__ wsq1, const float* __restrict__ s1, float* __restrict__ d1,
    const float* __restrict__ wsqs, const float* __restrict__ ss, float* __restrict__ dss,
    float cs0, float cs1, float css) {
  int idx = blockIdx.x * 256 + threadIdx.x;
  const float *wsq, *s; float* dsc; int I; float cs;
  if (idx < 2048) { wsq = wsq0; s = s0; dsc = d0; I = 512; cs = cs0; }
  else if (idx < 4096) { idx -= 2048; wsq = wsq1; s = s1; dsc = d1; I = 256; cs = cs1; }
  else if (idx < 6144) { idx -= 4096; wsq = wsqs; s = ss; dsc = dss; I = 512; cs = css; }
  else return;
  int b = idx >> 8, o = idx & 255;
  const float* wr = wsq + (size_t)o * I;
  const float* sr = s + (size_t)b * I;
  float a = 0.f;
  for (int i = 0; i < I; ++i) { float sv = sr[i]; a += wr[i] * sv * sv; }
  dsc[idx] = rsqrtf(cs * cs * a + 1e-8f) * cs;
}

// ---------------- weight pack helper ----------------
__device__ __forceinline__ void pack_one(int tid, const float* __restrict__ wg,
                                         const float* __restrict__ wb,
                                         short* __restrict__ ph, short* __restrict__ pl,
                                         int OCtot, int IC, int KK, int interleave) {
  int ICC = IC / 32;
  int OCT16 = OCtot / 16;
  int lane = tid & 63;
  int r = tid >> 6;
  int icC = r % ICC; r /= ICC;
  int ocT = r % OCT16; int tap = r / OCT16;
  int po = ocT * 16 + (lane & 15);
  int ic0 = icC * 32 + (lane >> 4) * 8;
  const float* srcw;
  int oc;
  if (interleave) { oc = po >> 1; srcw = (po & 1) ? wb : wg; }
  else { oc = po; srcw = wg; }
  short8v hv, lv;
  #pragma unroll
  for (int j = 0; j < 8; ++j) {
    float v = srcw[((size_t)oc * IC + ic0 + j) * KK + tap];
    short h = f2bf(v);
    hv[j] = h;
    lv[j] = f2bf(v - bf2f(h));
  }
  size_t o = (size_t)tid * 8;
  *(short8v*)(ph + o) = hv;
  if (pl) *(short8v*)(pl + o) = lv;
}

// ---------------- merged weight packing: 6 segments ----------------
__global__ __launch_bounds__(256) void pack_w_all_kernel(
    const float* w0, const float* w1, const float* wss,
    const float* ns_gw, const float* ns_bw,
    const float* n0_gw, const float* n0_bw,
    const float* n1_gw, const float* n1_bw,
    short* p0h, short* p0l, short* p1h, short* p1l, short* psh, short* psl,
    short* pgsh, short* pg0h, short* pg1h) {
  int tid = blockIdx.x * 256 + threadIdx.x;
  if (tid < 147456) { pack_one(tid, w0, nullptr, p0h, p0l, 256, 512, 9, 0); return; }
  tid -= 147456;
  if (tid < 73728) { pack_one(tid, w1, nullptr, p1h, p1l, 256, 256, 9, 0); return; }
  tid -= 73728;
  if (tid < 16384) { pack_one(tid, wss, nullptr, psh, psl, 256, 512, 1, 0); return; }
  tid -= 16384;
  if (tid < 147456) { pack_one(tid, ns_gw, ns_bw, pgsh, nullptr, 1024, 128, 9, 1); return; }
  tid -= 147456;
  if (tid < 147456) { pack_one(tid, n0_gw, n0_bw, pg0h, nullptr, 1024, 128, 9, 1); return; }
  tid -= 147456;
  if (tid < 73728) pack_one(tid, n1_gw, n1_bw, pg1h, nullptr, 512, 128, 9, 1);
}

// ---------------- pack the 3 seg-conv weight sets: OCtot=384, IC 35 padded to 64 ----------------
__global__ __launch_bounds__(256) void pack_sw_kernel(const float* __restrict__ sw0,
                                                      const float* __restrict__ sw1,
                                                      const float* __restrict__ sw2,
                                                      short* __restrict__ ph,
                                                      short* __restrict__ pl) {
  int tid = blockIdx.x * 256 + threadIdx.x;
  const int ICC = 2, OCT16 = 24;
  int total = 9 * OCT16 * ICC * 64;
  if (tid >= total) return;
  int lane = tid & 63;
  int r = tid >> 6;
  int icC = r % ICC; r /= ICC;
  int ocT = r % OCT16; int tap = r / OCT16;
  int oc = ocT * 16 + (lane & 15);
  int ic0 = icC * 32 + (lane >> 4) * 8;
  const float* srcw = (oc < 128) ? sw0 : ((oc < 256) ? sw1 : sw2);
  int ocl = oc & 127;
  short8v hv, lv;
  #pragma unroll
  for (int j = 0; j < 8; ++j) {
    int ic = ic0 + j;
    float v = (ic < SNC) ? srcw[((size_t)ocl * SNC + ic) * 9 + tap] : 0.f;
    short h = f2bf(v);
    hv[j] = h;
    lv[j] = f2bf(v - bf2f(h));
  }
  size_t o = (size_t)tid * 8;
  *(short8v*)(ph + o) = hv;
  *(short8v*)(pl + o) = lv;
}

// ---------------- seg transpose: [B,35,HW] fp32 -> pixel-major bf16 [B*HW][64] (pad 0) ----------------
__global__ __launch_bounds__(256) void seg_pack_kernel(const float* __restrict__ seg,
                                                       short* __restrict__ segT) {
  int pix = blockIdx.x * 256 + threadIdx.x;
  int b = pix >> 12, px = pix & 4095;
  float v[64];
  #pragma unroll
  for (int ic = 0; ic < SNC; ++ic)
    v[ic] = seg[((size_t)b * SNC + ic) * HW + px];
  #pragma unroll
  for (int ic = SNC; ic < 64; ++ic) v[ic] = 0.f;
  size_t o = (size_t)pix * 64;
  #pragma unroll
  for (int k = 0; k < 8; ++k) {
    short8v h;
    #pragma unroll
    for (int j = 0; j < 8; ++j) h[j] = f2bf(v[k * 8 + j]);
    *(short8v*)(segT + o + k * 8) = h;
  }
}

// ---------------- MFMA split-precision implicit-GEMM conv (r10 NROW=2 structure) ----------------
// WLO=1: weight hi+lo; WLO=0: hi only. INLO=1: + input-lo term.
// MODE 1 prefetches epilogue src values at block start (latency hidden under conv).
template<int IC, int ICSTRIDE, int K3, int MODE, int ACCUM, int INLO, int WLO>
__global__ __launch_bounds__(256) void conv_mfma_kernel(
    const short* __restrict__ in_hi, const short* __restrict__ in_lo,
    const short* __restrict__ wp_hi, const short* __restrict__ wp_lo,
    const float* __restrict__ dscale,
    const float* __restrict__ src, const float* __restrict__ mu,
    const float* __restrict__ rstd, const float* __restrict__ gbias,
    const float* __restrict__ bbias, const float* __restrict__ sscale,
    float* __restrict__ outF, short* __restrict__ out_hi,
    short* __restrict__ out_lo, int OCT16, int C, int icbase, int lrelu) {
  const int b = blockIdx.x;
  const int r0 = blockIdx.y * 2;
  const int zl = blockIdx.z;
  const int t = threadIdx.x;
  const int wv = t >> 6;
  const int lane = t & 63;
  const int l15 = lane & 15, lg = lane >> 4;
  const int ICC = IC / 32;
  const int PS = 2128;

  __shared__ __align__(16) short lds_hi[4 * 2128];
  __shared__ __align__(16) short lds_lo[INLO ? 4 * 2128 : 8];

  float pre[2][2][8];
  if (MODE == 1) {
    #pragma unroll
    for (int a = 0; a < 2; ++a) {
      int base = zl * 128 + wv * 32 + a * 16 + lg * 4;
      int cA = base >> 1, cB = cA + 1;
      const float* srcA = src + ((size_t)b * C + cA) * HW;
      const float* srcB = src + ((size_t)b * C + cB) * HW;
      #pragma unroll
      for (int pt = 0; pt < 8; ++pt) {
        int px = (r0 + (pt >> 2)) * 64 + (pt & 3) * 16 + l15;
        pre[a][0][pt] = srcA[px];
        pre[a][1][pt] = srcB[px];
      }
    }
  }

  float4v acc[2][8];
  #pragma unroll
  for (int a = 0; a < 2; ++a)
    #pragma unroll
    for (int pt = 0; pt < 8; ++pt) acc[a][pt] = (float4v){0.f, 0.f, 0.f, 0.f};

  for (int icC = 0; icC < ICC; ++icC) {
    __syncthreads();
    const int ic0 = icC * 32;
    for (int idx = t; idx < 264 * 4; idx += 256) {
      int pos = idx >> 2, part = idx & 3;
      int srow = pos / 66;
      int scol = pos - srow * 66;
      int gy = r0 + srow - 1, gx = scol - 1;
      uint4v vh = {0u, 0u, 0u, 0u}, vl = {0u, 0u, 0u, 0u};
      bool ok = (gy >= 0 && gy < 64 && gx >= 0 && gx < 64);
      if (!K3) ok = ok && (srow >= 1 && srow <= 2);
      if (ok) {
        size_t g = ((size_t)b * HW + gy * 64 + gx) * ICSTRIDE + icbase + ic0 + part * 8;
        vh = *(const uint4v*)(in_hi + g);
        if (INLO) vl = *(const uint4v*)(in_lo + g);
      }
      int lo = part * PS + pos * 8;
      *(uint4v*)(lds_hi + lo) = vh;
      if (INLO) *(uint4v*)(lds_lo + lo) = vl;
    }
    __syncthreads();

    if (K3) {
      #pragma unroll
      for (int dx = 0; dx < 3; ++dx) {
        short8v Ah[3][2], Al[3][2];
        #pragma unroll
        for (int dy = 0; dy < 3; ++dy) {
          #pragma unroll
          for (int a = 0; a < 2; ++a) {
            size_t wi = ((((size_t)(dy * 3 + dx) * OCT16) + (zl * 8 + wv * 2 + a)) * ICC + icC) * 64 + lane;
            Ah[dy][a] = *(const short8v*)(wp_hi + wi * 8);
            if (WLO) Al[dy][a] = *(const short8v*)(wp_lo + wi * 8);
          }
        }
        #pragma unroll
        for (int c0i = 0; c0i < 4; ++c0i) {
          #pragma unroll
          for (int sr = 0; sr < 4; ++sr) {
            int pix = sr * 66 + c0i * 16 + dx + l15;
            int addr = lg * PS + pix * 8;
            short8v Bh = *(const short8v*)(lds_hi + addr);
            #pragma unroll
            for (int dy = 0; dy < 3; ++dy) {
              int pt = sr - dy;
              if (pt < 0 || pt > 1) continue;  // compile-time
              int ptt = pt * 4 + c0i;
              acc[0][ptt] = __builtin_amdgcn_mfma_f32_16x16x32_bf16(Ah[dy][0], Bh, acc[0][ptt], 0, 0, 0);
              acc[1][ptt] = __builtin_amdgcn_mfma_f32_16x16x32_bf16(Ah[dy][1], Bh, acc[1][ptt], 0, 0, 0);
              if (WLO) {
                acc[0][ptt] = __builtin_amdgcn_mfma_f32_16x16x32_bf16(Al[dy][0], Bh, acc[0][ptt], 0, 0, 0);
                acc[1][ptt] = __builtin_amdgcn_mfma_f32_16x16x32_bf16(Al[dy][1], Bh, acc[1][ptt], 0, 0, 0);
              }
            }
            if (INLO) {
              short8v Bl = *(const short8v*)(lds_lo + addr);
              #pragma unroll
              for (int dy = 0; dy < 3; ++dy) {
                int pt = sr - dy;
                if (pt < 0 || pt > 1) continue;
                int ptt = pt * 4 + c0i;
                acc[0][ptt] = __builtin_amdgcn_mfma_f32_16x16x32_bf16(Ah[dy][0], Bl, acc[0][ptt], 0, 0, 0);
                acc[1][ptt] = __builtin_amdgcn_mfma_f32_16x16x32_bf16(Ah[dy][1], Bl, acc[1][ptt], 0, 0, 0);
              }
            }
          }
        }
      }
    } else {
      short8v Ah[2], Al[2];
      #pragma unroll
      for (int a = 0; a < 2; ++a) {
        size_t wi = (((size_t)(zl * 8 + wv * 2 + a)) * ICC + icC) * 64 + lane;
        Ah[a] = *(const short8v*)(wp_hi + wi * 8);
        if (WLO) Al[a] = *(const short8v*)(wp_lo + wi * 8);
      }
      #pragma unroll
      for (int pt = 0; pt < 8; ++pt) {
        int pix = ((pt >> 2) + 1) * 66 + (pt & 3) * 16 + 1 + l15;
        int addr = lg * PS + pix * 8;
        short8v Bh = *(const short8v*)(lds_hi + addr);
        acc[0][pt] = __builtin_amdgcn_mfma_f32_16x16x32_bf16(Ah[0], Bh, acc[0][pt], 0, 0, 0);
        acc[1][pt] = __builtin_amdgcn_mfma_f32_16x16x32_bf16(Ah[1], Bh, acc[1][pt], 0, 0, 0);
        if (WLO) {
          acc[0][pt] = __builtin_amdgcn_mfma_f32_16x16x32_bf16(Al[0], Bh, acc[0][pt], 0, 0, 0);
          acc[1][pt] = __builtin_amdgcn_mfma_f32_16x16x32_bf16(Al[1], Bh, acc[1][pt], 0, 0, 0);
        }
        if (INLO) {
          short8v Bl = *(const short8v*)(lds_lo + addr);
          acc[0][pt] = __builtin_amdgcn_mfma_f32_16x16x32_bf16(Ah[0], Bl, acc[0][pt], 0, 0, 0);
          acc[1][pt] = __builtin_amdgcn_mfma_f32_16x16x32_bf16(Ah[1], Bl, acc[1][pt], 0, 0, 0);
        }
      }
    }
  }

  if (MODE == 1) {
    #pragma unroll
    for (int a = 0; a < 2; ++a) {
      int base = zl * 128 + wv * 32 + a * 16 + lg * 4;
      int cA = base >> 1;
      int cB = cA + 1;
      float muA = mu[b * C + cA], rsA = rstd[b * C + cA];
      float gbA = gbias[cA], bbA = bbias[cA], sA = sscale[b * C + cA];
      float muB = mu[b * C + cB], rsB = rstd[b * C + cB];
      float gbB = gbias[cB], bbB = bbias[cB], sB = sscale[b * C + cB];
      #pragma unroll
      for (int pt = 0; pt < 8; ++pt) {
        int px = (r0 + (pt >> 2)) * 64 + (pt & 3) * 16 + l15;
        float nvA = (pre[a][0][pt] - muA) * rsA;
        float vA = nvA * (1.f + acc[a][pt][0] + gbA) + acc[a][pt][1] + bbA;
        if (lrelu) vA = (vA >= 0.f) ? vA : 0.2f * vA;
        vA *= sA;
        float nvB = (pre[a][1][pt] - muB) * rsB;
        float vB = nvB * (1.f + acc[a][pt][2] + gbB) + acc[a][pt][3] + bbB;
        if (lrelu) vB = (vB >= 0.f) ? vB : 0.2f * vB;
        vB *= sB;
        short hA = f2bf(vA), hB = f2bf(vB);
        short lA = f2bf(vA - bf2f(hA)), lB = f2bf(vB - bf2f(hB));
        size_t o = ((size_t)b * HW + px) * C + cA;
        *(unsigned*)(out_hi + o) =
            (unsigned)(unsigned short)hA | ((unsigned)(unsigned short)hB << 16);
        *(unsigned*)(out_lo + o) =
            (unsigned)(unsigned short)lA | ((unsigned)(unsigned short)lB << 16);
      }
    }
  } else if (MODE == 2) {
    #pragma unroll
    for (int a = 0; a < 2; ++a) {
      int ocbase = zl * 128 + wv * 32 + a * 16 + lg * 4;
      float bs[4];
      #pragma unroll
      for (int r = 0; r < 4; ++r) bs[r] = gbias[ocbase + r];
      #pragma unroll
      for (int pt = 0; pt < 8; ++pt) {
        int px = (r0 + (pt >> 2)) * 64 + (pt & 3) * 16 + l15;
        short4v hs;
        #pragma unroll
        for (int r = 0; r < 4; ++r)
          hs[r] = f2bf(fmaxf(acc[a][pt][r] + bs[r], 0.f));
        *(short4v*)(out_hi + ((size_t)b * HW + px) * C + ocbase) = hs;
      }
    }
  } else {
    #pragma unroll
    for (int a = 0; a < 2; ++a) {
      int ocbase = zl * 128 + wv * 32 + a * 16 + lg * 4;
      float ds[4];
      #pragma unroll
      for (int r = 0; r < 4; ++r) ds[r] = dscale[b * 256 + ocbase + r];
      #pragma unroll
      for (int pt = 0; pt < 8; ++pt) {
        int px = (r0 + (pt >> 2)) * 64 + (pt & 3) * 16 + l15;
        #pragma unroll
        for (int r = 0; r < 4; ++r) {
          size_t oi = ((size_t)b * 256 + ocbase + r) * HW + px;
          float v = acc[a][pt][r] * ds[r];
          if (ACCUM) v += outF[oi];
          outF[oi] = v;
        }
      }
    }
  }
}

// ---------------- dual GB conv (weight-hi only): z<8 = ns -> sp2 (hi+lo), z>=8 = n0 -> sp (hi only) ----------------
// 64-ic staging rounds (2 rounds, halved barrier drains) + prefetched epilogue x reads.
__global__ __launch_bounds__(256) void conv_gb_dual_kernel(
    const short* __restrict__ actv_hi,
    const short* __restrict__ pgsh, const short* __restrict__ pg0h,
    const float* __restrict__ x, const float* __restrict__ mu,
    const float* __restrict__ rstd,
    const float* __restrict__ ns_gb, const float* __restrict__ ns_bb,
    const float* __restrict__ ss,
    const float* __restrict__ n0_gb, const float* __restrict__ n0_bb,
    const float* __restrict__ s0,
    short* __restrict__ sp2_hi, short* __restrict__ sp2_lo,
    short* __restrict__ sp_hi, short* __restrict__ sp_lo) {
  const int b = blockIdx.x;
  const int r0 = blockIdx.y * 2;
  const int zz = blockIdx.z;
  const bool isN0 = zz >= 8;
  const int zl = zz & 7;
  const short* wph = isN0 ? pg0h : pgsh;
  const float* gbias = isN0 ? n0_gb : ns_gb;
  const float* bbias = isN0 ? n0_bb : ns_bb;
  const float* sscale = isN0 ? s0 : ss;
  short* out_hi = isN0 ? sp_hi : sp2_hi;
  short* out_lo = isN0 ? sp_lo : sp2_lo;
  const int icbase = isN0 ? 0 : 256;
  const int lrelu = isN0 ? 1 : 0;
  const int OCT16 = 64, C = 512, ICC = 4, ICSTRIDE = 384;

  const int t = threadIdx.x;
  const int wv = t >> 6;
  const int lane = t & 63;
  const int l15 = lane & 15, lg = lane >> 4;
  const int PS = 2128;

  __shared__ __align__(16) short lds_hi[8 * 2128];

  // prefetch epilogue x reads (latency hides under conv)
  float pre[2][2][8];
  #pragma unroll
  for (int a = 0; a < 2; ++a) {
    int base = zl * 128 + wv * 32 + a * 16 + lg * 4;
    int cA = base >> 1, cB = cA + 1;
    const float* srcA = x + ((size_t)b * C + cA) * HW;
    const float* srcB = x + ((size_t)b * C + cB) * HW;
    #pragma unroll
    for (int pt = 0; pt < 8; ++pt) {
      int px = (r0 + (pt >> 2)) * 64 + (pt & 3) * 16 + l15;
      pre[a][0][pt] = srcA[px];
      pre[a][1][pt] = srcB[px];
    }
  }

  float4v acc[2][8];
  #pragma unroll
  for (int a = 0; a < 2; ++a)
    #pragma unroll
    for (int pt = 0; pt < 8; ++pt) acc[a][pt] = (float4v){0.f, 0.f, 0.f, 0.f};

  for (int rnd = 0; rnd < 2; ++rnd) {
    __syncthreads();
    for (int idx = t; idx < 264 * 8; idx += 256) {
      int pos = idx >> 3, part = idx & 7;
      int srow = pos / 66;
      int scol = pos - srow * 66;
      int gy = r0 + srow - 1, gx = scol - 1;
      uint4v vh = {0u, 0u, 0u, 0u};
      if (gy >= 0 && gy < 64 && gx >= 0 && gx < 64)
        vh = *(const uint4v*)(actv_hi + ((size_t)b * HW + gy * 64 + gx) * ICSTRIDE
                              + icbase + rnd * 64 + part * 8);
      *(uint4v*)(lds_hi + part * PS + pos * 8) = vh;
    }
    __syncthreads();

    #pragma unroll
    for (int sub = 0; sub < 2; ++sub) {
      const int icC = rnd * 2 + sub;
      #pragma unroll
      for (int dx = 0; dx < 3; ++dx) {
        short8v Ah[3][2];
        #pragma unroll
        for (int dy = 0; dy < 3; ++dy) {
          #pragma unroll
          for (int a = 0; a < 2; ++a) {
            size_t wi = ((((size_t)(dy * 3 + dx) * OCT16) + (zl * 8 + wv * 2 + a)) * ICC + icC) * 64 + lane;
            Ah[dy][a] = *(const short8v*)(wph + wi * 8);
          }
        }
        #pragma unroll
        for (int c0i = 0; c0i < 4; ++c0i) {
          #pragma unroll
          for (int sr = 0; sr < 4; ++sr) {
            int pix = sr * 66 + c0i * 16 + dx + l15;
            int addr = (sub * 4 + lg) * PS + pix * 8;
            short8v Bh = *(const short8v*)(lds_hi + addr);
            #pragma unroll
            for (int dy = 0; dy < 3; ++dy) {
              int pt = sr - dy;
              if (pt < 0 || pt > 1) continue;  // compile-time
              int ptt = pt * 4 + c0i;
              acc[0][ptt] = __builtin_amdgcn_mfma_f32_16x16x32_bf16(Ah[dy][0], Bh, acc[0][ptt], 0, 0, 0);
              acc[1][ptt] = __builtin_amdgcn_mfma_f32_16x16x32_bf16(Ah[dy][1], Bh, acc[1][ptt], 0, 0, 0);
            }
          }
        }
      }
    }
  }

  #pragma unroll
  for (int a = 0; a < 2; ++a) {
    int base = zl * 128 + wv * 32 + a * 16 + lg * 4;
    int cA = base >> 1;
    int cB = cA + 1;
    float muA = mu[b * C + cA], rsA = rstd[b * C + cA];
    float gbA = gbias[cA], bbA = bbias[cA], sA = sscale[b * C + cA];
    float muB = mu[b * C + cB], rsB = rstd[b * C + cB];
    float gbB = gbias[cB], bbB = bbias[cB], sB = sscale[b * C + cB];
    #pragma unroll
    for (int pt = 0; pt < 8; ++pt) {
      int px = (r0 + (pt >> 2)) * 64 + (pt & 3) * 16 + l15;
      float nvA = (pre[a][0][pt] - muA) * rsA;
      float vA = nvA * (1.f + acc[a][pt][0] + gbA) + acc[a][pt][1] + bbA;
      if (lrelu) vA = (vA >= 0.f) ? vA : 0.2f * vA;
      vA *= sA;
      float nvB = (pre[a][1][pt] - muB) * rsB;
      float vB = nvB * (1.f + acc[a][pt][2] + gbB) + acc[a][pt][3] + bbB;
      if (lrelu) vB = (vB >= 0.f) ? vB : 0.2f * vB;
      vB *= sB;
      short hA = f2bf(vA), hB = f2bf(vB);
      size_t o = ((size_t)b * HW + px) * C + cA;
      *(unsigned*)(out_hi + o) =
          (unsigned)(unsigned short)hA | ((unsigned)(unsigned short)hB << 16);
      if (!isN0) {
        short lA = f2bf(vA - bf2f(hA)), lB = f2bf(vB - bf2f(hB));
        *(unsigned*)(out_lo + o) =
            (unsigned)(unsigned short)lA | ((unsigned)(unsigned short)lB << 16);
      }
    }
  }
}

// ---------------- dual modconv: z<2 = modconv0 (3x3, sp->bufH, input-hi only), z>=2 = 1x1 (sp2->out, full) ----------------
__global__ __launch_bounds__(256) void conv_mc_dual_kernel(
    const short* __restrict__ sp_hi, const short* __restrict__ sp_lo,
    const short* __restrict__ p0h, const short* __restrict__ p0l,
    const float* __restrict__ d0, float* __restrict__ bufH,
    const short* __restrict__ sp2_hi, const short* __restrict__ sp2_lo,
    const short* __restrict__ psh, const short* __restrict__ psl,
    const float* __restrict__ dss, float* __restrict__ outD) {
  const int b = blockIdx.x;
  const int r0 = blockIdx.y * 2;
  const int zz = blockIdx.z;
  const bool is1x1 = zz >= 2;
  const int zl = zz & 1;
  const short* in_hi = is1x1 ? sp2_hi : sp_hi;
  const short* in_lo = is1x1 ? sp2_lo : sp_lo;
  const short* wph = is1x1 ? psh : p0h;
  const short* wpl = is1x1 ? psl : p0l;
  const float* dscale = is1x1 ? dss : d0;
  float* outF = is1x1 ? outD : bufH;
  const int OCT16 = 16, ICC = 16, ICSTRIDE = 512;

  const int t = threadIdx.x;
  const int wv = t >> 6;
  const int lane = t & 63;
  const int l15 = lane & 15, lg = lane >> 4;
  const int PS = 2128;

  __shared__ __align__(16) short lds_hi[4 * 2128];
  __shared__ __align__(16) short lds_lo[4 * 2128];

  float4v acc[2][8];
  #pragma unroll
  for (int a = 0; a < 2; ++a)
    #pragma unroll
    for (int pt = 0; pt < 8; ++pt) acc[a][pt] = (float4v){0.f, 0.f, 0.f, 0.f};

  for (int icC = 0; icC < ICC; ++icC) {
    __syncthreads();
    const int ic0 = icC * 32;
    if (!is1x1) {
      // modconv0: input-hi only (error attenuated by downstream instance norm)
      for (int idx = t; idx < 264 * 4; idx += 256) {
        int pos = idx >> 2, part = idx & 3;
        int srow = pos / 66;
        int scol = pos - srow * 66;
        int gy = r0 + srow - 1, gx = scol - 1;
        uint4v vh = {0u, 0u, 0u, 0u};
        if (gy >= 0 && gy < 64 && gx >= 0 && gx < 64)
          vh = *(const uint4v*)(in_hi + ((size_t)b * HW + gy * 64 + gx) * ICSTRIDE + ic0 + part * 8);
        *(uint4v*)(lds_hi + part * PS + pos * 8) = vh;
      }
    } else {
      for (int idx = t; idx < 132 * 4; idx += 256) {
        int pos = idx >> 2, part = idx & 3;
        int srow = pos / 66;
        int scol = pos - srow * 66;
        int gy = r0 + srow, gx = scol - 1;
        uint4v vh = {0u, 0u, 0u, 0u}, vl = {0u, 0u, 0u, 0u};
        if (gx >= 0 && gx < 64) {
          size_t g = ((size_t)b * HW + gy * 64 + gx) * ICSTRIDE + ic0 + part * 8;
          vh = *(const uint4v*)(in_hi + g);
          vl = *(const uint4v*)(in_lo + g);
        }
        int lo = part * PS + pos * 8;
        *(uint4v*)(lds_hi + lo) = vh;
        *(uint4v*)(lds_lo + lo) = vl;
      }
    }
    __syncthreads();

    if (!is1x1) {
      #pragma unroll
      for (int dx = 0; dx < 3; ++dx) {
        short8v Ah[3][2], Al[3][2];
        #pragma unroll
        for (int dy = 0; dy < 3; ++dy) {
          #pragma unroll
          for (int a = 0; a < 2; ++a) {
            size_t wi = ((((size_t)(dy * 3 + dx) * OCT16) + (zl * 8 + wv * 2 + a)) * ICC + icC) * 64 + lane;
            Ah[dy][a] = *(const short8v*)(wph + wi * 8);
            Al[dy][a] = *(const short8v*)(wpl + wi * 8);
          }
        }
        #pragma unroll
        for (int c0i = 0; c0i < 4; ++c0i) {
          #pragma unroll
          for (int sr = 0; sr < 4; ++sr) {
            int pix = sr * 66 + c0i * 16 + dx + l15;
            int addr = lg * PS + pix * 8;
            short8v Bh = *(const short8v*)(lds_hi + addr);
            #pragma unroll
            for (int dy = 0; dy < 3; ++dy) {
              int pt = sr - dy;
              if (pt < 0 || pt > 1) continue;  // compile-time
              int ptt = pt * 4 + c0i;
              acc[0][ptt] = __builtin_amdgcn_mfma_f32_16x16x32_bf16(Ah[dy][0], Bh, acc[0][ptt], 0, 0, 0);
              acc[1][ptt] = __builtin_amdgcn_mfma_f32_16x16x32_bf16(Ah[dy][1], Bh, acc[1][ptt], 0, 0, 0);
              acc[0][ptt] = __builtin_amdgcn_mfma_f32_16x16x32_bf16(Al[dy][0], Bh, acc[0][ptt], 0, 0, 0);
              acc[1][ptt] = __builtin_amdgcn_mfma_f32_16x16x32_bf16(Al[dy][1], Bh, acc[1][ptt], 0, 0, 0);
            }
          }
        }
      }
    } else {
      short8v Ah[2], Al[2];
      #pragma unroll
      for (int a = 0; a < 2; ++a) {
        size_t wi = (((size_t)(zl * 8 + wv * 2 + a)) * ICC + icC) * 64 + lane;
        Ah[a] = *(const short8v*)(wph + wi * 8);
        Al[a] = *(const short8v*)(wpl + wi * 8);
      }
      #pragma unroll
      for (int pt = 0; pt < 8; ++pt) {
        int pix = (pt >> 2) * 66 + (pt & 3) * 16 + 1 + l15;
        int addr = lg * PS + pix * 8;
        short8v Bh = *(const short8v*)(lds_hi + addr);
        short8v Bl = *(const short8v*)(lds_lo + addr);
        acc[0][pt] = __builtin_amdgcn_mfma_f32_16x16x32_bf16(Ah[0], Bh, acc[0][pt], 0, 0, 0);
        acc[1][pt] = __builtin_amdgcn_mfma_f32_16x16x32_bf16(Ah[1], Bh, acc[1][pt], 0, 0, 0);
        acc[0][pt] = __builtin_amdgcn_mfma_f32_16x16x32_bf16(Al[0], Bh, acc[0][pt], 0, 0, 0);
        acc[1][pt] = __builtin_amdgcn_mfma_f32_16x16x32_bf16(Al[1], Bh, acc[1][pt], 0, 0, 0);
        acc[0][pt] = __builtin_amdgcn_mfma_f32_16x16x32_bf16(Ah[0], Bl, acc[0][pt], 0, 0, 0);
        acc[1][pt] = __builtin_amdgcn_mfma_f32_16x16x32_bf16(Ah[1], Bl, acc[1][pt], 0, 0, 0);
      }
    }
  }

  #pragma unroll
  for (int a = 0; a < 2; ++a) {
    int ocbase = zl * 128 + wv * 32 + a * 16 + lg * 4;
    float ds[4];
    #pragma unroll
    for (int r = 0; r < 4; ++r) ds[r] = dscale[b * 256 + ocbase + r];
    #pragma unroll
    for (int pt = 0; pt < 8; ++pt) {
      int px = (r0 + (pt >> 2)) * 64 + (pt & 3) * 16 + l15;
      #pragma unroll
      for (int r = 0; r < 4; ++r) {
        size_t oi = ((size_t)b * 256 + ocbase + r) * HW + px;
        outF[oi] = acc[a][pt][r] * ds[r];
      }
    }
  }
}

extern "C" void kernel_launch(void* const* d_in, const int* in_sizes, int n_in,
                              void* d_out, int out_size, void* d_ws, size_t ws_size,
                              hipStream_t stream) {
  const float* x     = (const float*)d_in[0];
  const float* seg   = (const float*)d_in[1];
  const float* style = (const float*)d_in[2];
  const float* n0_sw = (const float*)d_in[3];
  const float* n0_sb = (const float*)d_in[4];
  const float* n0_gw = (const float*)d_in[5];
  const float* n0_gb = (const float*)d_in[6];
  const float* n0_bw = (const float*)d_in[7];
  const float* n0_bb = (const float*)d_in[8];
  const float* n1_sw = (const float*)d_in[9];
  const float* n1_sb = (const float*)d_in[10];
  const float* n1_gw = (const float*)d_in[11];
  const float* n1_gb = (const float*)d_in[12];
  const float* n1_bw = (const float*)d_in[13];
  const float* n1_bb = (const float*)d_in[14];
  const float* ns_sw = (const float*)d_in[15];
  const float* ns_sb = (const float*)d_in[16];
  const float* ns_gw = (const float*)d_in[17];
  const float* ns_gb = (const float*)d_in[18];
  const float* ns_bw = (const float*)d_in[19];
  const float* ns_bb = (const float*)d_in[20];
  const float* w0  = (const float*)d_in[21];
  const float* m0w = (const float*)d_in[22];
  const float* m0b = (const float*)d_in[23];
  const float* w1  = (const float*)d_in[24];
  const float* m1w = (const float*)d_in[25];
  const float* m1b = (const float*)d_in[26];
  const float* wss = (const float*)d_in[27];
  const float* msw = (const float*)d_in[28];
  const float* msb = (const float*)d_in[29];
  float* out = (float*)d_out;

  char* p = (char*)d_ws;
  auto allocF = [&](size_t n) { float* r = (float*)p; p += n * 4; return r; };
  auto allocS = [&](size_t n) { short* r = (short*)p; p += n * 2; return r; };

  float* mu_x   = allocF(4096);
  float* rstd_x = allocF(4096);
  float* mu_h   = allocF(2048);
  float* rstd_h = allocF(2048);
  float* s0  = allocF(4096);
  float* s1  = allocF(2048);
  float* ss  = allocF(4096);
  float* d0  = allocF(2048);
  float* d1  = allocF(2048);
  float* dss = allocF(2048);
  float* wsq0 = allocF(256 * 512);
  float* wsq1 = allocF(256 * 256);
  float* wsqs = allocF(256 * 512);
  float* sb_cat = allocF(384);
  float* bufH = allocF((size_t)BN * 256 * HW);
  short* actv_hi = allocS((size_t)BN * HW * 384);
  short* segT = allocS((size_t)BN * HW * 64);
  short* sp_hi = allocS((size_t)BN * HW * 512);
  short* sp_lo = allocS((size_t)BN * HW * 512);
  short* sp2_hi = allocS((size_t)BN * HW * 512);
  short* sp2_lo = allocS((size_t)BN * HW * 512);
  short* p0h = allocS((size_t)256 * 512 * 9);
  short* p0l = allocS((size_t)256 * 512 * 9);
  short* p1h = allocS((size_t)256 * 256 * 9);
  short* p1l = allocS((size_t)256 * 256 * 9);
  short* psh = allocS((size_t)256 * 512);
  short* psl = allocS((size_t)256 * 512);
  short* pswh = allocS((size_t)9 * 24 * 2 * 64 * 8);
  short* pswl = allocS((size_t)9 * 24 * 2 * 64 * 8);
  short* pgsh = allocS((size_t)1024 * 128 * 9);
  short* pg0h = allocS((size_t)1024 * 128 * 9);
  short* pg1h = allocS((size_t)512 * 128 * 9);

  float cs0 = 1.0f / sqrtf(512.f * 9.f);
  float cs1 = 1.0f / sqrtf(256.f * 9.f);
  float css = 1.0f / sqrtf(512.f);

  // -------- small precompute (merged) --------
  stats_kernel<<<BN * 512, 256, 0, stream>>>(x, mu_x, rstd_x);
  modscale_all_kernel<<<40, 256, 0, stream>>>(style, m0w, m0b, m1w, m1b, msw, msb,
                                              s0, s1, ss);
  wsq_all_kernel<<<1280, 256, 0, stream>>>(w0, w1, wss, wsq0, wsq1, wsqs);
  demod_all_kernel<<<24, 256, 0, stream>>>(wsq0, s0, d0, wsq1, s1, d1, wsqs, ss, dss,
                                           cs0, cs1, css);

  // -------- seg transpose + bias concat --------
  seg_pack_kernel<<<(BN * HW) / 256, 256, 0, stream>>>(seg, segT);
  hipMemcpyAsync(sb_cat,       n0_sb, 128 * 4, hipMemcpyDeviceToDevice, stream);
  hipMemcpyAsync(sb_cat + 128, n1_sb, 128 * 4, hipMemcpyDeviceToDevice, stream);
  hipMemcpyAsync(sb_cat + 256, ns_sb, 128 * 4, hipMemcpyDeviceToDevice, stream);

  // -------- weight packing (merged; gb weights hi-only) --------
  pack_sw_kernel<<<108, 256, 0, stream>>>(n0_sw, n1_sw, ns_sw, pswh, pswl);
  pack_w_all_kernel<<<2368, 256, 0, stream>>>(
      w0, w1, wss, ns_gw, ns_bw, n0_gw, n0_bw, n1_gw, n1_bw,
      p0h, p0l, p1h, p1l, psh, psl, pgsh, pg0h, pg1h);

  // -------- all 3 seg convs via MFMA (MODE=2) --------
  conv_mfma_kernel<64, 64, 1, 2, 0, 0, 1><<<dim3(BN, 32, 3), 256, 0, stream>>>(
      segT, nullptr, pswh, pswl, nullptr, nullptr, nullptr, nullptr, sb_cat,
      nullptr, nullptr, nullptr, actv_hi, nullptr, 24, 384, 0, 0);

  // -------- dual GB (weight-hi only, 64-ic rounds, prefetched x): ns -> sp2, n0 -> sp --------
  conv_gb_dual_kernel<<<dim3(BN, 32, 16), 256, 0, stream>>>(
      actv_hi, pgsh, pg0h, x, mu_x, rstd_x,
      ns_gb, ns_bb, ss, n0_gb, n0_bb, s0, sp2_hi, sp2_lo, sp_hi, sp_lo);

  // -------- dual modconv: modconv0 (input-hi, sp->bufH) + 1x1 shortcut (full, sp2->out) --------
  conv_mc_dual_kernel<<<dim3(BN, 32, 4), 256, 0, stream>>>(
      sp_hi, sp_lo, p0h, p0l, d0, bufH,
      sp2_hi, sp2_lo, psh, psl, dss, out);

  // -------- spade_n1 over bufH (lrelu, weight-hi only, prefetched src) -> modconv1 (+= into d_out) --------
  stats_kernel<<<BN * 256, 256, 0, stream>>>(bufH, mu_h, rstd_h);
  conv_mfma_kernel<128, 384, 1, 1, 0, 0, 0><<<dim3(BN, 32, 4), 256, 0, stream>>>(
      actv_hi, nullptr, pg1h, nullptr, nullptr, bufH, mu_h, rstd_h, n1_gb, n1_bb, s1,
      nullptr, sp_hi, sp_lo, 32, 256, 128, 1);
  conv_mfma_kernel<256, 256, 1, 0, 1, 1, 1><<<dim3(BN, 32, 2), 256, 0, stream>>>(
      sp_hi, sp_lo, p1h, p1l, d1, nullptr, nullptr, nullptr, nullptr, nullptr,
      nullptr, out, nullptr, nullptr, 16, 0, 0, 0);
}

// Round 16
// 779.673 us; speedup vs baseline: 1.0997x; 1.0997x over previous
//
#include <hip/hip_runtime.h>
#include <math.h>

#define BN 8
#define HW 4096
#define NH 128
#define SNC 35
#define SD 512

typedef __attribute__((ext_vector_type(8))) short short8v;
typedef __attribute__((ext_vector_type(4))) short short4v;
typedef __attribute__((ext_vector_type(4))) float float4v;
typedef __attribute__((ext_vector_type(4))) unsigned int uint4v;

__device__ __forceinline__ short f2bf(float f) {
  unsigned u = __float_as_uint(f);
  unsigned r = (u + 0x7fffu + ((u >> 16) & 1u)) >> 16;
  return (short)r;
}
__device__ __forceinline__ float bf2f(short h) {
  return __uint_as_float(((unsigned)(unsigned short)h) << 16);
}

// ---------------- per-(b,c) instance-norm stats ----------------
__global__ __launch_bounds__(256) void stats_kernel(const float* __restrict__ x,
                                                    float* __restrict__ mu,
                                                    float* __restrict__ rstd) {
  int row = blockIdx.x;
  const float* p = x + (size_t)row * HW;
  float s = 0.f, s2 = 0.f;
  for (int i = threadIdx.x; i < HW; i += 256) {
    float v = p[i];
    s += v; s2 += v * v;
  }
  #pragma unroll
  for (int off = 32; off > 0; off >>= 1) {
    s  += __shfl_down(s, off);
    s2 += __shfl_down(s2, off);
  }
  __shared__ float as[4], as2[4];
  int wid = threadIdx.x >> 6;
  if ((threadIdx.x & 63) == 0) { as[wid] = s; as2[wid] = s2; }
  __syncthreads();
  if (threadIdx.x == 0) {
    float t  = as[0] + as[1] + as[2] + as[3];
    float t2 = as2[0] + as2[1] + as2[2] + as2[3];
    float m = t * (1.f / HW);
    float var = t2 * (1.f / HW) - m * m;
    mu[row] = m;
    rstd[row] = rsqrtf(var + 1e-5f);
  }
}

// ---------------- merged style modulation (3 segments) ----------------
__global__ __launch_bounds__(256) void modscale_all_kernel(
    const float* __restrict__ style,
    const float* __restrict__ m0w, const float* __restrict__ m0b,
    const float* __restrict__ m1w, const float* __restrict__ m1b,
    const float* __restrict__ msw, const float* __restrict__ msb,
    float* __restrict__ s0, float* __restrict__ s1, float* __restrict__ ss) {
  int idx = blockIdx.x * 256 + threadIdx.x;
  const float *mw, *mb; float* o; int I;
  if (idx < 4096) { mw = m0w; mb = m0b; o = s0; I = 512; }
  else if (idx < 6144) { idx -= 4096; mw = m1w; mb = m1b; o = s1; I = 256; }
  else if (idx < 10240) { idx -= 6144; mw = msw; mb = msb; o = ss; I = 512; }
  else return;
  int b = idx / I, i = idx - b * I;
  const float* st = style + (size_t)b * SD;
  const float* w  = mw + (size_t)i * SD;
  float acc = 0.f;
  for (int d = 0; d < SD; ++d) acc += st[d] * w[d];
  o[idx] = acc * 0.044194173824159216f + mb[i];
}

// ---------------- merged sum of w^2 (3 segments) ----------------
__global__ __launch_bounds__(256) void wsq_all_kernel(
    const float* __restrict__ w0, const float* __restrict__ w1,
    const float* __restrict__ wss,
    float* __restrict__ wsq0, float* __restrict__ wsq1, float* __restrict__ wsqs) {
  int idx = blockIdx.x * 256 + threadIdx.x;
  const float* w; float* o; int KK;
  if (idx < 131072) { w = w0; o = wsq0; KK = 9; }
  else if (idx < 196608) { idx -= 131072; w = w1; o = wsq1; KK = 9; }
  else if (idx < 327680) { idx -= 196608; w = wss; o = wsqs; KK = 1; }
  else return;
  const float* p = w + (size_t)idx * KK;
  float a = 0.f;
  for (int t = 0; t < KK; ++t) a += p[t] * p[t];
  o[idx] = a;
}

// ---------------- merged demod (3 segments) ----------------
__global__ __launch_bounds__(256) void demod_all_kernel(
    const float* __restrict__ wsq0, const float* __restrict__ s0, float* __restrict__ d0,
    const float* __restrict__ wsq1, const float* __restrict__ s1, float* __restrict__ d1,
    const float* __restrict__ wsqs, const float* __restrict__ ss, float* __restrict__ dss,
    float cs0, float cs1, float css) {
  int idx = blockIdx.x * 256 + threadIdx.x;
  const float *wsq, *s; float* dsc; int I; float cs;
  if (idx < 2048) { wsq = wsq0; s = s0; dsc = d0; I = 512; cs = cs0; }
  else if (idx < 4096) { idx -= 2048; wsq = wsq1; s = s1; dsc = d1; I = 256; cs = cs1; }
  else if (idx < 6144) { idx -= 4096; wsq = wsqs; s = ss; dsc = dss; I = 512; cs = css; }
  else return;
  int b = idx >> 8, o = idx & 255;
  const float* wr = wsq + (size_t)o * I;
  const float* sr = s + (size_t)b * I;
  float a = 0.f;
  for (int i = 0; i < I; ++i) { float sv = sr[i]; a += wr[i] * sv * sv; }
  dsc[idx] = rsqrtf(cs * cs * a + 1e-8f) * cs;
}

// ---------------- weight pack helper ----------------
__device__ __forceinline__ void pack_one(int tid, const float* __restrict__ wg,
                                         const float* __restrict__ wb,
                                         short* __restrict__ ph, short* __restrict__ pl,
                                         int OCtot, int IC, int KK, int interleave) {
  int ICC = IC / 32;
  int OCT16 = OCtot / 16;
  int lane = tid & 63;
  int r = tid >> 6;
  int icC = r % ICC; r /= ICC;
  int ocT = r % OCT16; int tap = r / OCT16;
  int po = ocT * 16 + (lane & 15);
  int ic0 = icC * 32 + (lane >> 4) * 8;
  const float* srcw;
  int oc;
  if (interleave) { oc = po >> 1; srcw = (po & 1) ? wb : wg; }
  else { oc = po; srcw = wg; }
  short8v hv, lv;
  #pragma unroll
  for (int j = 0; j < 8; ++j) {
    float v = srcw[((size_t)oc * IC + ic0 + j) * KK + tap];
    short h = f2bf(v);
    hv[j] = h;
    lv[j] = f2bf(v - bf2f(h));
  }
  size_t o = (size_t)tid * 8;
  *(short8v*)(ph + o) = hv;
  if (pl) *(short8v*)(pl + o) = lv;
}

// ---------------- merged weight packing: 6 segments ----------------
__global__ __launch_bounds__(256) void pack_w_all_kernel(
    const float* w0, const float* w1, const float* wss,
    const float* ns_gw, const float* ns_bw,
    const float* n0_gw, const float* n0_bw,
    const float* n1_gw, const float* n1_bw,
    short* p0h, short* p0l, short* p1h, short* p1l, short* psh, short* psl,
    short* pgsh, short* pg0h, short* pg1h) {
  int tid = blockIdx.x * 256 + threadIdx.x;
  if (tid < 147456) { pack_one(tid, w0, nullptr, p0h, p0l, 256, 512, 9, 0); return; }
  tid -= 147456;
  if (tid < 73728) { pack_one(tid, w1, nullptr, p1h, p1l, 256, 256, 9, 0); return; }
  tid -= 73728;
  if (tid < 16384) { pack_one(tid, wss, nullptr, psh, psl, 256, 512, 1, 0); return; }
  tid -= 16384;
  if (tid < 147456) { pack_one(tid, ns_gw, ns_bw, pgsh, nullptr, 1024, 128, 9, 1); return; }
  tid -= 147456;
  if (tid < 147456) { pack_one(tid, n0_gw, n0_bw, pg0h, nullptr, 1024, 128, 9, 1); return; }
  tid -= 147456;
  if (tid < 73728) pack_one(tid, n1_gw, n1_bw, pg1h, nullptr, 512, 128, 9, 1);
}

// ---------------- pack the 3 seg-conv weight sets: OCtot=384, IC 35 padded to 64 ----------------
__global__ __launch_bounds__(256) void pack_sw_kernel(const float* __restrict__ sw0,
                                                      const float* __restrict__ sw1,
                                                      const float* __restrict__ sw2,
                                                      short* __restrict__ ph,
                                                      short* __restrict__ pl) {
  int tid = blockIdx.x * 256 + threadIdx.x;
  const int ICC = 2, OCT16 = 24;
  int total = 9 * OCT16 * ICC * 64;
  if (tid >= total) return;
  int lane = tid & 63;
  int r = tid >> 6;
  int icC = r % ICC; r /= ICC;
  int ocT = r % OCT16; int tap = r / OCT16;
  int oc = ocT * 16 + (lane & 15);
  int ic0 = icC * 32 + (lane >> 4) * 8;
  const float* srcw = (oc < 128) ? sw0 : ((oc < 256) ? sw1 : sw2);
  int ocl = oc & 127;
  short8v hv, lv;
  #pragma unroll
  for (int j = 0; j < 8; ++j) {
    int ic = ic0 + j;
    float v = (ic < SNC) ? srcw[((size_t)ocl * SNC + ic) * 9 + tap] : 0.f;
    short h = f2bf(v);
    hv[j] = h;
    lv[j] = f2bf(v - bf2f(h));
  }
  size_t o = (size_t)tid * 8;
  *(short8v*)(ph + o) = hv;
  *(short8v*)(pl + o) = lv;
}

// ---------------- seg transpose: [B,35,HW] fp32 -> pixel-major bf16 [B*HW][64] (pad 0) ----------------
__global__ __launch_bounds__(256) void seg_pack_kernel(const float* __restrict__ seg,
                                                       short* __restrict__ segT) {
  int pix = blockIdx.x * 256 + threadIdx.x;
  int b = pix >> 12, px = pix & 4095;
  float v[64];
  #pragma unroll
  for (int ic = 0; ic < SNC; ++ic)
    v[ic] = seg[((size_t)b * SNC + ic) * HW + px];
  #pragma unroll
  for (int ic = SNC; ic < 64; ++ic) v[ic] = 0.f;
  size_t o = (size_t)pix * 64;
  #pragma unroll
  for (int k = 0; k < 8; ++k) {
    short8v h;
    #pragma unroll
    for (int j = 0; j < 8; ++j) h[j] = f2bf(v[k * 8 + j]);
    *(short8v*)(segT + o + k * 8) = h;
  }
}

// ---------------- MFMA split-precision implicit-GEMM conv (r10 NROW=2 structure) ----------------
template<int IC, int ICSTRIDE, int K3, int MODE, int ACCUM, int INLO, int WLO>
__global__ __launch_bounds__(256) void conv_mfma_kernel(
    const short* __restrict__ in_hi, const short* __restrict__ in_lo,
    const short* __restrict__ wp_hi, const short* __restrict__ wp_lo,
    const float* __restrict__ dscale,
    const float* __restrict__ src, const float* __restrict__ mu,
    const float* __restrict__ rstd, const float* __restrict__ gbias,
    const float* __restrict__ bbias, const float* __restrict__ sscale,
    float* __restrict__ outF, short* __restrict__ out_hi,
    short* __restrict__ out_lo, int OCT16, int C, int icbase, int lrelu) {
  const int b = blockIdx.x;
  const int r0 = blockIdx.y * 2;
  const int zl = blockIdx.z;
  const int t = threadIdx.x;
  const int wv = t >> 6;
  const int lane = t & 63;
  const int l15 = lane & 15, lg = lane >> 4;
  const int ICC = IC / 32;
  const int PS = 2128;

  __shared__ __align__(16) short lds_hi[4 * 2128];
  __shared__ __align__(16) short lds_lo[INLO ? 4 * 2128 : 8];

  float pre[2][2][8];
  if (MODE == 1) {
    #pragma unroll
    for (int a = 0; a < 2; ++a) {
      int base = zl * 128 + wv * 32 + a * 16 + lg * 4;
      int cA = base >> 1, cB = cA + 1;
      const float* srcA = src + ((size_t)b * C + cA) * HW;
      const float* srcB = src + ((size_t)b * C + cB) * HW;
      #pragma unroll
      for (int pt = 0; pt < 8; ++pt) {
        int px = (r0 + (pt >> 2)) * 64 + (pt & 3) * 16 + l15;
        pre[a][0][pt] = srcA[px];
        pre[a][1][pt] = srcB[px];
      }
    }
  }

  float4v acc[2][8];
  #pragma unroll
  for (int a = 0; a < 2; ++a)
    #pragma unroll
    for (int pt = 0; pt < 8; ++pt) acc[a][pt] = (float4v){0.f, 0.f, 0.f, 0.f};

  for (int icC = 0; icC < ICC; ++icC) {
    __syncthreads();
    const int ic0 = icC * 32;
    for (int idx = t; idx < 264 * 4; idx += 256) {
      int pos = idx >> 2, part = idx & 3;
      int srow = pos / 66;
      int scol = pos - srow * 66;
      int gy = r0 + srow - 1, gx = scol - 1;
      uint4v vh = {0u, 0u, 0u, 0u}, vl = {0u, 0u, 0u, 0u};
      bool ok = (gy >= 0 && gy < 64 && gx >= 0 && gx < 64);
      if (!K3) ok = ok && (srow >= 1 && srow <= 2);
      if (ok) {
        size_t g = ((size_t)b * HW + gy * 64 + gx) * ICSTRIDE + icbase + ic0 + part * 8;
        vh = *(const uint4v*)(in_hi + g);
        if (INLO) vl = *(const uint4v*)(in_lo + g);
      }
      int lo = part * PS + pos * 8;
      *(uint4v*)(lds_hi + lo) = vh;
      if (INLO) *(uint4v*)(lds_lo + lo) = vl;
    }
    __syncthreads();

    if (K3) {
      #pragma unroll
      for (int dx = 0; dx < 3; ++dx) {
        short8v Ah[3][2], Al[3][2];
        #pragma unroll
        for (int dy = 0; dy < 3; ++dy) {
          #pragma unroll
          for (int a = 0; a < 2; ++a) {
            size_t wi = ((((size_t)(dy * 3 + dx) * OCT16) + (zl * 8 + wv * 2 + a)) * ICC + icC) * 64 + lane;
            Ah[dy][a] = *(const short8v*)(wp_hi + wi * 8);
            if (WLO) Al[dy][a] = *(const short8v*)(wp_lo + wi * 8);
          }
        }
        #pragma unroll
        for (int c0i = 0; c0i < 4; ++c0i) {
          #pragma unroll
          for (int sr = 0; sr < 4; ++sr) {
            int pix = sr * 66 + c0i * 16 + dx + l15;
            int addr = lg * PS + pix * 8;
            short8v Bh = *(const short8v*)(lds_hi + addr);
            #pragma unroll
            for (int dy = 0; dy < 3; ++dy) {
              int pt = sr - dy;
              if (pt < 0 || pt > 1) continue;  // compile-time
              int ptt = pt * 4 + c0i;
              acc[0][ptt] = __builtin_amdgcn_mfma_f32_16x16x32_bf16(Ah[dy][0], Bh, acc[0][ptt], 0, 0, 0);
              acc[1][ptt] = __builtin_amdgcn_mfma_f32_16x16x32_bf16(Ah[dy][1], Bh, acc[1][ptt], 0, 0, 0);
              if (WLO) {
                acc[0][ptt] = __builtin_amdgcn_mfma_f32_16x16x32_bf16(Al[dy][0], Bh, acc[0][ptt], 0, 0, 0);
                acc[1][ptt] = __builtin_amdgcn_mfma_f32_16x16x32_bf16(Al[dy][1], Bh, acc[1][ptt], 0, 0, 0);
              }
            }
            if (INLO) {
              short8v Bl = *(const short8v*)(lds_lo + addr);
              #pragma unroll
              for (int dy = 0; dy < 3; ++dy) {
                int pt = sr - dy;
                if (pt < 0 || pt > 1) continue;
                int ptt = pt * 4 + c0i;
                acc[0][ptt] = __builtin_amdgcn_mfma_f32_16x16x32_bf16(Ah[dy][0], Bl, acc[0][ptt], 0, 0, 0);
                acc[1][ptt] = __builtin_amdgcn_mfma_f32_16x16x32_bf16(Ah[dy][1], Bl, acc[1][ptt], 0, 0, 0);
              }
            }
          }
        }
      }
    } else {
      short8v Ah[2], Al[2];
      #pragma unroll
      for (int a = 0; a < 2; ++a) {
        size_t wi = (((size_t)(zl * 8 + wv * 2 + a)) * ICC + icC) * 64 + lane;
        Ah[a] = *(const short8v*)(wp_hi + wi * 8);
        if (WLO) Al[a] = *(const short8v*)(wp_lo + wi * 8);
      }
      #pragma unroll
      for (int pt = 0; pt < 8; ++pt) {
        int pix = ((pt >> 2) + 1) * 66 + (pt & 3) * 16 + 1 + l15;
        int addr = lg * PS + pix * 8;
        short8v Bh = *(const short8v*)(lds_hi + addr);
        acc[0][pt] = __builtin_amdgcn_mfma_f32_16x16x32_bf16(Ah[0], Bh, acc[0][pt], 0, 0, 0);
        acc[1][pt] = __builtin_amdgcn_mfma_f32_16x16x32_bf16(Ah[1], Bh, acc[1][pt], 0, 0, 0);
        if (WLO) {
          acc[0][pt] = __builtin_amdgcn_mfma_f32_16x16x32_bf16(Al[0], Bh, acc[0][pt], 0, 0, 0);
          acc[1][pt] = __builtin_amdgcn_mfma_f32_16x16x32_bf16(Al[1], Bh, acc[1][pt], 0, 0, 0);
        }
        if (INLO) {
          short8v Bl = *(const short8v*)(lds_lo + addr);
          acc[0][pt] = __builtin_amdgcn_mfma_f32_16x16x32_bf16(Ah[0], Bl, acc[0][pt], 0, 0, 0);
          acc[1][pt] = __builtin_amdgcn_mfma_f32_16x16x32_bf16(Ah[1], Bl, acc[1][pt], 0, 0, 0);
        }
      }
    }
  }

  if (MODE == 1) {
    #pragma unroll
    for (int a = 0; a < 2; ++a) {
      int base = zl * 128 + wv * 32 + a * 16 + lg * 4;
      int cA = base >> 1;
      int cB = cA + 1;
      float muA = mu[b * C + cA], rsA = rstd[b * C + cA];
      float gbA = gbias[cA], bbA = bbias[cA], sA = sscale[b * C + cA];
      float muB = mu[b * C + cB], rsB = rstd[b * C + cB];
      float gbB = gbias[cB], bbB = bbias[cB], sB = sscale[b * C + cB];
      #pragma unroll
      for (int pt = 0; pt < 8; ++pt) {
        int px = (r0 + (pt >> 2)) * 64 + (pt & 3) * 16 + l15;
        float nvA = (pre[a][0][pt] - muA) * rsA;
        float vA = nvA * (1.f + acc[a][pt][0] + gbA) + acc[a][pt][1] + bbA;
        if (lrelu) vA = (vA >= 0.f) ? vA : 0.2f * vA;
        vA *= sA;
        float nvB = (pre[a][1][pt] - muB) * rsB;
        float vB = nvB * (1.f + acc[a][pt][2] + gbB) + acc[a][pt][3] + bbB;
        if (lrelu) vB = (vB >= 0.f) ? vB : 0.2f * vB;
        vB *= sB;
        short hA = f2bf(vA), hB = f2bf(vB);
        short lA = f2bf(vA - bf2f(hA)), lB = f2bf(vB - bf2f(hB));
        size_t o = ((size_t)b * HW + px) * C + cA;
        *(unsigned*)(out_hi + o) =
            (unsigned)(unsigned short)hA | ((unsigned)(unsigned short)hB << 16);
        *(unsigned*)(out_lo + o) =
            (unsigned)(unsigned short)lA | ((unsigned)(unsigned short)lB << 16);
      }
    }
  } else if (MODE == 2) {
    #pragma unroll
    for (int a = 0; a < 2; ++a) {
      int ocbase = zl * 128 + wv * 32 + a * 16 + lg * 4;
      float bs[4];
      #pragma unroll
      for (int r = 0; r < 4; ++r) bs[r] = gbias[ocbase + r];
      #pragma unroll
      for (int pt = 0; pt < 8; ++pt) {
        int px = (r0 + (pt >> 2)) * 64 + (pt & 3) * 16 + l15;
        short4v hs;
        #pragma unroll
        for (int r = 0; r < 4; ++r)
          hs[r] = f2bf(fmaxf(acc[a][pt][r] + bs[r], 0.f));
        *(short4v*)(out_hi + ((size_t)b * HW + px) * C + ocbase) = hs;
      }
    }
  } else {
    #pragma unroll
    for (int a = 0; a < 2; ++a) {
      int ocbase = zl * 128 + wv * 32 + a * 16 + lg * 4;
      float ds[4];
      #pragma unroll
      for (int r = 0; r < 4; ++r) ds[r] = dscale[b * 256 + ocbase + r];
      #pragma unroll
      for (int pt = 0; pt < 8; ++pt) {
        int px = (r0 + (pt >> 2)) * 64 + (pt & 3) * 16 + l15;
        #pragma unroll
        for (int r = 0; r < 4; ++r) {
          size_t oi = ((size_t)b * 256 + ocbase + r) * HW + px;
          float v = acc[a][pt][r] * ds[r];
          if (ACCUM) v += outF[oi];
          outF[oi] = v;
        }
      }
    }
  }
}

// ---------------- dual GB conv (weight-hi only): z<8 = ns -> sp2 (hi+lo), z>=8 = n0 -> sp (hi only) ----------------
__global__ __launch_bounds__(256) void conv_gb_dual_kernel(
    const short* __restrict__ actv_hi,
    const short* __restrict__ pgsh, const short* __restrict__ pg0h,
    const float* __restrict__ x, const float* __restrict__ mu,
    const float* __restrict__ rstd,
    const float* __restrict__ ns_gb, const float* __restrict__ ns_bb,
    const float* __restrict__ ss,
    const float* __restrict__ n0_gb, const float* __restrict__ n0_bb,
    const float* __restrict__ s0,
    short* __restrict__ sp2_hi, short* __restrict__ sp2_lo,
    short* __restrict__ sp_hi, short* __restrict__ sp_lo) {
  const int b = blockIdx.x;
  const int r0 = blockIdx.y * 2;
  const int zz = blockIdx.z;
  const bool isN0 = zz >= 8;
  const int zl = zz & 7;
  const short* wph = isN0 ? pg0h : pgsh;
  const float* gbias = isN0 ? n0_gb : ns_gb;
  const float* bbias = isN0 ? n0_bb : ns_bb;
  const float* sscale = isN0 ? s0 : ss;
  short* out_hi = isN0 ? sp_hi : sp2_hi;
  short* out_lo = isN0 ? sp_lo : sp2_lo;
  const int icbase = isN0 ? 0 : 256;
  const int lrelu = isN0 ? 1 : 0;
  const int OCT16 = 64, C = 512, ICC = 4, ICSTRIDE = 384;

  const int t = threadIdx.x;
  const int wv = t >> 6;
  const int lane = t & 63;
  const int l15 = lane & 15, lg = lane >> 4;
  const int PS = 2128;

  __shared__ __align__(16) short lds_hi[8 * 2128];

  float pre[2][2][8];
  #pragma unroll
  for (int a = 0; a < 2; ++a) {
    int base = zl * 128 + wv * 32 + a * 16 + lg * 4;
    int cA = base >> 1, cB = cA + 1;
    const float* srcA = x + ((size_t)b * C + cA) * HW;
    const float* srcB = x + ((size_t)b * C + cB) * HW;
    #pragma unroll
    for (int pt = 0; pt < 8; ++pt) {
      int px = (r0 + (pt >> 2)) * 64 + (pt & 3) * 16 + l15;
      pre[a][0][pt] = srcA[px];
      pre[a][1][pt] = srcB[px];
    }
  }

  float4v acc[2][8];
  #pragma unroll
  for (int a = 0; a < 2; ++a)
    #pragma unroll
    for (int pt = 0; pt < 8; ++pt) acc[a][pt] = (float4v){0.f, 0.f, 0.f, 0.f};

  for (int rnd = 0; rnd < 2; ++rnd) {
    __syncthreads();
    for (int idx = t; idx < 264 * 8; idx += 256) {
      int pos = idx >> 3, part = idx & 7;
      int srow = pos / 66;
      int scol = pos - srow * 66;
      int gy = r0 + srow - 1, gx = scol - 1;
      uint4v vh = {0u, 0u, 0u, 0u};
      if (gy >= 0 && gy < 64 && gx >= 0 && gx < 64)
        vh = *(const uint4v*)(actv_hi + ((size_t)b * HW + gy * 64 + gx) * ICSTRIDE
                              + icbase + rnd * 64 + part * 8);
      *(uint4v*)(lds_hi + part * PS + pos * 8) = vh;
    }
    __syncthreads();

    #pragma unroll
    for (int sub = 0; sub < 2; ++sub) {
      const int icC = rnd * 2 + sub;
      #pragma unroll
      for (int dx = 0; dx < 3; ++dx) {
        short8v Ah[3][2];
        #pragma unroll
        for (int dy = 0; dy < 3; ++dy) {
          #pragma unroll
          for (int a = 0; a < 2; ++a) {
            size_t wi = ((((size_t)(dy * 3 + dx) * OCT16) + (zl * 8 + wv * 2 + a)) * ICC + icC) * 64 + lane;
            Ah[dy][a] = *(const short8v*)(wph + wi * 8);
          }
        }
        #pragma unroll
        for (int c0i = 0; c0i < 4; ++c0i) {
          #pragma unroll
          for (int sr = 0; sr < 4; ++sr) {
            int pix = sr * 66 + c0i * 16 + dx + l15;
            int addr = (sub * 4 + lg) * PS + pix * 8;
            short8v Bh = *(const short8v*)(lds_hi + addr);
            #pragma unroll
            for (int dy = 0; dy < 3; ++dy) {
              int pt = sr - dy;
              if (pt < 0 || pt > 1) continue;  // compile-time
              int ptt = pt * 4 + c0i;
              acc[0][ptt] = __builtin_amdgcn_mfma_f32_16x16x32_bf16(Ah[dy][0], Bh, acc[0][ptt], 0, 0, 0);
              acc[1][ptt] = __builtin_amdgcn_mfma_f32_16x16x32_bf16(Ah[dy][1], Bh, acc[1][ptt], 0, 0, 0);
            }
          }
        }
      }
    }
  }

  #pragma unroll
  for (int a = 0; a < 2; ++a) {
    int base = zl * 128 + wv * 32 + a * 16 + lg * 4;
    int cA = base >> 1;
    int cB = cA + 1;
    float muA = mu[b * C + cA], rsA = rstd[b * C + cA];
    float gbA = gbias[cA], bbA = bbias[cA], sA = sscale[b * C + cA];
    float muB = mu[b * C + cB], rsB = rstd[b * C + cB];
    float gbB = gbias[cB], bbB = bbias[cB], sB = sscale[b * C + cB];
    #pragma unroll
    for (int pt = 0; pt < 8; ++pt) {
      int px = (r0 + (pt >> 2)) * 64 + (pt & 3) * 16 + l15;
      float nvA = (pre[a][0][pt] - muA) * rsA;
      float vA = nvA * (1.f + acc[a][pt][0] + gbA) + acc[a][pt][1] + bbA;
      if (lrelu) vA = (vA >= 0.f) ? vA : 0.2f * vA;
      vA *= sA;
      float nvB = (pre[a][1][pt] - muB) * rsB;
      float vB = nvB * (1.f + acc[a][pt][2] + gbB) + acc[a][pt][3] + bbB;
      if (lrelu) vB = (vB >= 0.f) ? vB : 0.2f * vB;
      vB *= sB;
      short hA = f2bf(vA), hB = f2bf(vB);
      size_t o = ((size_t)b * HW + px) * C + cA;
      *(unsigned*)(out_hi + o) =
          (unsigned)(unsigned short)hA | ((unsigned)(unsigned short)hB << 16);
      if (!isN0) {
        short lA = f2bf(vA - bf2f(hA)), lB = f2bf(vB - bf2f(hB));
        *(unsigned*)(out_lo + o) =
            (unsigned)(unsigned short)lA | ((unsigned)(unsigned short)lB << 16);
      }
    }
  }
}

// ---------------- dual modconv, VGPR-capped: z<2 = modconv0 (3x3, input-hi, 64-ic rounds),
// z>=2 = 1x1 (full precision). Shared 8-part LDS: 1x1 uses parts 0-3 hi / 4-7 lo. ----------------
__global__ __launch_bounds__(256, 4) void conv_mc_dual_kernel(
    const short* __restrict__ sp_hi, const short* __restrict__ sp_lo,
    const short* __restrict__ p0h, const short* __restrict__ p0l,
    const float* __restrict__ d0, float* __restrict__ bufH,
    const short* __restrict__ sp2_hi, const short* __restrict__ sp2_lo,
    const short* __restrict__ psh, const short* __restrict__ psl,
    const float* __restrict__ dss, float* __restrict__ outD) {
  const int b = blockIdx.x;
  const int r0 = blockIdx.y * 2;
  const int zz = blockIdx.z;
  const bool is1x1 = zz >= 2;
  const int zl = zz & 1;
  const int OCT16 = 16, ICC = 16, ICSTRIDE = 512;

  const int t = threadIdx.x;
  const int wv = t >> 6;
  const int lane = t & 63;
  const int l15 = lane & 15, lg = lane >> 4;
  const int PS = 2128;

  __shared__ __align__(16) short lds[8 * 2128];

  float4v acc[2][8];
  #pragma unroll
  for (int a = 0; a < 2; ++a)
    #pragma unroll
    for (int pt = 0; pt < 8; ++pt) acc[a][pt] = (float4v){0.f, 0.f, 0.f, 0.f};

  if (!is1x1) {
    // modconv0: input-hi only, weight hi+lo; 8 rounds x 64 ic
    for (int rnd = 0; rnd < 8; ++rnd) {
      __syncthreads();
      for (int idx = t; idx < 264 * 8; idx += 256) {
        int pos = idx >> 3, part = idx & 7;
        int srow = pos / 66;
        int scol = pos - srow * 66;
        int gy = r0 + srow - 1, gx = scol - 1;
        uint4v vh = {0u, 0u, 0u, 0u};
        if (gy >= 0 && gy < 64 && gx >= 0 && gx < 64)
          vh = *(const uint4v*)(sp_hi + ((size_t)b * HW + gy * 64 + gx) * ICSTRIDE
                                + rnd * 64 + part * 8);
        *(uint4v*)(lds + part * PS + pos * 8) = vh;
      }
      __syncthreads();

      #pragma unroll
      for (int sub = 0; sub < 2; ++sub) {
        const int icC = rnd * 2 + sub;
        #pragma unroll
        for (int dx = 0; dx < 3; ++dx) {
          short8v Ah[3][2], Al[3][2];
          #pragma unroll
          for (int dy = 0; dy < 3; ++dy) {
            #pragma unroll
            for (int a = 0; a < 2; ++a) {
              size_t wi = ((((size_t)(dy * 3 + dx) * OCT16) + (zl * 8 + wv * 2 + a)) * ICC + icC) * 64 + lane;
              Ah[dy][a] = *(const short8v*)(p0h + wi * 8);
              Al[dy][a] = *(const short8v*)(p0l + wi * 8);
            }
          }
          #pragma unroll
          for (int c0i = 0; c0i < 4; ++c0i) {
            #pragma unroll
            for (int sr = 0; sr < 4; ++sr) {
              int pix = sr * 66 + c0i * 16 + dx + l15;
              int addr = (sub * 4 + lg) * PS + pix * 8;
              short8v Bh = *(const short8v*)(lds + addr);
              #pragma unroll
              for (int dy = 0; dy < 3; ++dy) {
                int pt = sr - dy;
                if (pt < 0 || pt > 1) continue;  // compile-time
                int ptt = pt * 4 + c0i;
                acc[0][ptt] = __builtin_amdgcn_mfma_f32_16x16x32_bf16(Ah[dy][0], Bh, acc[0][ptt], 0, 0, 0);
                acc[1][ptt] = __builtin_amdgcn_mfma_f32_16x16x32_bf16(Ah[dy][1], Bh, acc[1][ptt], 0, 0, 0);
                acc[0][ptt] = __builtin_amdgcn_mfma_f32_16x16x32_bf16(Al[dy][0], Bh, acc[0][ptt], 0, 0, 0);
                acc[1][ptt] = __builtin_amdgcn_mfma_f32_16x16x32_bf16(Al[dy][1], Bh, acc[1][ptt], 0, 0, 0);
              }
            }
          }
        }
      }
    }
  } else {
    // 1x1: full split precision (3 MFMAs); 16 rounds x 32 ic; lo in parts 4-7
    for (int icC = 0; icC < ICC; ++icC) {
      __syncthreads();
      const int ic0 = icC * 32;
      for (int idx = t; idx < 132 * 4; idx += 256) {
        int pos = idx >> 2, part = idx & 3;
        int srow = pos / 66;
        int scol = pos - srow * 66;
        int gy = r0 + srow, gx = scol - 1;
        uint4v vh = {0u, 0u, 0u, 0u}, vl = {0u, 0u, 0u, 0u};
        if (gx >= 0 && gx < 64) {
          size_t g = ((size_t)b * HW + gy * 64 + gx) * ICSTRIDE + ic0 + part * 8;
          vh = *(const uint4v*)(sp2_hi + g);
          vl = *(const uint4v*)(sp2_lo + g);
        }
        *(uint4v*)(lds + part * PS + pos * 8) = vh;
        *(uint4v*)(lds + (part + 4) * PS + pos * 8) = vl;
      }
      __syncthreads();

      short8v Ah[2], Al[2];
      #pragma unroll
      for (int a = 0; a < 2; ++a) {
        size_t wi = (((size_t)(zl * 8 + wv * 2 + a)) * ICC + icC) * 64 + lane;
        Ah[a] = *(const short8v*)(psh + wi * 8);
        Al[a] = *(const short8v*)(psl + wi * 8);
      }
      #pragma unroll
      for (int pt = 0; pt < 8; ++pt) {
        int pix = (pt >> 2) * 66 + (pt & 3) * 16 + 1 + l15;
        short8v Bh = *(const short8v*)(lds + lg * PS + pix * 8);
        short8v Bl = *(const short8v*)(lds + (lg + 4) * PS + pix * 8);
        acc[0][pt] = __builtin_amdgcn_mfma_f32_16x16x32_bf16(Ah[0], Bh, acc[0][pt], 0, 0, 0);
        acc[1][pt] = __builtin_amdgcn_mfma_f32_16x16x32_bf16(Ah[1], Bh, acc[1][pt], 0, 0, 0);
        acc[0][pt] = __builtin_amdgcn_mfma_f32_16x16x32_bf16(Al[0], Bh, acc[0][pt], 0, 0, 0);
        acc[1][pt] = __builtin_amdgcn_mfma_f32_16x16x32_bf16(Al[1], Bh, acc[1][pt], 0, 0, 0);
        acc[0][pt] = __builtin_amdgcn_mfma_f32_16x16x32_bf16(Ah[0], Bl, acc[0][pt], 0, 0, 0);
        acc[1][pt] = __builtin_amdgcn_mfma_f32_16x16x32_bf16(Ah[1], Bl, acc[1][pt], 0, 0, 0);
      }
    }
  }

  const float* dscale = is1x1 ? dss : d0;
  float* outF = is1x1 ? outD : bufH;
  #pragma unroll
  for (int a = 0; a < 2; ++a) {
    int ocbase = zl * 128 + wv * 32 + a * 16 + lg * 4;
    float ds[4];
    #pragma unroll
    for (int r = 0; r < 4; ++r) ds[r] = dscale[b * 256 + ocbase + r];
    #pragma unroll
    for (int pt = 0; pt < 8; ++pt) {
      int px = (r0 + (pt >> 2)) * 64 + (pt & 3) * 16 + l15;
      #pragma unroll
      for (int r = 0; r < 4; ++r) {
        size_t oi = ((size_t)b * 256 + ocbase + r) * HW + px;
        outF[oi] = acc[a][pt][r] * ds[r];
      }
    }
  }
}

extern "C" void kernel_launch(void* const* d_in, const int* in_sizes, int n_in,
                              void* d_out, int out_size, void* d_ws, size_t ws_size,
                              hipStream_t stream) {
  const float* x     = (const float*)d_in[0];
  const float* seg   = (const float*)d_in[1];
  const float* style = (const float*)d_in[2];
  const float* n0_sw = (const float*)d_in[3];
  const float* n0_sb = (const float*)d_in[4];
  const float* n0_gw = (const float*)d_in[5];
  const float* n0_gb = (const float*)d_in[6];
  const float* n0_bw = (const float*)d_in[7];
  const float* n0_bb = (const float*)d_in[8];
  const float* n1_sw = (const float*)d_in[9];
  const float* n1_sb = (const float*)d_in[10];
  const float* n1_gw = (const float*)d_in[11];
  const float* n1_gb = (const float*)d_in[12];
  const float* n1_bw = (const float*)d_in[13];
  const float* n1_bb = (const float*)d_in[14];
  const float* ns_sw = (const float*)d_in[15];
  const float* ns_sb = (const float*)d_in[16];
  const float* ns_gw = (const float*)d_in[17];
  const float* ns_gb = (const float*)d_in[18];
  const float* ns_bw = (const float*)d_in[19];
  const float* ns_bb = (const float*)d_in[20];
  const float* w0  = (const float*)d_in[21];
  const float* m0w = (const float*)d_in[22];
  const float* m0b = (const float*)d_in[23];
  const float* w1  = (const float*)d_in[24];
  const float* m1w = (const float*)d_in[25];
  const float* m1b = (const float*)d_in[26];
  const float* wss = (const float*)d_in[27];
  const float* msw = (const float*)d_in[28];
  const float* msb = (const float*)d_in[29];
  float* out = (float*)d_out;

  char* p = (char*)d_ws;
  auto allocF = [&](size_t n) { float* r = (float*)p; p += n * 4; return r; };
  auto allocS = [&](size_t n) { short* r = (short*)p; p += n * 2; return r; };

  float* mu_x   = allocF(4096);
  float* rstd_x = allocF(4096);
  float* mu_h   = allocF(2048);
  float* rstd_h = allocF(2048);
  float* s0  = allocF(4096);
  float* s1  = allocF(2048);
  float* ss  = allocF(4096);
  float* d0  = allocF(2048);
  float* d1  = allocF(2048);
  float* dss = allocF(2048);
  float* wsq0 = allocF(256 * 512);
  float* wsq1 = allocF(256 * 256);
  float* wsqs = allocF(256 * 512);
  float* sb_cat = allocF(384);
  float* bufH = allocF((size_t)BN * 256 * HW);
  short* actv_hi = allocS((size_t)BN * HW * 384);
  short* segT = allocS((size_t)BN * HW * 64);
  short* sp_hi = allocS((size_t)BN * HW * 512);
  short* sp_lo = allocS((size_t)BN * HW * 512);
  short* sp2_hi = allocS((size_t)BN * HW * 512);
  short* sp2_lo = allocS((size_t)BN * HW * 512);
  short* p0h = allocS((size_t)256 * 512 * 9);
  short* p0l = allocS((size_t)256 * 512 * 9);
  short* p1h = allocS((size_t)256 * 256 * 9);
  short* p1l = allocS((size_t)256 * 256 * 9);
  short* psh = allocS((size_t)256 * 512);
  short* psl = allocS((size_t)256 * 512);
  short* pswh = allocS((size_t)9 * 24 * 2 * 64 * 8);
  short* pswl = allocS((size_t)9 * 24 * 2 * 64 * 8);
  short* pgsh = allocS((size_t)1024 * 128 * 9);
  short* pg0h = allocS((size_t)1024 * 128 * 9);
  short* pg1h = allocS((size_t)512 * 128 * 9);

  float cs0 = 1.0f / sqrtf(512.f * 9.f);
  float cs1 = 1.0f / sqrtf(256.f * 9.f);
  float css = 1.0f / sqrtf(512.f);

  // -------- small precompute (merged) --------
  stats_kernel<<<BN * 512, 256, 0, stream>>>(x, mu_x, rstd_x);
  modscale_all_kernel<<<40, 256, 0, stream>>>(style, m0w, m0b, m1w, m1b, msw, msb,
                                              s0, s1, ss);
  wsq_all_kernel<<<1280, 256, 0, stream>>>(w0, w1, wss, wsq0, wsq1, wsqs);
  demod_all_kernel<<<24, 256, 0, stream>>>(wsq0, s0, d0, wsq1, s1, d1, wsqs, ss, dss,
                                           cs0, cs1, css);

  // -------- seg transpose + bias concat --------
  seg_pack_kernel<<<(BN * HW) / 256, 256, 0, stream>>>(seg, segT);
  hipMemcpyAsync(sb_cat,       n0_sb, 128 * 4, hipMemcpyDeviceToDevice, stream);
  hipMemcpyAsync(sb_cat + 128, n1_sb, 128 * 4, hipMemcpyDeviceToDevice, stream);
  hipMemcpyAsync(sb_cat + 256, ns_sb, 128 * 4, hipMemcpyDeviceToDevice, stream);

  // -------- weight packing (merged; gb weights hi-only) --------
  pack_sw_kernel<<<108, 256, 0, stream>>>(n0_sw, n1_sw, ns_sw, pswh, pswl);
  pack_w_all_kernel<<<2368, 256, 0, stream>>>(
      w0, w1, wss, ns_gw, ns_bw, n0_gw, n0_bw, n1_gw, n1_bw,
      p0h, p0l, p1h, p1l, psh, psl, pgsh, pg0h, pg1h);

  // -------- all 3 seg convs via MFMA (MODE=2) --------
  conv_mfma_kernel<64, 64, 1, 2, 0, 0, 1><<<dim3(BN, 32, 3), 256, 0, stream>>>(
      segT, nullptr, pswh, pswl, nullptr, nullptr, nullptr, nullptr, sb_cat,
      nullptr, nullptr, nullptr, actv_hi, nullptr, 24, 384, 0, 0);

  // -------- dual GB (weight-hi only, 64-ic rounds, prefetched x): ns -> sp2, n0 -> sp --------
  conv_gb_dual_kernel<<<dim3(BN, 32, 16), 256, 0, stream>>>(
      actv_hi, pgsh, pg0h, x, mu_x, rstd_x,
      ns_gb, ns_bb, ss, n0_gb, n0_bb, s0, sp2_hi, sp2_lo, sp_hi, sp_lo);

  // -------- dual modconv (VGPR<=128): modconv0 (input-hi, 64-ic rounds) + 1x1 (full) --------
  conv_mc_dual_kernel<<<dim3(BN, 32, 4), 256, 0, stream>>>(
      sp_hi, sp_lo, p0h, p0l, d0, bufH,
      sp2_hi, sp2_lo, psh, psl, dss, out);

  // -------- spade_n1 over bufH (lrelu, weight-hi only, prefetched src) -> modconv1 (+= into d_out) --------
  stats_kernel<<<BN * 256, 256, 0, stream>>>(bufH, mu_h, rstd_h);
  conv_mfma_kernel<128, 384, 1, 1, 0, 0, 0><<<dim3(BN, 32, 4), 256, 0, stream>>>(
      actv_hi, nullptr, pg1h, nullptr, nullptr, bufH, mu_h, rstd_h, n1_gb, n1_bb, s1,
      nullptr, sp_hi, sp_lo, 32, 256, 128, 1);
  conv_mfma_kernel<256, 256, 1, 0, 1, 1, 1><<<dim3(BN, 32, 2), 256, 0, stream>>>(
      sp_hi, sp_lo, p1h, p1l, d1, nullptr, nullptr, nullptr, nullptr, nullptr,
      nullptr, out, nullptr, nullptr, 16, 0, 0, 0);
}

// Round 17
// 699.897 us; speedup vs baseline: 1.2250x; 1.1140x over previous
//
#include <hip/hip_runtime.h>
#include <math.h>

#define BN 8
#define HW 4096
#define NH 128
#define SNC 35
#define SD 512

typedef __attribute__((ext_vector_type(8))) short short8v;
typedef __attribute__((ext_vector_type(4))) short short4v;
typedef __attribute__((ext_vector_type(4))) float float4v;
typedef __attribute__((ext_vector_type(4))) unsigned int uint4v;

__device__ __forceinline__ short f2bf(float f) {
  unsigned u = __float_as_uint(f);
  unsigned r = (u + 0x7fffu + ((u >> 16) & 1u)) >> 16;
  return (short)r;
}
__device__ __forceinline__ float bf2f(short h) {
  return __uint_as_float(((unsigned)(unsigned short)h) << 16);
}

// ---------------- per-(b,c) instance-norm stats ----------------
__global__ __launch_bounds__(256) void stats_kernel(const float* __restrict__ x,
                                                    float* __restrict__ mu,
                                                    float* __restrict__ rstd) {
  int row = blockIdx.x;
  const float* p = x + (size_t)row * HW;
  float s = 0.f, s2 = 0.f;
  for (int i = threadIdx.x; i < HW; i += 256) {
    float v = p[i];
    s += v; s2 += v * v;
  }
  #pragma unroll
  for (int off = 32; off > 0; off >>= 1) {
    s  += __shfl_down(s, off);
    s2 += __shfl_down(s2, off);
  }
  __shared__ float as[4], as2[4];
  int wid = threadIdx.x >> 6;
  if ((threadIdx.x & 63) == 0) { as[wid] = s; as2[wid] = s2; }
  __syncthreads();
  if (threadIdx.x == 0) {
    float t  = as[0] + as[1] + as[2] + as[3];
    float t2 = as2[0] + as2[1] + as2[2] + as2[3];
    float m = t * (1.f / HW);
    float var = t2 * (1.f / HW) - m * m;
    mu[row] = m;
    rstd[row] = rsqrtf(var + 1e-5f);
  }
}

// ---------------- merged style modulation (3 segments) ----------------
__global__ __launch_bounds__(256) void modscale_all_kernel(
    const float* __restrict__ style,
    const float* __restrict__ m0w, const float* __restrict__ m0b,
    const float* __restrict__ m1w, const float* __restrict__ m1b,
    const float* __restrict__ msw, const float* __restrict__ msb,
    float* __restrict__ s0, float* __restrict__ s1, float* __restrict__ ss) {
  int idx = blockIdx.x * 256 + threadIdx.x;
  const float *mw, *mb; float* o; int I;
  if (idx < 4096) { mw = m0w; mb = m0b; o = s0; I = 512; }
  else if (idx < 6144) { idx -= 4096; mw = m1w; mb = m1b; o = s1; I = 256; }
  else if (idx < 10240) { idx -= 6144; mw = msw; mb = msb; o = ss; I = 512; }
  else return;
  int b = idx / I, i = idx - b * I;
  const float* st = style + (size_t)b * SD;
  const float* w  = mw + (size_t)i * SD;
  float acc = 0.f;
  for (int d = 0; d < SD; ++d) acc += st[d] * w[d];
  o[idx] = acc * 0.044194173824159216f + mb[i];
}

// ---------------- merged sum of w^2 (3 segments) ----------------
__global__ __launch_bounds__(256) void wsq_all_kernel(
    const float* __restrict__ w0, const float* __restrict__ w1,
    const float* __restrict__ wss,
    float* __restrict__ wsq0, float* __restrict__ wsq1, float* __restrict__ wsqs) {
  int idx = blockIdx.x * 256 + threadIdx.x;
  const float* w; float* o; int KK;
  if (idx < 131072) { w = w0; o = wsq0; KK = 9; }
  else if (idx < 196608) { idx -= 131072; w = w1; o = wsq1; KK = 9; }
  else if (idx < 327680) { idx -= 196608; w = wss; o = wsqs; KK = 1; }
  else return;
  const float* p = w + (size_t)idx * KK;
  float a = 0.f;
  for (int t = 0; t < KK; ++t) a += p[t] * p[t];
  o[idx] = a;
}

// ---------------- merged demod (3 segments) ----------------
__global__ __launch_bounds__(256) void demod_all_kernel(
    const float* __restrict__ wsq0, const float* __restrict__ s0, float* __restrict__ d0,
    const float* __restrict__ wsq1, const float* __restrict__ s1, float* __restrict__ d1,
    const float* __restrict__ wsqs, const float* __restrict__ ss, float* __restrict__ dss,
    float cs0, float cs1, float css) {
  int idx = blockIdx.x * 256 + threadIdx.x;
  const float *wsq, *s; float* dsc; int I; float cs;
  if (idx < 2048) { wsq = wsq0; s = s0; dsc = d0; I = 512; cs = cs0; }
  else if (idx < 4096) { idx -= 2048; wsq = wsq1; s = s1; dsc = d1; I = 256; cs = cs1; }
  else if (idx < 6144) { idx -= 4096; wsq = wsqs; s = ss; dsc = dss; I = 512; cs = css; }
  else return;
  int b = idx >> 8, o = idx & 255;
  const float* wr = wsq + (size_t)o * I;
  const float* sr = s + (size_t)b * I;
  float a = 0.f;
  for (int i = 0; i < I; ++i) { float sv = sr[i]; a += wr[i] * sv * sv; }
  dsc[idx] = rsqrtf(cs * cs * a + 1e-8f) * cs;
}

// ---------------- weight pack helper ----------------
__device__ __forceinline__ void pack_one(int tid, const float* __restrict__ wg,
                                         const float* __restrict__ wb,
                                         short* __restrict__ ph, short* __restrict__ pl,
                                         int OCtot, int IC, int KK, int interleave) {
  int ICC = IC / 32;
  int OCT16 = OCtot / 16;
  int lane = tid & 63;
  int r = tid >> 6;
  int icC = r % ICC; r /= ICC;
  int ocT = r % OCT16; int tap = r / OCT16;
  int po = ocT * 16 + (lane & 15);
  int ic0 = icC * 32 + (lane >> 4) * 8;
  const float* srcw;
  int oc;
  if (interleave) { oc = po >> 1; srcw = (po & 1) ? wb : wg; }
  else { oc = po; srcw = wg; }
  short8v hv, lv;
  #pragma unroll
  for (int j = 0; j < 8; ++j) {
    float v = srcw[((size_t)oc * IC + ic0 + j) * KK + tap];
    short h = f2bf(v);
    hv[j] = h;
    lv[j] = f2bf(v - bf2f(h));
  }
  size_t o = (size_t)tid * 8;
  *(short8v*)(ph + o) = hv;
  if (pl) *(short8v*)(pl + o) = lv;
}

// ---------------- merged weight packing: 6 segments ----------------
__global__ __launch_bounds__(256) void pack_w_all_kernel(
    const float* w0, const float* w1, const float* wss,
    const float* ns_gw, const float* ns_bw,
    const float* n0_gw, const float* n0_bw,
    const float* n1_gw, const float* n1_bw,
    short* p0h, short* p0l, short* p1h, short* p1l, short* psh, short* psl,
    short* pgsh, short* pg0h, short* pg1h) {
  int tid = blockIdx.x * 256 + threadIdx.x;
  if (tid < 147456) { pack_one(tid, w0, nullptr, p0h, p0l, 256, 512, 9, 0); return; }
  tid -= 147456;
  if (tid < 73728) { pack_one(tid, w1, nullptr, p1h, p1l, 256, 256, 9, 0); return; }
  tid -= 73728;
  if (tid < 16384) { pack_one(tid, wss, nullptr, psh, psl, 256, 512, 1, 0); return; }
  tid -= 16384;
  if (tid < 147456) { pack_one(tid, ns_gw, ns_bw, pgsh, nullptr, 1024, 128, 9, 1); return; }
  tid -= 147456;
  if (tid < 147456) { pack_one(tid, n0_gw, n0_bw, pg0h, nullptr, 1024, 128, 9, 1); return; }
  tid -= 147456;
  if (tid < 73728) pack_one(tid, n1_gw, n1_bw, pg1h, nullptr, 512, 128, 9, 1);
}

// ---------------- pack the 3 seg-conv weight sets: OCtot=384, IC 35 padded to 64 ----------------
__global__ __launch_bounds__(256) void pack_sw_kernel(const float* __restrict__ sw0,
                                                      const float* __restrict__ sw1,
                                                      const float* __restrict__ sw2,
                                                      short* __restrict__ ph,
                                                      short* __restrict__ pl) {
  int tid = blockIdx.x * 256 + threadIdx.x;
  const int ICC = 2, OCT16 = 24;
  int total = 9 * OCT16 * ICC * 64;
  if (tid >= total) return;
  int lane = tid & 63;
  int r = tid >> 6;
  int icC = r % ICC; r /= ICC;
  int ocT = r % OCT16; int tap = r / OCT16;
  int oc = ocT * 16 + (lane & 15);
  int ic0 = icC * 32 + (lane >> 4) * 8;
  const float* srcw = (oc < 128) ? sw0 : ((oc < 256) ? sw1 : sw2);
  int ocl = oc & 127;
  short8v hv, lv;
  #pragma unroll
  for (int j = 0; j < 8; ++j) {
    int ic = ic0 + j;
    float v = (ic < SNC) ? srcw[((size_t)ocl * SNC + ic) * 9 + tap] : 0.f;
    short h = f2bf(v);
    hv[j] = h;
    lv[j] = f2bf(v - bf2f(h));
  }
  size_t o = (size_t)tid * 8;
  *(short8v*)(ph + o) = hv;
  *(short8v*)(pl + o) = lv;
}

// ---------------- seg transpose: [B,35,HW] fp32 -> pixel-major bf16 [B*HW][64] (pad 0) ----------------
__global__ __launch_bounds__(256) void seg_pack_kernel(const float* __restrict__ seg,
                                                       short* __restrict__ segT) {
  int pix = blockIdx.x * 256 + threadIdx.x;
  int b = pix >> 12, px = pix & 4095;
  float v[64];
  #pragma unroll
  for (int ic = 0; ic < SNC; ++ic)
    v[ic] = seg[((size_t)b * SNC + ic) * HW + px];
  #pragma unroll
  for (int ic = SNC; ic < 64; ++ic) v[ic] = 0.f;
  size_t o = (size_t)pix * 64;
  #pragma unroll
  for (int k = 0; k < 8; ++k) {
    short8v h;
    #pragma unroll
    for (int j = 0; j < 8; ++j) h[j] = f2bf(v[k * 8 + j]);
    *(short8v*)(segT + o + k * 8) = h;
  }
}

// ---------------- MFMA split-precision implicit-GEMM conv (r10 NROW=2 structure) ----------------
template<int IC, int ICSTRIDE, int K3, int MODE, int ACCUM, int INLO, int WLO>
__global__ __launch_bounds__(256) void conv_mfma_kernel(
    const short* __restrict__ in_hi, const short* __restrict__ in_lo,
    const short* __restrict__ wp_hi, const short* __restrict__ wp_lo,
    const float* __restrict__ dscale,
    const float* __restrict__ src, const float* __restrict__ mu,
    const float* __restrict__ rstd, const float* __restrict__ gbias,
    const float* __restrict__ bbias, const float* __restrict__ sscale,
    float* __restrict__ outF, short* __restrict__ out_hi,
    short* __restrict__ out_lo, int OCT16, int C, int icbase, int lrelu) {
  const int b = blockIdx.x;
  const int r0 = blockIdx.y * 2;
  const int zl = blockIdx.z;
  const int t = threadIdx.x;
  const int wv = t >> 6;
  const int lane = t & 63;
  const int l15 = lane & 15, lg = lane >> 4;
  const int ICC = IC / 32;
  const int PS = 2128;

  __shared__ __align__(16) short lds_hi[4 * 2128];
  __shared__ __align__(16) short lds_lo[INLO ? 4 * 2128 : 8];

  float pre[2][2][8];
  if (MODE == 1) {
    #pragma unroll
    for (int a = 0; a < 2; ++a) {
      int base = zl * 128 + wv * 32 + a * 16 + lg * 4;
      int cA = base >> 1, cB = cA + 1;
      const float* srcA = src + ((size_t)b * C + cA) * HW;
      const float* srcB = src + ((size_t)b * C + cB) * HW;
      #pragma unroll
      for (int pt = 0; pt < 8; ++pt) {
        int px = (r0 + (pt >> 2)) * 64 + (pt & 3) * 16 + l15;
        pre[a][0][pt] = srcA[px];
        pre[a][1][pt] = srcB[px];
      }
    }
  }

  float4v acc[2][8];
  #pragma unroll
  for (int a = 0; a < 2; ++a)
    #pragma unroll
    for (int pt = 0; pt < 8; ++pt) acc[a][pt] = (float4v){0.f, 0.f, 0.f, 0.f};

  for (int icC = 0; icC < ICC; ++icC) {
    __syncthreads();
    const int ic0 = icC * 32;
    for (int idx = t; idx < 264 * 4; idx += 256) {
      int pos = idx >> 2, part = idx & 3;
      int srow = pos / 66;
      int scol = pos - srow * 66;
      int gy = r0 + srow - 1, gx = scol - 1;
      uint4v vh = {0u, 0u, 0u, 0u}, vl = {0u, 0u, 0u, 0u};
      bool ok = (gy >= 0 && gy < 64 && gx >= 0 && gx < 64);
      if (!K3) ok = ok && (srow >= 1 && srow <= 2);
      if (ok) {
        size_t g = ((size_t)b * HW + gy * 64 + gx) * ICSTRIDE + icbase + ic0 + part * 8;
        vh = *(const uint4v*)(in_hi + g);
        if (INLO) vl = *(const uint4v*)(in_lo + g);
      }
      int lo = part * PS + pos * 8;
      *(uint4v*)(lds_hi + lo) = vh;
      if (INLO) *(uint4v*)(lds_lo + lo) = vl;
    }
    __syncthreads();

    if (K3) {
      #pragma unroll
      for (int dx = 0; dx < 3; ++dx) {
        short8v Ah[3][2], Al[3][2];
        #pragma unroll
        for (int dy = 0; dy < 3; ++dy) {
          #pragma unroll
          for (int a = 0; a < 2; ++a) {
            size_t wi = ((((size_t)(dy * 3 + dx) * OCT16) + (zl * 8 + wv * 2 + a)) * ICC + icC) * 64 + lane;
            Ah[dy][a] = *(const short8v*)(wp_hi + wi * 8);
            if (WLO) Al[dy][a] = *(const short8v*)(wp_lo + wi * 8);
          }
        }
        #pragma unroll
        for (int c0i = 0; c0i < 4; ++c0i) {
          #pragma unroll
          for (int sr = 0; sr < 4; ++sr) {
            int pix = sr * 66 + c0i * 16 + dx + l15;
            int addr = lg * PS + pix * 8;
            short8v Bh = *(const short8v*)(lds_hi + addr);
            #pragma unroll
            for (int dy = 0; dy < 3; ++dy) {
              int pt = sr - dy;
              if (pt < 0 || pt > 1) continue;  // compile-time
              int ptt = pt * 4 + c0i;
              acc[0][ptt] = __builtin_amdgcn_mfma_f32_16x16x32_bf16(Ah[dy][0], Bh, acc[0][ptt], 0, 0, 0);
              acc[1][ptt] = __builtin_amdgcn_mfma_f32_16x16x32_bf16(Ah[dy][1], Bh, acc[1][ptt], 0, 0, 0);
              if (WLO) {
                acc[0][ptt] = __builtin_amdgcn_mfma_f32_16x16x32_bf16(Al[dy][0], Bh, acc[0][ptt], 0, 0, 0);
                acc[1][ptt] = __builtin_amdgcn_mfma_f32_16x16x32_bf16(Al[dy][1], Bh, acc[1][ptt], 0, 0, 0);
              }
            }
            if (INLO) {
              short8v Bl = *(const short8v*)(lds_lo + addr);
              #pragma unroll
              for (int dy = 0; dy < 3; ++dy) {
                int pt = sr - dy;
                if (pt < 0 || pt > 1) continue;
                int ptt = pt * 4 + c0i;
                acc[0][ptt] = __builtin_amdgcn_mfma_f32_16x16x32_bf16(Ah[dy][0], Bl, acc[0][ptt], 0, 0, 0);
                acc[1][ptt] = __builtin_amdgcn_mfma_f32_16x16x32_bf16(Ah[dy][1], Bl, acc[1][ptt], 0, 0, 0);
              }
            }
          }
        }
      }
    } else {
      short8v Ah[2], Al[2];
      #pragma unroll
      for (int a = 0; a < 2; ++a) {
        size_t wi = (((size_t)(zl * 8 + wv * 2 + a)) * ICC + icC) * 64 + lane;
        Ah[a] = *(const short8v*)(wp_hi + wi * 8);
        if (WLO) Al[a] = *(const short8v*)(wp_lo + wi * 8);
      }
      #pragma unroll
      for (int pt = 0; pt < 8; ++pt) {
        int pix = ((pt >> 2) + 1) * 66 + (pt & 3) * 16 + 1 + l15;
        int addr = lg * PS + pix * 8;
        short8v Bh = *(const short8v*)(lds_hi + addr);
        acc[0][pt] = __builtin_amdgcn_mfma_f32_16x16x32_bf16(Ah[0], Bh, acc[0][pt], 0, 0, 0);
        acc[1][pt] = __builtin_amdgcn_mfma_f32_16x16x32_bf16(Ah[1], Bh, acc[1][pt], 0, 0, 0);
        if (WLO) {
          acc[0][pt] = __builtin_amdgcn_mfma_f32_16x16x32_bf16(Al[0], Bh, acc[0][pt], 0, 0, 0);
          acc[1][pt] = __builtin_amdgcn_mfma_f32_16x16x32_bf16(Al[1], Bh, acc[1][pt], 0, 0, 0);
        }
        if (INLO) {
          short8v Bl = *(const short8v*)(lds_lo + addr);
          acc[0][pt] = __builtin_amdgcn_mfma_f32_16x16x32_bf16(Ah[0], Bl, acc[0][pt], 0, 0, 0);
          acc[1][pt] = __builtin_amdgcn_mfma_f32_16x16x32_bf16(Ah[1], Bl, acc[1][pt], 0, 0, 0);
        }
      }
    }
  }

  if (MODE == 1) {
    #pragma unroll
    for (int a = 0; a < 2; ++a) {
      int base = zl * 128 + wv * 32 + a * 16 + lg * 4;
      int cA = base >> 1;
      int cB = cA + 1;
      float muA = mu[b * C + cA], rsA = rstd[b * C + cA];
      float gbA = gbias[cA], bbA = bbias[cA], sA = sscale[b * C + cA];
      float muB = mu[b * C + cB], rsB = rstd[b * C + cB];
      float gbB = gbias[cB], bbB = bbias[cB], sB = sscale[b * C + cB];
      #pragma unroll
      for (int pt = 0; pt < 8; ++pt) {
        int px = (r0 + (pt >> 2)) * 64 + (pt & 3) * 16 + l15;
        float nvA = (pre[a][0][pt] - muA) * rsA;
        float vA = nvA * (1.f + acc[a][pt][0] + gbA) + acc[a][pt][1] + bbA;
        if (lrelu) vA = (vA >= 0.f) ? vA : 0.2f * vA;
        vA *= sA;
        float nvB = (pre[a][1][pt] - muB) * rsB;
        float vB = nvB * (1.f + acc[a][pt][2] + gbB) + acc[a][pt][3] + bbB;
        if (lrelu) vB = (vB >= 0.f) ? vB : 0.2f * vB;
        vB *= sB;
        short hA = f2bf(vA), hB = f2bf(vB);
        short lA = f2bf(vA - bf2f(hA)), lB = f2bf(vB - bf2f(hB));
        size_t o = ((size_t)b * HW + px) * C + cA;
        *(unsigned*)(out_hi + o) =
            (unsigned)(unsigned short)hA | ((unsigned)(unsigned short)hB << 16);
        *(unsigned*)(out_lo + o) =
            (unsigned)(unsigned short)lA | ((unsigned)(unsigned short)lB << 16);
      }
    }
  } else if (MODE == 2) {
    #pragma unroll
    for (int a = 0; a < 2; ++a) {
      int ocbase = zl * 128 + wv * 32 + a * 16 + lg * 4;
      float bs[4];
      #pragma unroll
      for (int r = 0; r < 4; ++r) bs[r] = gbias[ocbase + r];
      #pragma unroll
      for (int pt = 0; pt < 8; ++pt) {
        int px = (r0 + (pt >> 2)) * 64 + (pt & 3) * 16 + l15;
        short4v hs;
        #pragma unroll
        for (int r = 0; r < 4; ++r)
          hs[r] = f2bf(fmaxf(acc[a][pt][r] + bs[r], 0.f));
        *(short4v*)(out_hi + ((size_t)b * HW + px) * C + ocbase) = hs;
      }
    }
  } else {
    #pragma unroll
    for (int a = 0; a < 2; ++a) {
      int ocbase = zl * 128 + wv * 32 + a * 16 + lg * 4;
      float ds[4];
      #pragma unroll
      for (int r = 0; r < 4; ++r) ds[r] = dscale[b * 256 + ocbase + r];
      #pragma unroll
      for (int pt = 0; pt < 8; ++pt) {
        int px = (r0 + (pt >> 2)) * 64 + (pt & 3) * 16 + l15;
        #pragma unroll
        for (int r = 0; r < 4; ++r) {
          size_t oi = ((size_t)b * 256 + ocbase + r) * HW + px;
          float v = acc[a][pt][r] * ds[r];
          if (ACCUM) v += outF[oi];
          outF[oi] = v;
        }
      }
    }
  }
}

// ---------------- dual GB conv (weight-hi only, hi-only outputs, single staging round) ----------------
// z<8 = ns -> sp2_hi, z>=8 = n0 -> sp_hi. All 128 ic staged once (16 parts, 68KB LDS);
// one barrier pair per block. Epilogue x reads prefetched.
__global__ __launch_bounds__(256) void conv_gb_dual_kernel(
    const short* __restrict__ actv_hi,
    const short* __restrict__ pgsh, const short* __restrict__ pg0h,
    const float* __restrict__ x, const float* __restrict__ mu,
    const float* __restrict__ rstd,
    const float* __restrict__ ns_gb, const float* __restrict__ ns_bb,
    const float* __restrict__ ss,
    const float* __restrict__ n0_gb, const float* __restrict__ n0_bb,
    const float* __restrict__ s0,
    short* __restrict__ sp2_hi, short* __restrict__ sp_hi) {
  const int b = blockIdx.x;
  const int r0 = blockIdx.y * 2;
  const int zz = blockIdx.z;
  const bool isN0 = zz >= 8;
  const int zl = zz & 7;
  const short* wph = isN0 ? pg0h : pgsh;
  const float* gbias = isN0 ? n0_gb : ns_gb;
  const float* bbias = isN0 ? n0_bb : ns_bb;
  const float* sscale = isN0 ? s0 : ss;
  short* out_hi = isN0 ? sp_hi : sp2_hi;
  const int icbase = isN0 ? 0 : 256;
  const int lrelu = isN0 ? 1 : 0;
  const int OCT16 = 64, C = 512, ICC = 4, ICSTRIDE = 384;

  const int t = threadIdx.x;
  const int wv = t >> 6;
  const int lane = t & 63;
  const int l15 = lane & 15, lg = lane >> 4;
  const int PS = 2128;

  __shared__ __align__(16) short lds_hi[16 * 2128];

  float pre[2][2][8];
  #pragma unroll
  for (int a = 0; a < 2; ++a) {
    int base = zl * 128 + wv * 32 + a * 16 + lg * 4;
    int cA = base >> 1, cB = cA + 1;
    const float* srcA = x + ((size_t)b * C + cA) * HW;
    const float* srcB = x + ((size_t)b * C + cB) * HW;
    #pragma unroll
    for (int pt = 0; pt < 8; ++pt) {
      int px = (r0 + (pt >> 2)) * 64 + (pt & 3) * 16 + l15;
      pre[a][0][pt] = srcA[px];
      pre[a][1][pt] = srcB[px];
    }
  }

  float4v acc[2][8];
  #pragma unroll
  for (int a = 0; a < 2; ++a)
    #pragma unroll
    for (int pt = 0; pt < 8; ++pt) acc[a][pt] = (float4v){0.f, 0.f, 0.f, 0.f};

  // single staging round: all 128 ic
  for (int idx = t; idx < 264 * 16; idx += 256) {
    int pos = idx >> 4, part = idx & 15;
    int srow = pos / 66;
    int scol = pos - srow * 66;
    int gy = r0 + srow - 1, gx = scol - 1;
    uint4v vh = {0u, 0u, 0u, 0u};
    if (gy >= 0 && gy < 64 && gx >= 0 && gx < 64)
      vh = *(const uint4v*)(actv_hi + ((size_t)b * HW + gy * 64 + gx) * ICSTRIDE
                            + icbase + part * 8);
    *(uint4v*)(lds_hi + part * PS + pos * 8) = vh;
  }
  __syncthreads();

  #pragma unroll
  for (int icC = 0; icC < 4; ++icC) {
    #pragma unroll
    for (int dx = 0; dx < 3; ++dx) {
      short8v Ah[3][2];
      #pragma unroll
      for (int dy = 0; dy < 3; ++dy) {
        #pragma unroll
        for (int a = 0; a < 2; ++a) {
          size_t wi = ((((size_t)(dy * 3 + dx) * OCT16) + (zl * 8 + wv * 2 + a)) * ICC + icC) * 64 + lane;
          Ah[dy][a] = *(const short8v*)(wph + wi * 8);
        }
      }
      #pragma unroll
      for (int c0i = 0; c0i < 4; ++c0i) {
        #pragma unroll
        for (int sr = 0; sr < 4; ++sr) {
          int pix = sr * 66 + c0i * 16 + dx + l15;
          int addr = (icC * 4 + lg) * PS + pix * 8;
          short8v Bh = *(const short8v*)(lds_hi + addr);
          #pragma unroll
          for (int dy = 0; dy < 3; ++dy) {
            int pt = sr - dy;
            if (pt < 0 || pt > 1) continue;  // compile-time
            int ptt = pt * 4 + c0i;
            acc[0][ptt] = __builtin_amdgcn_mfma_f32_16x16x32_bf16(Ah[dy][0], Bh, acc[0][ptt], 0, 0, 0);
            acc[1][ptt] = __builtin_amdgcn_mfma_f32_16x16x32_bf16(Ah[dy][1], Bh, acc[1][ptt], 0, 0, 0);
          }
        }
      }
    }
  }

  #pragma unroll
  for (int a = 0; a < 2; ++a) {
    int base = zl * 128 + wv * 32 + a * 16 + lg * 4;
    int cA = base >> 1;
    int cB = cA + 1;
    float muA = mu[b * C + cA], rsA = rstd[b * C + cA];
    float gbA = gbias[cA], bbA = bbias[cA], sA = sscale[b * C + cA];
    float muB = mu[b * C + cB], rsB = rstd[b * C + cB];
    float gbB = gbias[cB], bbB = bbias[cB], sB = sscale[b * C + cB];
    #pragma unroll
    for (int pt = 0; pt < 8; ++pt) {
      int px = (r0 + (pt >> 2)) * 64 + (pt & 3) * 16 + l15;
      float nvA = (pre[a][0][pt] - muA) * rsA;
      float vA = nvA * (1.f + acc[a][pt][0] + gbA) + acc[a][pt][1] + bbA;
      if (lrelu) vA = (vA >= 0.f) ? vA : 0.2f * vA;
      vA *= sA;
      float nvB = (pre[a][1][pt] - muB) * rsB;
      float vB = nvB * (1.f + acc[a][pt][2] + gbB) + acc[a][pt][3] + bbB;
      if (lrelu) vB = (vB >= 0.f) ? vB : 0.2f * vB;
      vB *= sB;
      short hA = f2bf(vA), hB = f2bf(vB);
      size_t o = ((size_t)b * HW + px) * C + cA;
      *(unsigned*)(out_hi + o) =
          (unsigned)(unsigned short)hA | ((unsigned)(unsigned short)hB << 16);
    }
  }
}

// ---------------- dual modconv, VGPR-capped: z<2 = modconv0 (3x3, input-hi, 64-ic rounds),
// z>=2 = 1x1 (input-hi, weight hi+lo). ----------------
__global__ __launch_bounds__(256, 4) void conv_mc_dual_kernel(
    const short* __restrict__ sp_hi,
    const short* __restrict__ p0h, const short* __restrict__ p0l,
    const float* __restrict__ d0, float* __restrict__ bufH,
    const short* __restrict__ sp2_hi,
    const short* __restrict__ psh, const short* __restrict__ psl,
    const float* __restrict__ dss, float* __restrict__ outD) {
  const int b = blockIdx.x;
  const int r0 = blockIdx.y * 2;
  const int zz = blockIdx.z;
  const bool is1x1 = zz >= 2;
  const int zl = zz & 1;
  const int OCT16 = 16, ICC = 16, ICSTRIDE = 512;

  const int t = threadIdx.x;
  const int wv = t >> 6;
  const int lane = t & 63;
  const int l15 = lane & 15, lg = lane >> 4;
  const int PS = 2128;

  __shared__ __align__(16) short lds[8 * 2128];

  float4v acc[2][8];
  #pragma unroll
  for (int a = 0; a < 2; ++a)
    #pragma unroll
    for (int pt = 0; pt < 8; ++pt) acc[a][pt] = (float4v){0.f, 0.f, 0.f, 0.f};

  if (!is1x1) {
    // modconv0: input-hi only, weight hi+lo; 8 rounds x 64 ic
    for (int rnd = 0; rnd < 8; ++rnd) {
      __syncthreads();
      for (int idx = t; idx < 264 * 8; idx += 256) {
        int pos = idx >> 3, part = idx & 7;
        int srow = pos / 66;
        int scol = pos - srow * 66;
        int gy = r0 + srow - 1, gx = scol - 1;
        uint4v vh = {0u, 0u, 0u, 0u};
        if (gy >= 0 && gy < 64 && gx >= 0 && gx < 64)
          vh = *(const uint4v*)(sp_hi + ((size_t)b * HW + gy * 64 + gx) * ICSTRIDE
                                + rnd * 64 + part * 8);
        *(uint4v*)(lds + part * PS + pos * 8) = vh;
      }
      __syncthreads();

      #pragma unroll
      for (int sub = 0; sub < 2; ++sub) {
        const int icC = rnd * 2 + sub;
        #pragma unroll
        for (int dx = 0; dx < 3; ++dx) {
          short8v Ah[3][2], Al[3][2];
          #pragma unroll
          for (int dy = 0; dy < 3; ++dy) {
            #pragma unroll
            for (int a = 0; a < 2; ++a) {
              size_t wi = ((((size_t)(dy * 3 + dx) * OCT16) + (zl * 8 + wv * 2 + a)) * ICC + icC) * 64 + lane;
              Ah[dy][a] = *(const short8v*)(p0h + wi * 8);
              Al[dy][a] = *(const short8v*)(p0l + wi * 8);
            }
          }
          #pragma unroll
          for (int c0i = 0; c0i < 4; ++c0i) {
            #pragma unroll
            for (int sr = 0; sr < 4; ++sr) {
              int pix = sr * 66 + c0i * 16 + dx + l15;
              int addr = (sub * 4 + lg) * PS + pix * 8;
              short8v Bh = *(const short8v*)(lds + addr);
              #pragma unroll
              for (int dy = 0; dy < 3; ++dy) {
                int pt = sr - dy;
                if (pt < 0 || pt > 1) continue;  // compile-time
                int ptt = pt * 4 + c0i;
                acc[0][ptt] = __builtin_amdgcn_mfma_f32_16x16x32_bf16(Ah[dy][0], Bh, acc[0][ptt], 0, 0, 0);
                acc[1][ptt] = __builtin_amdgcn_mfma_f32_16x16x32_bf16(Ah[dy][1], Bh, acc[1][ptt], 0, 0, 0);
                acc[0][ptt] = __builtin_amdgcn_mfma_f32_16x16x32_bf16(Al[dy][0], Bh, acc[0][ptt], 0, 0, 0);
                acc[1][ptt] = __builtin_amdgcn_mfma_f32_16x16x32_bf16(Al[dy][1], Bh, acc[1][ptt], 0, 0, 0);
              }
            }
          }
        }
      }
    }
  } else {
    // 1x1: input-hi, weight hi+lo (2 MFMAs); 16 rounds x 32 ic
    for (int icC = 0; icC < ICC; ++icC) {
      __syncthreads();
      const int ic0 = icC * 32;
      for (int idx = t; idx < 132 * 4; idx += 256) {
        int pos = idx >> 2, part = idx & 3;
        int srow = pos / 66;
        int scol = pos - srow * 66;
        int gy = r0 + srow, gx = scol - 1;
        uint4v vh = {0u, 0u, 0u, 0u};
        if (gx >= 0 && gx < 64)
          vh = *(const uint4v*)(sp2_hi + ((size_t)b * HW + gy * 64 + gx) * ICSTRIDE + ic0 + part * 8);
        *(uint4v*)(lds + part * PS + pos * 8) = vh;
      }
      __syncthreads();

      short8v Ah[2], Al[2];
      #pragma unroll
      for (int a = 0; a < 2; ++a) {
        size_t wi = (((size_t)(zl * 8 + wv * 2 + a)) * ICC + icC) * 64 + lane;
        Ah[a] = *(const short8v*)(psh + wi * 8);
        Al[a] = *(const short8v*)(psl + wi * 8);
      }
      #pragma unroll
      for (int pt = 0; pt < 8; ++pt) {
        int pix = (pt >> 2) * 66 + (pt & 3) * 16 + 1 + l15;
        short8v Bh = *(const short8v*)(lds + lg * PS + pix * 8);
        acc[0][pt] = __builtin_amdgcn_mfma_f32_16x16x32_bf16(Ah[0], Bh, acc[0][pt], 0, 0, 0);
        acc[1][pt] = __builtin_amdgcn_mfma_f32_16x16x32_bf16(Ah[1], Bh, acc[1][pt], 0, 0, 0);
        acc[0][pt] = __builtin_amdgcn_mfma_f32_16x16x32_bf16(Al[0], Bh, acc[0][pt], 0, 0, 0);
        acc[1][pt] = __builtin_amdgcn_mfma_f32_16x16x32_bf16(Al[1], Bh, acc[1][pt], 0, 0, 0);
      }
    }
  }

  const float* dscale = is1x1 ? dss : d0;
  float* outF = is1x1 ? outD : bufH;
  #pragma unroll
  for (int a = 0; a < 2; ++a) {
    int ocbase = zl * 128 + wv * 32 + a * 16 + lg * 4;
    float ds[4];
    #pragma unroll
    for (int r = 0; r < 4; ++r) ds[r] = dscale[b * 256 + ocbase + r];
    #pragma unroll
    for (int pt = 0; pt < 8; ++pt) {
      int px = (r0 + (pt >> 2)) * 64 + (pt & 3) * 16 + l15;
      #pragma unroll
      for (int r = 0; r < 4; ++r) {
        size_t oi = ((size_t)b * 256 + ocbase + r) * HW + px;
        outF[oi] = acc[a][pt][r] * ds[r];
      }
    }
  }
}

extern "C" void kernel_launch(void* const* d_in, const int* in_sizes, int n_in,
                              void* d_out, int out_size, void* d_ws, size_t ws_size,
                              hipStream_t stream) {
  const float* x     = (const float*)d_in[0];
  const float* seg   = (const float*)d_in[1];
  const float* style = (const float*)d_in[2];
  const float* n0_sw = (const float*)d_in[3];
  const float* n0_sb = (const float*)d_in[4];
  const float* n0_gw = (const float*)d_in[5];
  const float* n0_gb = (const float*)d_in[6];
  const float* n0_bw = (const float*)d_in[7];
  const float* n0_bb = (const float*)d_in[8];
  const float* n1_sw = (const float*)d_in[9];
  const float* n1_sb = (const float*)d_in[10];
  const float* n1_gw = (const float*)d_in[11];
  const float* n1_gb = (const float*)d_in[12];
  const float* n1_bw = (const float*)d_in[13];
  const float* n1_bb = (const float*)d_in[14];
  const float* ns_sw = (const float*)d_in[15];
  const float* ns_sb = (const float*)d_in[16];
  const float* ns_gw = (const float*)d_in[17];
  const float* ns_gb = (const float*)d_in[18];
  const float* ns_bw = (const float*)d_in[19];
  const float* ns_bb = (const float*)d_in[20];
  const float* w0  = (const float*)d_in[21];
  const float* m0w = (const float*)d_in[22];
  const float* m0b = (const float*)d_in[23];
  const float* w1  = (const float*)d_in[24];
  const float* m1w = (const float*)d_in[25];
  const float* m1b = (const float*)d_in[26];
  const float* wss = (const float*)d_in[27];
  const float* msw = (const float*)d_in[28];
  const float* msb = (const float*)d_in[29];
  float* out = (float*)d_out;

  char* p = (char*)d_ws;
  auto allocF = [&](size_t n) { float* r = (float*)p; p += n * 4; return r; };
  auto allocS = [&](size_t n) { short* r = (short*)p; p += n * 2; return r; };

  float* mu_x   = allocF(4096);
  float* rstd_x = allocF(4096);
  float* mu_h   = allocF(2048);
  float* rstd_h = allocF(2048);
  float* s0  = allocF(4096);
  float* s1  = allocF(2048);
  float* ss  = allocF(4096);
  float* d0  = allocF(2048);
  float* d1  = allocF(2048);
  float* dss = allocF(2048);
  float* wsq0 = allocF(256 * 512);
  float* wsq1 = allocF(256 * 256);
  float* wsqs = allocF(256 * 512);
  float* sb_cat = allocF(384);
  float* bufH = allocF((size_t)BN * 256 * HW);
  short* actv_hi = allocS((size_t)BN * HW * 384);
  short* segT = allocS((size_t)BN * HW * 64);
  short* sp_hi = allocS((size_t)BN * HW * 512);
  short* sp_lo = allocS((size_t)BN * HW * 512);
  short* sp2_hi = allocS((size_t)BN * HW * 512);
  short* p0h = allocS((size_t)256 * 512 * 9);
  short* p0l = allocS((size_t)256 * 512 * 9);
  short* p1h = allocS((size_t)256 * 256 * 9);
  short* p1l = allocS((size_t)256 * 256 * 9);
  short* psh = allocS((size_t)256 * 512);
  short* psl = allocS((size_t)256 * 512);
  short* pswh = allocS((size_t)9 * 24 * 2 * 64 * 8);
  short* pswl = allocS((size_t)9 * 24 * 2 * 64 * 8);
  short* pgsh = allocS((size_t)1024 * 128 * 9);
  short* pg0h = allocS((size_t)1024 * 128 * 9);
  short* pg1h = allocS((size_t)512 * 128 * 9);

  float cs0 = 1.0f / sqrtf(512.f * 9.f);
  float cs1 = 1.0f / sqrtf(256.f * 9.f);
  float css = 1.0f / sqrtf(512.f);

  // -------- small precompute (merged) --------
  stats_kernel<<<BN * 512, 256, 0, stream>>>(x, mu_x, rstd_x);
  modscale_all_kernel<<<40, 256, 0, stream>>>(style, m0w, m0b, m1w, m1b, msw, msb,
                                              s0, s1, ss);
  wsq_all_kernel<<<1280, 256, 0, stream>>>(w0, w1, wss, wsq0, wsq1, wsqs);
  demod_all_kernel<<<24, 256, 0, stream>>>(wsq0, s0, d0, wsq1, s1, d1, wsqs, ss, dss,
                                           cs0, cs1, css);

  // -------- seg transpose + bias concat --------
  seg_pack_kernel<<<(BN * HW) / 256, 256, 0, stream>>>(seg, segT);
  hipMemcpyAsync(sb_cat,       n0_sb, 128 * 4, hipMemcpyDeviceToDevice, stream);
  hipMemcpyAsync(sb_cat + 128, n1_sb, 128 * 4, hipMemcpyDeviceToDevice, stream);
  hipMemcpyAsync(sb_cat + 256, ns_sb, 128 * 4, hipMemcpyDeviceToDevice, stream);

  // -------- weight packing (merged; gb weights hi-only) --------
  pack_sw_kernel<<<108, 256, 0, stream>>>(n0_sw, n1_sw, ns_sw, pswh, pswl);
  pack_w_all_kernel<<<2368, 256, 0, stream>>>(
      w0, w1, wss, ns_gw, ns_bw, n0_gw, n0_bw, n1_gw, n1_bw,
      p0h, p0l, p1h, p1l, psh, psl, pgsh, pg0h, pg1h);

  // -------- all 3 seg convs via MFMA (MODE=2) --------
  conv_mfma_kernel<64, 64, 1, 2, 0, 0, 1><<<dim3(BN, 32, 3), 256, 0, stream>>>(
      segT, nullptr, pswh, pswl, nullptr, nullptr, nullptr, nullptr, sb_cat,
      nullptr, nullptr, nullptr, actv_hi, nullptr, 24, 384, 0, 0);

  // -------- dual GB (hi-only out, single staging round): ns -> sp2_hi, n0 -> sp_hi --------
  conv_gb_dual_kernel<<<dim3(BN, 32, 16), 256, 0, stream>>>(
      actv_hi, pgsh, pg0h, x, mu_x, rstd_x,
      ns_gb, ns_bb, ss, n0_gb, n0_bb, s0, sp2_hi, sp_hi);

  // -------- dual modconv (VGPR<=128): modconv0 (input-hi) + 1x1 (input-hi) --------
  conv_mc_dual_kernel<<<dim3(BN, 32, 4), 256, 0, stream>>>(
      sp_hi, p0h, p0l, d0, bufH,
      sp2_hi, psh, psl, dss, out);

  // -------- spade_n1 over bufH (lrelu, weight-hi only, prefetched src) -> modconv1 (+= into d_out) --------
  stats_kernel<<<BN * 256, 256, 0, stream>>>(bufH, mu_h, rstd_h);
  conv_mfma_kernel<128, 384, 1, 1, 0, 0, 0><<<dim3(BN, 32, 4), 256, 0, stream>>>(
      actv_hi, nullptr, pg1h, nullptr, nullptr, bufH, mu_h, rstd_h, n1_gb, n1_bb, s1,
      nullptr, sp_hi, sp_lo, 32, 256, 128, 1);
  conv_mfma_kernel<256, 256, 1, 0, 1, 1, 1><<<dim3(BN, 32, 2), 256, 0, stream>>>(
      sp_hi, sp_lo, p1h, p1l, d1, nullptr, nullptr, nullptr, nullptr, nullptr,
      nullptr, out, nullptr, nullptr, 16, 0, 0, 0);
}

// Round 18
// 607.004 us; speedup vs baseline: 1.4125x; 1.1530x over previous
//
#include <hip/hip_runtime.h>
#include <math.h>

#define BN 8
#define HW 4096
#define NH 128
#define SNC 35
#define SD 512

typedef __attribute__((ext_vector_type(8))) short short8v;
typedef __attribute__((ext_vector_type(4))) short short4v;
typedef __attribute__((ext_vector_type(4))) float float4v;
typedef __attribute__((ext_vector_type(4))) unsigned int uint4v;

__device__ __forceinline__ short f2bf(float f) {
  unsigned u = __float_as_uint(f);
  unsigned r = (u + 0x7fffu + ((u >> 16) & 1u)) >> 16;
  return (short)r;
}
__device__ __forceinline__ float bf2f(short h) {
  return __uint_as_float(((unsigned)(unsigned short)h) << 16);
}

// ---------------- per-(b,c) instance-norm stats ----------------
__global__ __launch_bounds__(256) void stats_kernel(const float* __restrict__ x,
                                                    float* __restrict__ mu,
                                                    float* __restrict__ rstd) {
  int row = blockIdx.x;
  const float* p = x + (size_t)row * HW;
  float s = 0.f, s2 = 0.f;
  for (int i = threadIdx.x; i < HW; i += 256) {
    float v = p[i];
    s += v; s2 += v * v;
  }
  #pragma unroll
  for (int off = 32; off > 0; off >>= 1) {
    s  += __shfl_down(s, off);
    s2 += __shfl_down(s2, off);
  }
  __shared__ float as[4], as2[4];
  int wid = threadIdx.x >> 6;
  if ((threadIdx.x & 63) == 0) { as[wid] = s; as2[wid] = s2; }
  __syncthreads();
  if (threadIdx.x == 0) {
    float t  = as[0] + as[1] + as[2] + as[3];
    float t2 = as2[0] + as2[1] + as2[2] + as2[3];
    float m = t * (1.f / HW);
    float var = t2 * (1.f / HW) - m * m;
    mu[row] = m;
    rstd[row] = rsqrtf(var + 1e-5f);
  }
}

// ---------------- merged style modulation (3 segments) ----------------
__global__ __launch_bounds__(256) void modscale_all_kernel(
    const float* __restrict__ style,
    const float* __restrict__ m0w, const float* __restrict__ m0b,
    const float* __restrict__ m1w, const float* __restrict__ m1b,
    const float* __restrict__ msw, const float* __restrict__ msb,
    float* __restrict__ s0, float* __restrict__ s1, float* __restrict__ ss) {
  int idx = blockIdx.x * 256 + threadIdx.x;
  const float *mw, *mb; float* o; int I;
  if (idx < 4096) { mw = m0w; mb = m0b; o = s0; I = 512; }
  else if (idx < 6144) { idx -= 4096; mw = m1w; mb = m1b; o = s1; I = 256; }
  else if (idx < 10240) { idx -= 6144; mw = msw; mb = msb; o = ss; I = 512; }
  else return;
  int b = idx / I, i = idx - b * I;
  const float* st = style + (size_t)b * SD;
  const float* w  = mw + (size_t)i * SD;
  float acc = 0.f;
  for (int d = 0; d < SD; ++d) acc += st[d] * w[d];
  o[idx] = acc * 0.044194173824159216f + mb[i];
}

// ---------------- merged sum of w^2 (3 segments) ----------------
__global__ __launch_bounds__(256) void wsq_all_kernel(
    const float* __restrict__ w0, const float* __restrict__ w1,
    const float* __restrict__ wss,
    float* __restrict__ wsq0, float* __restrict__ wsq1, float* __restrict__ wsqs) {
  int idx = blockIdx.x * 256 + threadIdx.x;
  const float* w; float* o; int KK;
  if (idx < 131072) { w = w0; o = wsq0; KK = 9; }
  else if (idx < 196608) { idx -= 131072; w = w1; o = wsq1; KK = 9; }
  else if (idx < 327680) { idx -= 196608; w = wss; o = wsqs; KK = 1; }
  else return;
  const float* p = w + (size_t)idx * KK;
  float a = 0.f;
  for (int t = 0; t < KK; ++t) a += p[t] * p[t];
  o[idx] = a;
}

// ---------------- merged demod (3 segments) ----------------
__global__ __launch_bounds__(256) void demod_all_kernel(
    const float* __restrict__ wsq0, const float* __restrict__ s0, float* __restrict__ d0,
    const float* __restrict__ wsq1, const float* __restrict__ s1, float* __restrict__ d1,
    const float* __restrict__ wsqs, const float* __restrict__ ss, float* __restrict__ dss,
    float cs0, float cs1, float css) {
  int idx = blockIdx.x * 256 + threadIdx.x;
  const float *wsq, *s; float* dsc; int I; float cs;
  if (idx < 2048) { wsq = wsq0; s = s0; dsc = d0; I = 512; cs = cs0; }
  else if (idx < 4096) { idx -= 2048; wsq = wsq1; s = s1; dsc = d1; I = 256; cs = cs1; }
  else if (idx < 6144) { idx -= 4096; wsq = wsqs; s = ss; dsc = dss; I = 512; cs = css; }
  else return;
  int b = idx >> 8, o = idx & 255;
  const float* wr = wsq + (size_t)o * I;
  const float* sr = s + (size_t)b * I;
  float a = 0.f;
  for (int i = 0; i < I; ++i) { float sv = sr[i]; a += wr[i] * sv * sv; }
  dsc[idx] = rsqrtf(cs * cs * a + 1e-8f) * cs;
}

// ---------------- weight pack helper ----------------
__device__ __forceinline__ void pack_one(int tid, const float* __restrict__ wg,
                                         const float* __restrict__ wb,
                                         short* __restrict__ ph, short* __restrict__ pl,
                                         int OCtot, int IC, int KK, int interleave) {
  int ICC = IC / 32;
  int OCT16 = OCtot / 16;
  int lane = tid & 63;
  int r = tid >> 6;
  int icC = r % ICC; r /= ICC;
  int ocT = r % OCT16; int tap = r / OCT16;
  int po = ocT * 16 + (lane & 15);
  int ic0 = icC * 32 + (lane >> 4) * 8;
  const float* srcw;
  int oc;
  if (interleave) { oc = po >> 1; srcw = (po & 1) ? wb : wg; }
  else { oc = po; srcw = wg; }
  short8v hv, lv;
  #pragma unroll
  for (int j = 0; j < 8; ++j) {
    float v = srcw[((size_t)oc * IC + ic0 + j) * KK + tap];
    short h = f2bf(v);
    hv[j] = h;
    lv[j] = f2bf(v - bf2f(h));
  }
  size_t o = (size_t)tid * 8;
  *(short8v*)(ph + o) = hv;
  if (pl) *(short8v*)(pl + o) = lv;
}

// ---------------- merged weight packing: 6 segments ----------------
__global__ __launch_bounds__(256) void pack_w_all_kernel(
    const float* w0, const float* w1, const float* wss,
    const float* ns_gw, const float* ns_bw,
    const float* n0_gw, const float* n0_bw,
    const float* n1_gw, const float* n1_bw,
    short* p0h, short* p1h, short* p1l, short* psh, short* psl,
    short* pgsh, short* pg0h, short* pg1h) {
  int tid = blockIdx.x * 256 + threadIdx.x;
  if (tid < 147456) { pack_one(tid, w0, nullptr, p0h, nullptr, 256, 512, 9, 0); return; }
  tid -= 147456;
  if (tid < 73728) { pack_one(tid, w1, nullptr, p1h, p1l, 256, 256, 9, 0); return; }
  tid -= 73728;
  if (tid < 16384) { pack_one(tid, wss, nullptr, psh, psl, 256, 512, 1, 0); return; }
  tid -= 16384;
  if (tid < 147456) { pack_one(tid, ns_gw, ns_bw, pgsh, nullptr, 1024, 128, 9, 1); return; }
  tid -= 147456;
  if (tid < 147456) { pack_one(tid, n0_gw, n0_bw, pg0h, nullptr, 1024, 128, 9, 1); return; }
  tid -= 147456;
  if (tid < 73728) pack_one(tid, n1_gw, n1_bw, pg1h, nullptr, 512, 128, 9, 1);
}

// ---------------- pack the 3 seg-conv weight sets: OCtot=384, IC 35 padded to 64 ----------------
__global__ __launch_bounds__(256) void pack_sw_kernel(const float* __restrict__ sw0,
                                                      const float* __restrict__ sw1,
                                                      const float* __restrict__ sw2,
                                                      short* __restrict__ ph,
                                                      short* __restrict__ pl) {
  int tid = blockIdx.x * 256 + threadIdx.x;
  const int ICC = 2, OCT16 = 24;
  int total = 9 * OCT16 * ICC * 64;
  if (tid >= total) return;
  int lane = tid & 63;
  int r = tid >> 6;
  int icC = r % ICC; r /= ICC;
  int ocT = r % OCT16; int tap = r / OCT16;
  int oc = ocT * 16 + (lane & 15);
  int ic0 = icC * 32 + (lane >> 4) * 8;
  const float* srcw = (oc < 128) ? sw0 : ((oc < 256) ? sw1 : sw2);
  int ocl = oc & 127;
  short8v hv, lv;
  #pragma unroll
  for (int j = 0; j < 8; ++j) {
    int ic = ic0 + j;
    float v = (ic < SNC) ? srcw[((size_t)ocl * SNC + ic) * 9 + tap] : 0.f;
    short h = f2bf(v);
    hv[j] = h;
    lv[j] = f2bf(v - bf2f(h));
  }
  size_t o = (size_t)tid * 8;
  *(short8v*)(ph + o) = hv;
  *(short8v*)(pl + o) = lv;
}

// ---------------- seg transpose: [B,35,HW] fp32 -> pixel-major bf16 [B*HW][64] (pad 0) ----------------
__global__ __launch_bounds__(256) void seg_pack_kernel(const float* __restrict__ seg,
                                                       short* __restrict__ segT) {
  int pix = blockIdx.x * 256 + threadIdx.x;
  int b = pix >> 12, px = pix & 4095;
  float v[64];
  #pragma unroll
  for (int ic = 0; ic < SNC; ++ic)
    v[ic] = seg[((size_t)b * SNC + ic) * HW + px];
  #pragma unroll
  for (int ic = SNC; ic < 64; ++ic) v[ic] = 0.f;
  size_t o = (size_t)pix * 64;
  #pragma unroll
  for (int k = 0; k < 8; ++k) {
    short8v h;
    #pragma unroll
    for (int j = 0; j < 8; ++j) h[j] = f2bf(v[k * 8 + j]);
    *(short8v*)(segT + o + k * 8) = h;
  }
}

// ---------------- MFMA split-precision implicit-GEMM conv (r10 NROW=2 structure) ----------------
template<int IC, int ICSTRIDE, int K3, int MODE, int ACCUM, int INLO, int WLO>
__global__ __launch_bounds__(256) void conv_mfma_kernel(
    const short* __restrict__ in_hi, const short* __restrict__ in_lo,
    const short* __restrict__ wp_hi, const short* __restrict__ wp_lo,
    const float* __restrict__ dscale,
    const float* __restrict__ src, const float* __restrict__ mu,
    const float* __restrict__ rstd, const float* __restrict__ gbias,
    const float* __restrict__ bbias, const float* __restrict__ sscale,
    float* __restrict__ outF, short* __restrict__ out_hi,
    short* __restrict__ out_lo, int OCT16, int C, int icbase, int lrelu) {
  const int b = blockIdx.x;
  const int r0 = blockIdx.y * 2;
  const int zl = blockIdx.z;
  const int t = threadIdx.x;
  const int wv = t >> 6;
  const int lane = t & 63;
  const int l15 = lane & 15, lg = lane >> 4;
  const int ICC = IC / 32;
  const int PS = 2128;

  __shared__ __align__(16) short lds_hi[4 * 2128];
  __shared__ __align__(16) short lds_lo[INLO ? 4 * 2128 : 8];

  float4v acc[2][8];
  #pragma unroll
  for (int a = 0; a < 2; ++a)
    #pragma unroll
    for (int pt = 0; pt < 8; ++pt) acc[a][pt] = (float4v){0.f, 0.f, 0.f, 0.f};

  for (int icC = 0; icC < ICC; ++icC) {
    __syncthreads();
    const int ic0 = icC * 32;
    for (int idx = t; idx < 264 * 4; idx += 256) {
      int pos = idx >> 2, part = idx & 3;
      int srow = pos / 66;
      int scol = pos - srow * 66;
      int gy = r0 + srow - 1, gx = scol - 1;
      uint4v vh = {0u, 0u, 0u, 0u}, vl = {0u, 0u, 0u, 0u};
      bool ok = (gy >= 0 && gy < 64 && gx >= 0 && gx < 64);
      if (!K3) ok = ok && (srow >= 1 && srow <= 2);
      if (ok) {
        size_t g = ((size_t)b * HW + gy * 64 + gx) * ICSTRIDE + icbase + ic0 + part * 8;
        vh = *(const uint4v*)(in_hi + g);
        if (INLO) vl = *(const uint4v*)(in_lo + g);
      }
      int lo = part * PS + pos * 8;
      *(uint4v*)(lds_hi + lo) = vh;
      if (INLO) *(uint4v*)(lds_lo + lo) = vl;
    }
    __syncthreads();

    if (K3) {
      #pragma unroll
      for (int dx = 0; dx < 3; ++dx) {
        short8v Ah[3][2], Al[3][2];
        #pragma unroll
        for (int dy = 0; dy < 3; ++dy) {
          #pragma unroll
          for (int a = 0; a < 2; ++a) {
            size_t wi = ((((size_t)(dy * 3 + dx) * OCT16) + (zl * 8 + wv * 2 + a)) * ICC + icC) * 64 + lane;
            Ah[dy][a] = *(const short8v*)(wp_hi + wi * 8);
            if (WLO) Al[dy][a] = *(const short8v*)(wp_lo + wi * 8);
          }
        }
        #pragma unroll
        for (int c0i = 0; c0i < 4; ++c0i) {
          #pragma unroll
          for (int sr = 0; sr < 4; ++sr) {
            int pix = sr * 66 + c0i * 16 + dx + l15;
            int addr = lg * PS + pix * 8;
            short8v Bh = *(const short8v*)(lds_hi + addr);
            #pragma unroll
            for (int dy = 0; dy < 3; ++dy) {
              int pt = sr - dy;
              if (pt < 0 || pt > 1) continue;  // compile-time
              int ptt = pt * 4 + c0i;
              acc[0][ptt] = __builtin_amdgcn_mfma_f32_16x16x32_bf16(Ah[dy][0], Bh, acc[0][ptt], 0, 0, 0);
              acc[1][ptt] = __builtin_amdgcn_mfma_f32_16x16x32_bf16(Ah[dy][1], Bh, acc[1][ptt], 0, 0, 0);
              if (WLO) {
                acc[0][ptt] = __builtin_amdgcn_mfma_f32_16x16x32_bf16(Al[dy][0], Bh, acc[0][ptt], 0, 0, 0);
                acc[1][ptt] = __builtin_amdgcn_mfma_f32_16x16x32_bf16(Al[dy][1], Bh, acc[1][ptt], 0, 0, 0);
              }
            }
            if (INLO) {
              short8v Bl = *(const short8v*)(lds_lo + addr);
              #pragma unroll
              for (int dy = 0; dy < 3; ++dy) {
                int pt = sr - dy;
                if (pt < 0 || pt > 1) continue;
                int ptt = pt * 4 + c0i;
                acc[0][ptt] = __builtin_amdgcn_mfma_f32_16x16x32_bf16(Ah[dy][0], Bl, acc[0][ptt], 0, 0, 0);
                acc[1][ptt] = __builtin_amdgcn_mfma_f32_16x16x32_bf16(Ah[dy][1], Bl, acc[1][ptt], 0, 0, 0);
              }
            }
          }
        }
      }
    } else {
      short8v Ah[2], Al[2];
      #pragma unroll
      for (int a = 0; a < 2; ++a) {
        size_t wi = (((size_t)(zl * 8 + wv * 2 + a)) * ICC + icC) * 64 + lane;
        Ah[a] = *(const short8v*)(wp_hi + wi * 8);
        if (WLO) Al[a] = *(const short8v*)(wp_lo + wi * 8);
      }
      #pragma unroll
      for (int pt = 0; pt < 8; ++pt) {
        int pix = ((pt >> 2) + 1) * 66 + (pt & 3) * 16 + 1 + l15;
        int addr = lg * PS + pix * 8;
        short8v Bh = *(const short8v*)(lds_hi + addr);
        acc[0][pt] = __builtin_amdgcn_mfma_f32_16x16x32_bf16(Ah[0], Bh, acc[0][pt], 0, 0, 0);
        acc[1][pt] = __builtin_amdgcn_mfma_f32_16x16x32_bf16(Ah[1], Bh, acc[1][pt], 0, 0, 0);
        if (WLO) {
          acc[0][pt] = __builtin_amdgcn_mfma_f32_16x16x32_bf16(Al[0], Bh, acc[0][pt], 0, 0, 0);
          acc[1][pt] = __builtin_amdgcn_mfma_f32_16x16x32_bf16(Al[1], Bh, acc[1][pt], 0, 0, 0);
        }
        if (INLO) {
          short8v Bl = *(const short8v*)(lds_lo + addr);
          acc[0][pt] = __builtin_amdgcn_mfma_f32_16x16x32_bf16(Ah[0], Bl, acc[0][pt], 0, 0, 0);
          acc[1][pt] = __builtin_amdgcn_mfma_f32_16x16x32_bf16(Ah[1], Bl, acc[1][pt], 0, 0, 0);
        }
      }
    }
  }

  if (MODE == 2) {
    #pragma unroll
    for (int a = 0; a < 2; ++a) {
      int ocbase = zl * 128 + wv * 32 + a * 16 + lg * 4;
      float bs[4];
      #pragma unroll
      for (int r = 0; r < 4; ++r) bs[r] = gbias[ocbase + r];
      #pragma unroll
      for (int pt = 0; pt < 8; ++pt) {
        int px = (r0 + (pt >> 2)) * 64 + (pt & 3) * 16 + l15;
        short4v hs;
        #pragma unroll
        for (int r = 0; r < 4; ++r)
          hs[r] = f2bf(fmaxf(acc[a][pt][r] + bs[r], 0.f));
        *(short4v*)(out_hi + ((size_t)b * HW + px) * C + ocbase) = hs;
      }
    }
  } else {
    #pragma unroll
    for (int a = 0; a < 2; ++a) {
      int ocbase = zl * 128 + wv * 32 + a * 16 + lg * 4;
      float ds[4];
      #pragma unroll
      for (int r = 0; r < 4; ++r) ds[r] = dscale[b * 256 + ocbase + r];
      #pragma unroll
      for (int pt = 0; pt < 8; ++pt) {
        int px = (r0 + (pt >> 2)) * 64 + (pt & 3) * 16 + l15;
        #pragma unroll
        for (int r = 0; r < 4; ++r) {
          size_t oi = ((size_t)b * 256 + ocbase + r) * HW + px;
          float v = acc[a][pt][r] * ds[r];
          if (ACCUM) v += outF[oi];
          outF[oi] = v;
        }
      }
    }
  }
}

// ---------------- dual GB conv (weight-hi only, hi-only outputs, single staging round) ----------------
__global__ __launch_bounds__(256) void conv_gb_dual_kernel(
    const short* __restrict__ actv_hi,
    const short* __restrict__ pgsh, const short* __restrict__ pg0h,
    const float* __restrict__ x, const float* __restrict__ mu,
    const float* __restrict__ rstd,
    const float* __restrict__ ns_gb, const float* __restrict__ ns_bb,
    const float* __restrict__ ss,
    const float* __restrict__ n0_gb, const float* __restrict__ n0_bb,
    const float* __restrict__ s0,
    short* __restrict__ sp2_hi, short* __restrict__ sp_hi) {
  const int b = blockIdx.x;
  const int r0 = blockIdx.y * 2;
  const int zz = blockIdx.z;
  const bool isN0 = zz >= 8;
  const int zl = zz & 7;
  const short* wph = isN0 ? pg0h : pgsh;
  const float* gbias = isN0 ? n0_gb : ns_gb;
  const float* bbias = isN0 ? n0_bb : ns_bb;
  const float* sscale = isN0 ? s0 : ss;
  short* out_hi = isN0 ? sp_hi : sp2_hi;
  const int icbase = isN0 ? 0 : 256;
  const int lrelu = isN0 ? 1 : 0;
  const int OCT16 = 64, C = 512, ICC = 4, ICSTRIDE = 384;

  const int t = threadIdx.x;
  const int wv = t >> 6;
  const int lane = t & 63;
  const int l15 = lane & 15, lg = lane >> 4;
  const int PS = 2128;

  __shared__ __align__(16) short lds_hi[16 * 2128];

  float pre[2][2][8];
  #pragma unroll
  for (int a = 0; a < 2; ++a) {
    int base = zl * 128 + wv * 32 + a * 16 + lg * 4;
    int cA = base >> 1, cB = cA + 1;
    const float* srcA = x + ((size_t)b * C + cA) * HW;
    const float* srcB = x + ((size_t)b * C + cB) * HW;
    #pragma unroll
    for (int pt = 0; pt < 8; ++pt) {
      int px = (r0 + (pt >> 2)) * 64 + (pt & 3) * 16 + l15;
      pre[a][0][pt] = srcA[px];
      pre[a][1][pt] = srcB[px];
    }
  }

  float4v acc[2][8];
  #pragma unroll
  for (int a = 0; a < 2; ++a)
    #pragma unroll
    for (int pt = 0; pt < 8; ++pt) acc[a][pt] = (float4v){0.f, 0.f, 0.f, 0.f};

  for (int idx = t; idx < 264 * 16; idx += 256) {
    int pos = idx >> 4, part = idx & 15;
    int srow = pos / 66;
    int scol = pos - srow * 66;
    int gy = r0 + srow - 1, gx = scol - 1;
    uint4v vh = {0u, 0u, 0u, 0u};
    if (gy >= 0 && gy < 64 && gx >= 0 && gx < 64)
      vh = *(const uint4v*)(actv_hi + ((size_t)b * HW + gy * 64 + gx) * ICSTRIDE
                            + icbase + part * 8);
    *(uint4v*)(lds_hi + part * PS + pos * 8) = vh;
  }
  __syncthreads();

  #pragma unroll
  for (int icC = 0; icC < 4; ++icC) {
    #pragma unroll
    for (int dx = 0; dx < 3; ++dx) {
      short8v Ah[3][2];
      #pragma unroll
      for (int dy = 0; dy < 3; ++dy) {
        #pragma unroll
        for (int a = 0; a < 2; ++a) {
          size_t wi = ((((size_t)(dy * 3 + dx) * OCT16) + (zl * 8 + wv * 2 + a)) * ICC + icC) * 64 + lane;
          Ah[dy][a] = *(const short8v*)(wph + wi * 8);
        }
      }
      #pragma unroll
      for (int c0i = 0; c0i < 4; ++c0i) {
        #pragma unroll
        for (int sr = 0; sr < 4; ++sr) {
          int pix = sr * 66 + c0i * 16 + dx + l15;
          int addr = (icC * 4 + lg) * PS + pix * 8;
          short8v Bh = *(const short8v*)(lds_hi + addr);
          #pragma unroll
          for (int dy = 0; dy < 3; ++dy) {
            int pt = sr - dy;
            if (pt < 0 || pt > 1) continue;  // compile-time
            int ptt = pt * 4 + c0i;
            acc[0][ptt] = __builtin_amdgcn_mfma_f32_16x16x32_bf16(Ah[dy][0], Bh, acc[0][ptt], 0, 0, 0);
            acc[1][ptt] = __builtin_amdgcn_mfma_f32_16x16x32_bf16(Ah[dy][1], Bh, acc[1][ptt], 0, 0, 0);
          }
        }
      }
    }
  }

  #pragma unroll
  for (int a = 0; a < 2; ++a) {
    int base = zl * 128 + wv * 32 + a * 16 + lg * 4;
    int cA = base >> 1;
    int cB = cA + 1;
    float muA = mu[b * C + cA], rsA = rstd[b * C + cA];
    float gbA = gbias[cA], bbA = bbias[cA], sA = sscale[b * C + cA];
    float muB = mu[b * C + cB], rsB = rstd[b * C + cB];
    float gbB = gbias[cB], bbB = bbias[cB], sB = sscale[b * C + cB];
    #pragma unroll
    for (int pt = 0; pt < 8; ++pt) {
      int px = (r0 + (pt >> 2)) * 64 + (pt & 3) * 16 + l15;
      float nvA = (pre[a][0][pt] - muA) * rsA;
      float vA = nvA * (1.f + acc[a][pt][0] + gbA) + acc[a][pt][1] + bbA;
      if (lrelu) vA = (vA >= 0.f) ? vA : 0.2f * vA;
      vA *= sA;
      float nvB = (pre[a][1][pt] - muB) * rsB;
      float vB = nvB * (1.f + acc[a][pt][2] + gbB) + acc[a][pt][3] + bbB;
      if (lrelu) vB = (vB >= 0.f) ? vB : 0.2f * vB;
      vB *= sB;
      short hA = f2bf(vA), hB = f2bf(vB);
      size_t o = ((size_t)b * HW + px) * C + cA;
      *(unsigned*)(out_hi + o) =
          (unsigned)(unsigned short)hA | ((unsigned)(unsigned short)hB << 16);
    }
  }
}

// ---------------- gb_n1: single staging round (128 ic), weight-hi only, hi+lo outputs ----------------
__global__ __launch_bounds__(256) void conv_gb1_kernel(
    const short* __restrict__ actv_hi, const short* __restrict__ pg1h,
    const float* __restrict__ src, const float* __restrict__ mu,
    const float* __restrict__ rstd,
    const float* __restrict__ gbias, const float* __restrict__ bbias,
    const float* __restrict__ sscale,
    short* __restrict__ out_hi, short* __restrict__ out_lo) {
  const int b = blockIdx.x;
  const int r0 = blockIdx.y * 2;
  const int zl = blockIdx.z;
  const int OCT16 = 32, C = 256, ICC = 4, ICSTRIDE = 384, icbase = 128;

  const int t = threadIdx.x;
  const int wv = t >> 6;
  const int lane = t & 63;
  const int l15 = lane & 15, lg = lane >> 4;
  const int PS = 2128;

  __shared__ __align__(16) short lds_hi[16 * 2128];

  float pre[2][2][8];
  #pragma unroll
  for (int a = 0; a < 2; ++a) {
    int base = zl * 128 + wv * 32 + a * 16 + lg * 4;
    int cA = base >> 1, cB = cA + 1;
    const float* srcA = src + ((size_t)b * C + cA) * HW;
    const float* srcB = src + ((size_t)b * C + cB) * HW;
    #pragma unroll
    for (int pt = 0; pt < 8; ++pt) {
      int px = (r0 + (pt >> 2)) * 64 + (pt & 3) * 16 + l15;
      pre[a][0][pt] = srcA[px];
      pre[a][1][pt] = srcB[px];
    }
  }

  float4v acc[2][8];
  #pragma unroll
  for (int a = 0; a < 2; ++a)
    #pragma unroll
    for (int pt = 0; pt < 8; ++pt) acc[a][pt] = (float4v){0.f, 0.f, 0.f, 0.f};

  for (int idx = t; idx < 264 * 16; idx += 256) {
    int pos = idx >> 4, part = idx & 15;
    int srow = pos / 66;
    int scol = pos - srow * 66;
    int gy = r0 + srow - 1, gx = scol - 1;
    uint4v vh = {0u, 0u, 0u, 0u};
    if (gy >= 0 && gy < 64 && gx >= 0 && gx < 64)
      vh = *(const uint4v*)(actv_hi + ((size_t)b * HW + gy * 64 + gx) * ICSTRIDE
                            + icbase + part * 8);
    *(uint4v*)(lds_hi + part * PS + pos * 8) = vh;
  }
  __syncthreads();

  #pragma unroll
  for (int icC = 0; icC < 4; ++icC) {
    #pragma unroll
    for (int dx = 0; dx < 3; ++dx) {
      short8v Ah[3][2];
      #pragma unroll
      for (int dy = 0; dy < 3; ++dy) {
        #pragma unroll
        for (int a = 0; a < 2; ++a) {
          size_t wi = ((((size_t)(dy * 3 + dx) * OCT16) + (zl * 8 + wv * 2 + a)) * ICC + icC) * 64 + lane;
          Ah[dy][a] = *(const short8v*)(pg1h + wi * 8);
        }
      }
      #pragma unroll
      for (int c0i = 0; c0i < 4; ++c0i) {
        #pragma unroll
        for (int sr = 0; sr < 4; ++sr) {
          int pix = sr * 66 + c0i * 16 + dx + l15;
          int addr = (icC * 4 + lg) * PS + pix * 8;
          short8v Bh = *(const short8v*)(lds_hi + addr);
          #pragma unroll
          for (int dy = 0; dy < 3; ++dy) {
            int pt = sr - dy;
            if (pt < 0 || pt > 1) continue;  // compile-time
            int ptt = pt * 4 + c0i;
            acc[0][ptt] = __builtin_amdgcn_mfma_f32_16x16x32_bf16(Ah[dy][0], Bh, acc[0][ptt], 0, 0, 0);
            acc[1][ptt] = __builtin_amdgcn_mfma_f32_16x16x32_bf16(Ah[dy][1], Bh, acc[1][ptt], 0, 0, 0);
          }
        }
      }
    }
  }

  #pragma unroll
  for (int a = 0; a < 2; ++a) {
    int base = zl * 128 + wv * 32 + a * 16 + lg * 4;
    int cA = base >> 1;
    int cB = cA + 1;
    float muA = mu[b * C + cA], rsA = rstd[b * C + cA];
    float gbA = gbias[cA], bbA = bbias[cA], sA = sscale[b * C + cA];
    float muB = mu[b * C + cB], rsB = rstd[b * C + cB];
    float gbB = gbias[cB], bbB = bbias[cB], sB = sscale[b * C + cB];
    #pragma unroll
    for (int pt = 0; pt < 8; ++pt) {
      int px = (r0 + (pt >> 2)) * 64 + (pt & 3) * 16 + l15;
      float nvA = (pre[a][0][pt] - muA) * rsA;
      float vA = nvA * (1.f + acc[a][pt][0] + gbA) + acc[a][pt][1] + bbA;
      vA = (vA >= 0.f) ? vA : 0.2f * vA;
      vA *= sA;
      float nvB = (pre[a][1][pt] - muB) * rsB;
      float vB = nvB * (1.f + acc[a][pt][2] + gbB) + acc[a][pt][3] + bbB;
      vB = (vB >= 0.f) ? vB : 0.2f * vB;
      vB *= sB;
      short hA = f2bf(vA), hB = f2bf(vB);
      short lA = f2bf(vA - bf2f(hA)), lB = f2bf(vB - bf2f(hB));
      size_t o = ((size_t)b * HW + px) * C + cA;
      *(unsigned*)(out_hi + o) =
          (unsigned)(unsigned short)hA | ((unsigned)(unsigned short)hB << 16);
      *(unsigned*)(out_lo + o) =
          (unsigned)(unsigned short)lA | ((unsigned)(unsigned short)lB << 16);
    }
  }
}

// ---------------- dual modconv, VGPR-capped: z<2 = modconv0 (3x3, input-hi, weight-hi, 64-ic rounds),
// z>=2 = 1x1 (input-hi, weight hi+lo). ----------------
__global__ __launch_bounds__(256, 4) void conv_mc_dual_kernel(
    const short* __restrict__ sp_hi,
    const short* __restrict__ p0h,
    const float* __restrict__ d0, float* __restrict__ bufH,
    const short* __restrict__ sp2_hi,
    const short* __restrict__ psh, const short* __restrict__ psl,
    const float* __restrict__ dss, float* __restrict__ outD) {
  const int b = blockIdx.x;
  const int r0 = blockIdx.y * 2;
  const int zz = blockIdx.z;
  const bool is1x1 = zz >= 2;
  const int zl = zz & 1;
  const int OCT16 = 16, ICC = 16, ICSTRIDE = 512;

  const int t = threadIdx.x;
  const int wv = t >> 6;
  const int lane = t & 63;
  const int l15 = lane & 15, lg = lane >> 4;
  const int PS = 2128;

  __shared__ __align__(16) short lds[8 * 2128];

  float4v acc[2][8];
  #pragma unroll
  for (int a = 0; a < 2; ++a)
    #pragma unroll
    for (int pt = 0; pt < 8; ++pt) acc[a][pt] = (float4v){0.f, 0.f, 0.f, 0.f};

  if (!is1x1) {
    // modconv0: input-hi, weight-hi (1 MFMA/tap); 8 rounds x 64 ic
    for (int rnd = 0; rnd < 8; ++rnd) {
      __syncthreads();
      for (int idx = t; idx < 264 * 8; idx += 256) {
        int pos = idx >> 3, part = idx & 7;
        int srow = pos / 66;
        int scol = pos - srow * 66;
        int gy = r0 + srow - 1, gx = scol - 1;
        uint4v vh = {0u, 0u, 0u, 0u};
        if (gy >= 0 && gy < 64 && gx >= 0 && gx < 64)
          vh = *(const uint4v*)(sp_hi + ((size_t)b * HW + gy * 64 + gx) * ICSTRIDE
                                + rnd * 64 + part * 8);
        *(uint4v*)(lds + part * PS + pos * 8) = vh;
      }
      __syncthreads();

      #pragma unroll
      for (int sub = 0; sub < 2; ++sub) {
        const int icC = rnd * 2 + sub;
        #pragma unroll
        for (int dx = 0; dx < 3; ++dx) {
          short8v Ah[3][2];
          #pragma unroll
          for (int dy = 0; dy < 3; ++dy) {
            #pragma unroll
            for (int a = 0; a < 2; ++a) {
              size_t wi = ((((size_t)(dy * 3 + dx) * OCT16) + (zl * 8 + wv * 2 + a)) * ICC + icC) * 64 + lane;
              Ah[dy][a] = *(const short8v*)(p0h + wi * 8);
            }
          }
          #pragma unroll
          for (int c0i = 0; c0i < 4; ++c0i) {
            #pragma unroll
            for (int sr = 0; sr < 4; ++sr) {
              int pix = sr * 66 + c0i * 16 + dx + l15;
              int addr = (sub * 4 + lg) * PS + pix * 8;
              short8v Bh = *(const short8v*)(lds + addr);
              #pragma unroll
              for (int dy = 0; dy < 3; ++dy) {
                int pt = sr - dy;
                if (pt < 0 || pt > 1) continue;  // compile-time
                int ptt = pt * 4 + c0i;
                acc[0][ptt] = __builtin_amdgcn_mfma_f32_16x16x32_bf16(Ah[dy][0], Bh, acc[0][ptt], 0, 0, 0);
                acc[1][ptt] = __builtin_amdgcn_mfma_f32_16x16x32_bf16(Ah[dy][1], Bh, acc[1][ptt], 0, 0, 0);
              }
            }
          }
        }
      }
    }
  } else {
    // 1x1: input-hi, weight hi+lo (2 MFMAs); 16 rounds x 32 ic
    for (int icC = 0; icC < ICC; ++icC) {
      __syncthreads();
      const int ic0 = icC * 32;
      for (int idx = t; idx < 132 * 4; idx += 256) {
        int pos = idx >> 2, part = idx & 3;
        int srow = pos / 66;
        int scol = pos - srow * 66;
        int gy = r0 + srow, gx = scol - 1;
        uint4v vh = {0u, 0u, 0u, 0u};
        if (gx >= 0 && gx < 64)
          vh = *(const uint4v*)(sp2_hi + ((size_t)b * HW + gy * 64 + gx) * ICSTRIDE + ic0 + part * 8);
        *(uint4v*)(lds + part * PS + pos * 8) = vh;
      }
      __syncthreads();

      short8v Ah[2], Al[2];
      #pragma unroll
      for (int a = 0; a < 2; ++a) {
        size_t wi = (((size_t)(zl * 8 + wv * 2 + a)) * ICC + icC) * 64 + lane;
        Ah[a] = *(const short8v*)(psh + wi * 8);
        Al[a] = *(const short8v*)(psl + wi * 8);
      }
      #pragma unroll
      for (int pt = 0; pt < 8; ++pt) {
        int pix = (pt >> 2) * 66 + (pt & 3) * 16 + 1 + l15;
        short8v Bh = *(const short8v*)(lds + lg * PS + pix * 8);
        acc[0][pt] = __builtin_amdgcn_mfma_f32_16x16x32_bf16(Ah[0], Bh, acc[0][pt], 0, 0, 0);
        acc[1][pt] = __builtin_amdgcn_mfma_f32_16x16x32_bf16(Ah[1], Bh, acc[1][pt], 0, 0, 0);
        acc[0][pt] = __builtin_amdgcn_mfma_f32_16x16x32_bf16(Al[0], Bh, acc[0][pt], 0, 0, 0);
        acc[1][pt] = __builtin_amdgcn_mfma_f32_16x16x32_bf16(Al[1], Bh, acc[1][pt], 0, 0, 0);
      }
    }
  }

  const float* dscale = is1x1 ? dss : d0;
  float* outF = is1x1 ? outD : bufH;
  #pragma unroll
  for (int a = 0; a < 2; ++a) {
    int ocbase = zl * 128 + wv * 32 + a * 16 + lg * 4;
    float ds[4];
    #pragma unroll
    for (int r = 0; r < 4; ++r) ds[r] = dscale[b * 256 + ocbase + r];
    #pragma unroll
    for (int pt = 0; pt < 8; ++pt) {
      int px = (r0 + (pt >> 2)) * 64 + (pt & 3) * 16 + l15;
      #pragma unroll
      for (int r = 0; r < 4; ++r) {
        size_t oi = ((size_t)b * 256 + ocbase + r) * HW + px;
        outF[oi] = acc[a][pt][r] * ds[r];
      }
    }
  }
}

extern "C" void kernel_launch(void* const* d_in, const int* in_sizes, int n_in,
                              void* d_out, int out_size, void* d_ws, size_t ws_size,
                              hipStream_t stream) {
  const float* x     = (const float*)d_in[0];
  const float* seg   = (const float*)d_in[1];
  const float* style = (const float*)d_in[2];
  const float* n0_sw = (const float*)d_in[3];
  const float* n0_sb = (const float*)d_in[4];
  const float* n0_gw = (const float*)d_in[5];
  const float* n0_gb = (const float*)d_in[6];
  const float* n0_bw = (const float*)d_in[7];
  const float* n0_bb = (const float*)d_in[8];
  const float* n1_sw = (const float*)d_in[9];
  const float* n1_sb = (const float*)d_in[10];
  const float* n1_gw = (const float*)d_in[11];
  const float* n1_gb = (const float*)d_in[12];
  const float* n1_bw = (const float*)d_in[13];
  const float* n1_bb = (const float*)d_in[14];
  const float* ns_sw = (const float*)d_in[15];
  const float* ns_sb = (const float*)d_in[16];
  const float* ns_gw = (const float*)d_in[17];
  const float* ns_gb = (const float*)d_in[18];
  const float* ns_bw = (const float*)d_in[19];
  const float* ns_bb = (const float*)d_in[20];
  const float* w0  = (const float*)d_in[21];
  const float* m0w = (const float*)d_in[22];
  const float* m0b = (const float*)d_in[23];
  const float* w1  = (const float*)d_in[24];
  const float* m1w = (const float*)d_in[25];
  const float* m1b = (const float*)d_in[26];
  const float* wss = (const float*)d_in[27];
  const float* msw = (const float*)d_in[28];
  const float* msb = (const float*)d_in[29];
  float* out = (float*)d_out;

  char* p = (char*)d_ws;
  auto allocF = [&](size_t n) { float* r = (float*)p; p += n * 4; return r; };
  auto allocS = [&](size_t n) { short* r = (short*)p; p += n * 2; return r; };

  float* mu_x   = allocF(4096);
  float* rstd_x = allocF(4096);
  float* mu_h   = allocF(2048);
  float* rstd_h = allocF(2048);
  float* s0  = allocF(4096);
  float* s1  = allocF(2048);
  float* ss  = allocF(4096);
  float* d0  = allocF(2048);
  float* d1  = allocF(2048);
  float* dss = allocF(2048);
  float* wsq0 = allocF(256 * 512);
  float* wsq1 = allocF(256 * 256);
  float* wsqs = allocF(256 * 512);
  float* sb_cat = allocF(384);
  float* bufH = allocF((size_t)BN * 256 * HW);
  short* actv_hi = allocS((size_t)BN * HW * 384);
  short* segT = allocS((size_t)BN * HW * 64);
  short* sp_hi = allocS((size_t)BN * HW * 512);
  short* sp_lo = allocS((size_t)BN * HW * 512);
  short* sp2_hi = allocS((size_t)BN * HW * 512);
  short* p0h = allocS((size_t)256 * 512 * 9);
  short* p1h = allocS((size_t)256 * 256 * 9);
  short* p1l = allocS((size_t)256 * 256 * 9);
  short* psh = allocS((size_t)256 * 512);
  short* psl = allocS((size_t)256 * 512);
  short* pswh = allocS((size_t)9 * 24 * 2 * 64 * 8);
  short* pswl = allocS((size_t)9 * 24 * 2 * 64 * 8);
  short* pgsh = allocS((size_t)1024 * 128 * 9);
  short* pg0h = allocS((size_t)1024 * 128 * 9);
  short* pg1h = allocS((size_t)512 * 128 * 9);

  float cs0 = 1.0f / sqrtf(512.f * 9.f);
  float cs1 = 1.0f / sqrtf(256.f * 9.f);
  float css = 1.0f / sqrtf(512.f);

  // -------- small precompute (merged) --------
  stats_kernel<<<BN * 512, 256, 0, stream>>>(x, mu_x, rstd_x);
  modscale_all_kernel<<<40, 256, 0, stream>>>(style, m0w, m0b, m1w, m1b, msw, msb,
                                              s0, s1, ss);
  wsq_all_kernel<<<1280, 256, 0, stream>>>(w0, w1, wss, wsq0, wsq1, wsqs);
  demod_all_kernel<<<24, 256, 0, stream>>>(wsq0, s0, d0, wsq1, s1, d1, wsqs, ss, dss,
                                           cs0, cs1, css);

  // -------- seg transpose + bias concat --------
  seg_pack_kernel<<<(BN * HW) / 256, 256, 0, stream>>>(seg, segT);
  hipMemcpyAsync(sb_cat,       n0_sb, 128 * 4, hipMemcpyDeviceToDevice, stream);
  hipMemcpyAsync(sb_cat + 128, n1_sb, 128 * 4, hipMemcpyDeviceToDevice, stream);
  hipMemcpyAsync(sb_cat + 256, ns_sb, 128 * 4, hipMemcpyDeviceToDevice, stream);

  // -------- weight packing (merged; gb + w0 weights hi-only) --------
  pack_sw_kernel<<<108, 256, 0, stream>>>(n0_sw, n1_sw, ns_sw, pswh, pswl);
  pack_w_all_kernel<<<2368, 256, 0, stream>>>(
      w0, w1, wss, ns_gw, ns_bw, n0_gw, n0_bw, n1_gw, n1_bw,
      p0h, p1h, p1l, psh, psl, pgsh, pg0h, pg1h);

  // -------- all 3 seg convs via MFMA (MODE=2) --------
  conv_mfma_kernel<64, 64, 1, 2, 0, 0, 1><<<dim3(BN, 32, 3), 256, 0, stream>>>(
      segT, nullptr, pswh, pswl, nullptr, nullptr, nullptr, nullptr, sb_cat,
      nullptr, nullptr, nullptr, actv_hi, nullptr, 24, 384, 0, 0);

  // -------- dual GB (hi-only out, single staging round): ns -> sp2_hi, n0 -> sp_hi --------
  conv_gb_dual_kernel<<<dim3(BN, 32, 16), 256, 0, stream>>>(
      actv_hi, pgsh, pg0h, x, mu_x, rstd_x,
      ns_gb, ns_bb, ss, n0_gb, n0_bb, s0, sp2_hi, sp_hi);

  // -------- dual modconv (VGPR<=128): modconv0 (hi*hi) + 1x1 (hi in, hi+lo w) --------
  conv_mc_dual_kernel<<<dim3(BN, 32, 4), 256, 0, stream>>>(
      sp_hi, p0h, d0, bufH,
      sp2_hi, psh, psl, dss, out);

  // -------- spade_n1 over bufH (single staging round, hi+lo out) -> modconv1 (+= into d_out) --------
  stats_kernel<<<BN * 256, 256, 0, stream>>>(bufH, mu_h, rstd_h);
  conv_gb1_kernel<<<dim3(BN, 32, 4), 256, 0, stream>>>(
      actv_hi, pg1h, bufH, mu_h, rstd_h, n1_gb, n1_bb, s1, sp_hi, sp_lo);
  conv_mfma_kernel<256, 256, 1, 0, 1, 1, 1><<<dim3(BN, 32, 2), 256, 0, stream>>>(
      sp_hi, sp_lo, p1h, p1l, d1, nullptr, nullptr, nullptr, nullptr, nullptr,
      nullptr, out, nullptr, nullptr, 16, 0, 0, 0);
}

// Round 19
// 569.430 us; speedup vs baseline: 1.5057x; 1.0660x over previous
//
#include <hip/hip_runtime.h>
#include <math.h>

#define BN 8
#define HW 4096
#define NH 128
#define SNC 35
#define SD 512

typedef __attribute__((ext_vector_type(8))) short short8v;
typedef __attribute__((ext_vector_type(4))) short short4v;
typedef __attribute__((ext_vector_type(4))) float float4v;
typedef __attribute__((ext_vector_type(4))) unsigned int uint4v;

__device__ __forceinline__ short f2bf(float f) {
  unsigned u = __float_as_uint(f);
  unsigned r = (u + 0x7fffu + ((u >> 16) & 1u)) >> 16;
  return (short)r;
}
__device__ __forceinline__ float bf2f(short h) {
  return __uint_as_float(((unsigned)(unsigned short)h) << 16);
}

// ---------------- per-(b,c) instance-norm stats ----------------
__global__ __launch_bounds__(256) void stats_kernel(const float* __restrict__ x,
                                                    float* __restrict__ mu,
                                                    float* __restrict__ rstd) {
  int row = blockIdx.x;
  const float* p = x + (size_t)row * HW;
  float s = 0.f, s2 = 0.f;
  for (int i = threadIdx.x; i < HW; i += 256) {
    float v = p[i];
    s += v; s2 += v * v;
  }
  #pragma unroll
  for (int off = 32; off > 0; off >>= 1) {
    s  += __shfl_down(s, off);
    s2 += __shfl_down(s2, off);
  }
  __shared__ float as[4], as2[4];
  int wid = threadIdx.x >> 6;
  if ((threadIdx.x & 63) == 0) { as[wid] = s; as2[wid] = s2; }
  __syncthreads();
  if (threadIdx.x == 0) {
    float t  = as[0] + as[1] + as[2] + as[3];
    float t2 = as2[0] + as2[1] + as2[2] + as2[3];
    float m = t * (1.f / HW);
    float var = t2 * (1.f / HW) - m * m;
    mu[row] = m;
    rstd[row] = rsqrtf(var + 1e-5f);
  }
}

// ---------------- merged style modulation (3 segments) ----------------
__global__ __launch_bounds__(256) void modscale_all_kernel(
    const float* __restrict__ style,
    const float* __restrict__ m0w, const float* __restrict__ m0b,
    const float* __restrict__ m1w, const float* __restrict__ m1b,
    const float* __restrict__ msw, const float* __restrict__ msb,
    float* __restrict__ s0, float* __restrict__ s1, float* __restrict__ ss) {
  int idx = blockIdx.x * 256 + threadIdx.x;
  const float *mw, *mb; float* o; int I;
  if (idx < 4096) { mw = m0w; mb = m0b; o = s0; I = 512; }
  else if (idx < 6144) { idx -= 4096; mw = m1w; mb = m1b; o = s1; I = 256; }
  else if (idx < 10240) { idx -= 6144; mw = msw; mb = msb; o = ss; I = 512; }
  else return;
  int b = idx / I, i = idx - b * I;
  const float* st = style + (size_t)b * SD;
  const float* w  = mw + (size_t)i * SD;
  float acc = 0.f;
  for (int d = 0; d < SD; ++d) acc += st[d] * w[d];
  o[idx] = acc * 0.044194173824159216f + mb[i];
}

// ---------------- merged sum of w^2 (3 segments) ----------------
__global__ __launch_bounds__(256) void wsq_all_kernel(
    const float* __restrict__ w0, const float* __restrict__ w1,
    const float* __restrict__ wss,
    float* __restrict__ wsq0, float* __restrict__ wsq1, float* __restrict__ wsqs) {
  int idx = blockIdx.x * 256 + threadIdx.x;
  const float* w; float* o; int KK;
  if (idx < 131072) { w = w0; o = wsq0; KK = 9; }
  else if (idx < 196608) { idx -= 131072; w = w1; o = wsq1; KK = 9; }
  else if (idx < 327680) { idx -= 196608; w = wss; o = wsqs; KK = 1; }
  else return;
  const float* p = w + (size_t)idx * KK;
  float a = 0.f;
  for (int t = 0; t < KK; ++t) a += p[t] * p[t];
  o[idx] = a;
}

// ---------------- merged demod (3 segments) ----------------
__global__ __launch_bounds__(256) void demod_all_kernel(
    const float* __restrict__ wsq0, const float* __restrict__ s0, float* __restrict__ d0,
    const float* __restrict__ wsq1, const float* __restrict__ s1, float* __restrict__ d1,
    const float* __restrict__ wsqs, const float* __restrict__ ss, float* __restrict__ dss,
    float cs0, float cs1, float css) {
  int idx = blockIdx.x * 256 + threadIdx.x;
  const float *wsq, *s; float* dsc; int I; float cs;
  if (idx < 2048) { wsq = wsq0; s = s0; dsc = d0; I = 512; cs = cs0; }
  else if (idx < 4096) { idx -= 2048; wsq = wsq1; s = s1; dsc = d1; I = 256; cs = cs1; }
  else if (idx < 6144) { idx -= 4096; wsq = wsqs; s = ss; dsc = dss; I = 512; cs = css; }
  else return;
  int b = idx >> 8, o = idx & 255;
  const float* wr = wsq + (size_t)o * I;
  const float* sr = s + (size_t)b * I;
  float a = 0.f;
  for (int i = 0; i < I; ++i) { float sv = sr[i]; a += wr[i] * sv * sv; }
  dsc[idx] = rsqrtf(cs * cs * a + 1e-8f) * cs;
}

// ---------------- weight pack helper ----------------
__device__ __forceinline__ void pack_one(int tid, const float* __restrict__ wg,
                                         const float* __restrict__ wb,
                                         short* __restrict__ ph, short* __restrict__ pl,
                                         int OCtot, int IC, int KK, int interleave) {
  int ICC = IC / 32;
  int OCT16 = OCtot / 16;
  int lane = tid & 63;
  int r = tid >> 6;
  int icC = r % ICC; r /= ICC;
  int ocT = r % OCT16; int tap = r / OCT16;
  int po = ocT * 16 + (lane & 15);
  int ic0 = icC * 32 + (lane >> 4) * 8;
  const float* srcw;
  int oc;
  if (interleave) { oc = po >> 1; srcw = (po & 1) ? wb : wg; }
  else { oc = po; srcw = wg; }
  short8v hv, lv;
  #pragma unroll
  for (int j = 0; j < 8; ++j) {
    float v = srcw[((size_t)oc * IC + ic0 + j) * KK + tap];
    short h = f2bf(v);
    hv[j] = h;
    lv[j] = f2bf(v - bf2f(h));
  }
  size_t o = (size_t)tid * 8;
  *(short8v*)(ph + o) = hv;
  if (pl) *(short8v*)(pl + o) = lv;
}

// ---------------- merged weight packing: 6 segments ----------------
__global__ __launch_bounds__(256) void pack_w_all_kernel(
    const float* w0, const float* w1, const float* wss,
    const float* ns_gw, const float* ns_bw,
    const float* n0_gw, const float* n0_bw,
    const float* n1_gw, const float* n1_bw,
    short* p0h, short* p1h, short* p1l, short* psh, short* psl,
    short* pgsh, short* pg0h, short* pg1h) {
  int tid = blockIdx.x * 256 + threadIdx.x;
  if (tid < 147456) { pack_one(tid, w0, nullptr, p0h, nullptr, 256, 512, 9, 0); return; }
  tid -= 147456;
  if (tid < 73728) { pack_one(tid, w1, nullptr, p1h, p1l, 256, 256, 9, 0); return; }
  tid -= 73728;
  if (tid < 16384) { pack_one(tid, wss, nullptr, psh, psl, 256, 512, 1, 0); return; }
  tid -= 16384;
  if (tid < 147456) { pack_one(tid, ns_gw, ns_bw, pgsh, nullptr, 1024, 128, 9, 1); return; }
  tid -= 147456;
  if (tid < 147456) { pack_one(tid, n0_gw, n0_bw, pg0h, nullptr, 1024, 128, 9, 1); return; }
  tid -= 147456;
  if (tid < 73728) pack_one(tid, n1_gw, n1_bw, pg1h, nullptr, 512, 128, 9, 1);
}

// ---------------- pack the 3 seg-conv weight sets: OCtot=384, IC 35 padded to 64 ----------------
__global__ __launch_bounds__(256) void pack_sw_kernel(const float* __restrict__ sw0,
                                                      const float* __restrict__ sw1,
                                                      const float* __restrict__ sw2,
                                                      short* __restrict__ ph,
                                                      short* __restrict__ pl) {
  int tid = blockIdx.x * 256 + threadIdx.x;
  const int ICC = 2, OCT16 = 24;
  int total = 9 * OCT16 * ICC * 64;
  if (tid >= total) return;
  int lane = tid & 63;
  int r = tid >> 6;
  int icC = r % ICC; r /= ICC;
  int ocT = r % OCT16; int tap = r / OCT16;
  int oc = ocT * 16 + (lane & 15);
  int ic0 = icC * 32 + (lane >> 4) * 8;
  const float* srcw = (oc < 128) ? sw0 : ((oc < 256) ? sw1 : sw2);
  int ocl = oc & 127;
  short8v hv, lv;
  #pragma unroll
  for (int j = 0; j < 8; ++j) {
    int ic = ic0 + j;
    float v = (ic < SNC) ? srcw[((size_t)ocl * SNC + ic) * 9 + tap] : 0.f;
    short h = f2bf(v);
    hv[j] = h;
    lv[j] = f2bf(v - bf2f(h));
  }
  size_t o = (size_t)tid * 8;
  *(short8v*)(ph + o) = hv;
  *(short8v*)(pl + o) = lv;
}

// ---------------- seg transpose: [B,35,HW] fp32 -> pixel-major bf16 [B*HW][64] (pad 0) ----------------
__global__ __launch_bounds__(256) void seg_pack_kernel(const float* __restrict__ seg,
                                                       short* __restrict__ segT) {
  int pix = blockIdx.x * 256 + threadIdx.x;
  int b = pix >> 12, px = pix & 4095;
  float v[64];
  #pragma unroll
  for (int ic = 0; ic < SNC; ++ic)
    v[ic] = seg[((size_t)b * SNC + ic) * HW + px];
  #pragma unroll
  for (int ic = SNC; ic < 64; ++ic) v[ic] = 0.f;
  size_t o = (size_t)pix * 64;
  #pragma unroll
  for (int k = 0; k < 8; ++k) {
    short8v h;
    #pragma unroll
    for (int j = 0; j < 8; ++j) h[j] = f2bf(v[k * 8 + j]);
    *(short8v*)(segT + o + k * 8) = h;
  }
}

// ---------------- MFMA split-precision implicit-GEMM conv (r10 NROW=2 structure) ----------------
template<int IC, int ICSTRIDE, int K3, int MODE, int ACCUM, int INLO, int WLO>
__global__ __launch_bounds__(256) void conv_mfma_kernel(
    const short* __restrict__ in_hi, const short* __restrict__ in_lo,
    const short* __restrict__ wp_hi, const short* __restrict__ wp_lo,
    const float* __restrict__ dscale,
    const float* __restrict__ src, const float* __restrict__ mu,
    const float* __restrict__ rstd, const float* __restrict__ gbias,
    const float* __restrict__ bbias, const float* __restrict__ sscale,
    float* __restrict__ outF, short* __restrict__ out_hi,
    short* __restrict__ out_lo, int OCT16, int C, int icbase, int lrelu) {
  const int b = blockIdx.x;
  const int r0 = blockIdx.y * 2;
  const int zl = blockIdx.z;
  const int t = threadIdx.x;
  const int wv = t >> 6;
  const int lane = t & 63;
  const int l15 = lane & 15, lg = lane >> 4;
  const int ICC = IC / 32;
  const int PS = 2128;

  __shared__ __align__(16) short lds_hi[4 * 2128];
  __shared__ __align__(16) short lds_lo[INLO ? 4 * 2128 : 8];

  float4v acc[2][8];
  #pragma unroll
  for (int a = 0; a < 2; ++a)
    #pragma unroll
    for (int pt = 0; pt < 8; ++pt) acc[a][pt] = (float4v){0.f, 0.f, 0.f, 0.f};

  for (int icC = 0; icC < ICC; ++icC) {
    __syncthreads();
    const int ic0 = icC * 32;
    for (int idx = t; idx < 264 * 4; idx += 256) {
      int pos = idx >> 2, part = idx & 3;
      int srow = pos / 66;
      int scol = pos - srow * 66;
      int gy = r0 + srow - 1, gx = scol - 1;
      uint4v vh = {0u, 0u, 0u, 0u}, vl = {0u, 0u, 0u, 0u};
      bool ok = (gy >= 0 && gy < 64 && gx >= 0 && gx < 64);
      if (!K3) ok = ok && (srow >= 1 && srow <= 2);
      if (ok) {
        size_t g = ((size_t)b * HW + gy * 64 + gx) * ICSTRIDE + icbase + ic0 + part * 8;
        vh = *(const uint4v*)(in_hi + g);
        if (INLO) vl = *(const uint4v*)(in_lo + g);
      }
      int lo = part * PS + pos * 8;
      *(uint4v*)(lds_hi + lo) = vh;
      if (INLO) *(uint4v*)(lds_lo + lo) = vl;
    }
    __syncthreads();

    if (K3) {
      #pragma unroll
      for (int dx = 0; dx < 3; ++dx) {
        short8v Ah[3][2], Al[3][2];
        #pragma unroll
        for (int dy = 0; dy < 3; ++dy) {
          #pragma unroll
          for (int a = 0; a < 2; ++a) {
            size_t wi = ((((size_t)(dy * 3 + dx) * OCT16) + (zl * 8 + wv * 2 + a)) * ICC + icC) * 64 + lane;
            Ah[dy][a] = *(const short8v*)(wp_hi + wi * 8);
            if (WLO) Al[dy][a] = *(const short8v*)(wp_lo + wi * 8);
          }
        }
        #pragma unroll
        for (int c0i = 0; c0i < 4; ++c0i) {
          #pragma unroll
          for (int sr = 0; sr < 4; ++sr) {
            int pix = sr * 66 + c0i * 16 + dx + l15;
            int addr = lg * PS + pix * 8;
            short8v Bh = *(const short8v*)(lds_hi + addr);
            #pragma unroll
            for (int dy = 0; dy < 3; ++dy) {
              int pt = sr - dy;
              if (pt < 0 || pt > 1) continue;  // compile-time
              int ptt = pt * 4 + c0i;
              acc[0][ptt] = __builtin_amdgcn_mfma_f32_16x16x32_bf16(Ah[dy][0], Bh, acc[0][ptt], 0, 0, 0);
              acc[1][ptt] = __builtin_amdgcn_mfma_f32_16x16x32_bf16(Ah[dy][1], Bh, acc[1][ptt], 0, 0, 0);
              if (WLO) {
                acc[0][ptt] = __builtin_amdgcn_mfma_f32_16x16x32_bf16(Al[dy][0], Bh, acc[0][ptt], 0, 0, 0);
                acc[1][ptt] = __builtin_amdgcn_mfma_f32_16x16x32_bf16(Al[dy][1], Bh, acc[1][ptt], 0, 0, 0);
              }
            }
            if (INLO) {
              short8v Bl = *(const short8v*)(lds_lo + addr);
              #pragma unroll
              for (int dy = 0; dy < 3; ++dy) {
                int pt = sr - dy;
                if (pt < 0 || pt > 1) continue;
                int ptt = pt * 4 + c0i;
                acc[0][ptt] = __builtin_amdgcn_mfma_f32_16x16x32_bf16(Ah[dy][0], Bl, acc[0][ptt], 0, 0, 0);
                acc[1][ptt] = __builtin_amdgcn_mfma_f32_16x16x32_bf16(Ah[dy][1], Bl, acc[1][ptt], 0, 0, 0);
              }
            }
          }
        }
      }
    } else {
      short8v Ah[2], Al[2];
      #pragma unroll
      for (int a = 0; a < 2; ++a) {
        size_t wi = (((size_t)(zl * 8 + wv * 2 + a)) * ICC + icC) * 64 + lane;
        Ah[a] = *(const short8v*)(wp_hi + wi * 8);
        if (WLO) Al[a] = *(const short8v*)(wp_lo + wi * 8);
      }
      #pragma unroll
      for (int pt = 0; pt < 8; ++pt) {
        int pix = ((pt >> 2) + 1) * 66 + (pt & 3) * 16 + 1 + l15;
        int addr = lg * PS + pix * 8;
        short8v Bh = *(const short8v*)(lds_hi + addr);
        acc[0][pt] = __builtin_amdgcn_mfma_f32_16x16x32_bf16(Ah[0], Bh, acc[0][pt], 0, 0, 0);
        acc[1][pt] = __builtin_amdgcn_mfma_f32_16x16x32_bf16(Ah[1], Bh, acc[1][pt], 0, 0, 0);
        if (WLO) {
          acc[0][pt] = __builtin_amdgcn_mfma_f32_16x16x32_bf16(Al[0], Bh, acc[0][pt], 0, 0, 0);
          acc[1][pt] = __builtin_amdgcn_mfma_f32_16x16x32_bf16(Al[1], Bh, acc[1][pt], 0, 0, 0);
        }
        if (INLO) {
          short8v Bl = *(const short8v*)(lds_lo + addr);
          acc[0][pt] = __builtin_amdgcn_mfma_f32_16x16x32_bf16(Ah[0], Bl, acc[0][pt], 0, 0, 0);
          acc[1][pt] = __builtin_amdgcn_mfma_f32_16x16x32_bf16(Ah[1], Bl, acc[1][pt], 0, 0, 0);
        }
      }
    }
  }

  if (MODE == 2) {
    #pragma unroll
    for (int a = 0; a < 2; ++a) {
      int ocbase = zl * 128 + wv * 32 + a * 16 + lg * 4;
      float bs[4];
      #pragma unroll
      for (int r = 0; r < 4; ++r) bs[r] = gbias[ocbase + r];
      #pragma unroll
      for (int pt = 0; pt < 8; ++pt) {
        int px = (r0 + (pt >> 2)) * 64 + (pt & 3) * 16 + l15;
        short4v hs;
        #pragma unroll
        for (int r = 0; r < 4; ++r)
          hs[r] = f2bf(fmaxf(acc[a][pt][r] + bs[r], 0.f));
        *(short4v*)(out_hi + ((size_t)b * HW + px) * C + ocbase) = hs;
      }
    }
  } else {
    #pragma unroll
    for (int a = 0; a < 2; ++a) {
      int ocbase = zl * 128 + wv * 32 + a * 16 + lg * 4;
      float ds[4];
      #pragma unroll
      for (int r = 0; r < 4; ++r) ds[r] = dscale[b * 256 + ocbase + r];
      #pragma unroll
      for (int pt = 0; pt < 8; ++pt) {
        int px = (r0 + (pt >> 2)) * 64 + (pt & 3) * 16 + l15;
        #pragma unroll
        for (int r = 0; r < 4; ++r) {
          size_t oi = ((size_t)b * 256 + ocbase + r) * HW + px;
          float v = acc[a][pt][r] * ds[r];
          if (ACCUM) v += outF[oi];
          outF[oi] = v;
        }
      }
    }
  }
}

// ---------------- dual GB conv (weight-hi only, hi-only outputs, single staging round) ----------------
__global__ __launch_bounds__(256) void conv_gb_dual_kernel(
    const short* __restrict__ actv_hi,
    const short* __restrict__ pgsh, const short* __restrict__ pg0h,
    const float* __restrict__ x, const float* __restrict__ mu,
    const float* __restrict__ rstd,
    const float* __restrict__ ns_gb, const float* __restrict__ ns_bb,
    const float* __restrict__ ss,
    const float* __restrict__ n0_gb, const float* __restrict__ n0_bb,
    const float* __restrict__ s0,
    short* __restrict__ sp2_hi, short* __restrict__ sp_hi) {
  const int b = blockIdx.x;
  const int r0 = blockIdx.y * 2;
  const int zz = blockIdx.z;
  const bool isN0 = zz >= 8;
  const int zl = zz & 7;
  const short* wph = isN0 ? pg0h : pgsh;
  const float* gbias = isN0 ? n0_gb : ns_gb;
  const float* bbias = isN0 ? n0_bb : ns_bb;
  const float* sscale = isN0 ? s0 : ss;
  short* out_hi = isN0 ? sp_hi : sp2_hi;
  const int icbase = isN0 ? 0 : 256;
  const int lrelu = isN0 ? 1 : 0;
  const int OCT16 = 64, C = 512, ICC = 4, ICSTRIDE = 384;

  const int t = threadIdx.x;
  const int wv = t >> 6;
  const int lane = t & 63;
  const int l15 = lane & 15, lg = lane >> 4;
  const int PS = 2128;

  __shared__ __align__(16) short lds_hi[16 * 2128];

  float pre[2][2][8];
  #pragma unroll
  for (int a = 0; a < 2; ++a) {
    int base = zl * 128 + wv * 32 + a * 16 + lg * 4;
    int cA = base >> 1, cB = cA + 1;
    const float* srcA = x + ((size_t)b * C + cA) * HW;
    const float* srcB = x + ((size_t)b * C + cB) * HW;
    #pragma unroll
    for (int pt = 0; pt < 8; ++pt) {
      int px = (r0 + (pt >> 2)) * 64 + (pt & 3) * 16 + l15;
      pre[a][0][pt] = srcA[px];
      pre[a][1][pt] = srcB[px];
    }
  }

  float4v acc[2][8];
  #pragma unroll
  for (int a = 0; a < 2; ++a)
    #pragma unroll
    for (int pt = 0; pt < 8; ++pt) acc[a][pt] = (float4v){0.f, 0.f, 0.f, 0.f};

  for (int idx = t; idx < 264 * 16; idx += 256) {
    int pos = idx >> 4, part = idx & 15;
    int srow = pos / 66;
    int scol = pos - srow * 66;
    int gy = r0 + srow - 1, gx = scol - 1;
    uint4v vh = {0u, 0u, 0u, 0u};
    if (gy >= 0 && gy < 64 && gx >= 0 && gx < 64)
      vh = *(const uint4v*)(actv_hi + ((size_t)b * HW + gy * 64 + gx) * ICSTRIDE
                            + icbase + part * 8);
    *(uint4v*)(lds_hi + part * PS + pos * 8) = vh;
  }
  __syncthreads();

  #pragma unroll
  for (int icC = 0; icC < 4; ++icC) {
    #pragma unroll
    for (int dx = 0; dx < 3; ++dx) {
      short8v Ah[3][2];
      #pragma unroll
      for (int dy = 0; dy < 3; ++dy) {
        #pragma unroll
        for (int a = 0; a < 2; ++a) {
          size_t wi = ((((size_t)(dy * 3 + dx) * OCT16) + (zl * 8 + wv * 2 + a)) * ICC + icC) * 64 + lane;
          Ah[dy][a] = *(const short8v*)(wph + wi * 8);
        }
      }
      #pragma unroll
      for (int c0i = 0; c0i < 4; ++c0i) {
        #pragma unroll
        for (int sr = 0; sr < 4; ++sr) {
          int pix = sr * 66 + c0i * 16 + dx + l15;
          int addr = (icC * 4 + lg) * PS + pix * 8;
          short8v Bh = *(const short8v*)(lds_hi + addr);
          #pragma unroll
          for (int dy = 0; dy < 3; ++dy) {
            int pt = sr - dy;
            if (pt < 0 || pt > 1) continue;  // compile-time
            int ptt = pt * 4 + c0i;
            acc[0][ptt] = __builtin_amdgcn_mfma_f32_16x16x32_bf16(Ah[dy][0], Bh, acc[0][ptt], 0, 0, 0);
            acc[1][ptt] = __builtin_amdgcn_mfma_f32_16x16x32_bf16(Ah[dy][1], Bh, acc[1][ptt], 0, 0, 0);
          }
        }
      }
    }
  }

  #pragma unroll
  for (int a = 0; a < 2; ++a) {
    int base = zl * 128 + wv * 32 + a * 16 + lg * 4;
    int cA = base >> 1;
    int cB = cA + 1;
    float muA = mu[b * C + cA], rsA = rstd[b * C + cA];
    float gbA = gbias[cA], bbA = bbias[cA], sA = sscale[b * C + cA];
    float muB = mu[b * C + cB], rsB = rstd[b * C + cB];
    float gbB = gbias[cB], bbB = bbias[cB], sB = sscale[b * C + cB];
    #pragma unroll
    for (int pt = 0; pt < 8; ++pt) {
      int px = (r0 + (pt >> 2)) * 64 + (pt & 3) * 16 + l15;
      float nvA = (pre[a][0][pt] - muA) * rsA;
      float vA = nvA * (1.f + acc[a][pt][0] + gbA) + acc[a][pt][1] + bbA;
      if (lrelu) vA = (vA >= 0.f) ? vA : 0.2f * vA;
      vA *= sA;
      float nvB = (pre[a][1][pt] - muB) * rsB;
      float vB = nvB * (1.f + acc[a][pt][2] + gbB) + acc[a][pt][3] + bbB;
      if (lrelu) vB = (vB >= 0.f) ? vB : 0.2f * vB;
      vB *= sB;
      short hA = f2bf(vA), hB = f2bf(vB);
      size_t o = ((size_t)b * HW + px) * C + cA;
      *(unsigned*)(out_hi + o) =
          (unsigned)(unsigned short)hA | ((unsigned)(unsigned short)hB << 16);
    }
  }
}

// ---------------- gb_n1: single staging round (128 ic), weight-hi only, hi-only output ----------------
__global__ __launch_bounds__(256) void conv_gb1_kernel(
    const short* __restrict__ actv_hi, const short* __restrict__ pg1h,
    const float* __restrict__ src, const float* __restrict__ mu,
    const float* __restrict__ rstd,
    const float* __restrict__ gbias, const float* __restrict__ bbias,
    const float* __restrict__ sscale,
    short* __restrict__ out_hi) {
  const int b = blockIdx.x;
  const int r0 = blockIdx.y * 2;
  const int zl = blockIdx.z;
  const int OCT16 = 32, C = 256, ICC = 4, ICSTRIDE = 384, icbase = 128;

  const int t = threadIdx.x;
  const int wv = t >> 6;
  const int lane = t & 63;
  const int l15 = lane & 15, lg = lane >> 4;
  const int PS = 2128;

  __shared__ __align__(16) short lds_hi[16 * 2128];

  float pre[2][2][8];
  #pragma unroll
  for (int a = 0; a < 2; ++a) {
    int base = zl * 128 + wv * 32 + a * 16 + lg * 4;
    int cA = base >> 1, cB = cA + 1;
    const float* srcA = src + ((size_t)b * C + cA) * HW;
    const float* srcB = src + ((size_t)b * C + cB) * HW;
    #pragma unroll
    for (int pt = 0; pt < 8; ++pt) {
      int px = (r0 + (pt >> 2)) * 64 + (pt & 3) * 16 + l15;
      pre[a][0][pt] = srcA[px];
      pre[a][1][pt] = srcB[px];
    }
  }

  float4v acc[2][8];
  #pragma unroll
  for (int a = 0; a < 2; ++a)
    #pragma unroll
    for (int pt = 0; pt < 8; ++pt) acc[a][pt] = (float4v){0.f, 0.f, 0.f, 0.f};

  for (int idx = t; idx < 264 * 16; idx += 256) {
    int pos = idx >> 4, part = idx & 15;
    int srow = pos / 66;
    int scol = pos - srow * 66;
    int gy = r0 + srow - 1, gx = scol - 1;
    uint4v vh = {0u, 0u, 0u, 0u};
    if (gy >= 0 && gy < 64 && gx >= 0 && gx < 64)
      vh = *(const uint4v*)(actv_hi + ((size_t)b * HW + gy * 64 + gx) * ICSTRIDE
                            + icbase + part * 8);
    *(uint4v*)(lds_hi + part * PS + pos * 8) = vh;
  }
  __syncthreads();

  #pragma unroll
  for (int icC = 0; icC < 4; ++icC) {
    #pragma unroll
    for (int dx = 0; dx < 3; ++dx) {
      short8v Ah[3][2];
      #pragma unroll
      for (int dy = 0; dy < 3; ++dy) {
        #pragma unroll
        for (int a = 0; a < 2; ++a) {
          size_t wi = ((((size_t)(dy * 3 + dx) * OCT16) + (zl * 8 + wv * 2 + a)) * ICC + icC) * 64 + lane;
          Ah[dy][a] = *(const short8v*)(pg1h + wi * 8);
        }
      }
      #pragma unroll
      for (int c0i = 0; c0i < 4; ++c0i) {
        #pragma unroll
        for (int sr = 0; sr < 4; ++sr) {
          int pix = sr * 66 + c0i * 16 + dx + l15;
          int addr = (icC * 4 + lg) * PS + pix * 8;
          short8v Bh = *(const short8v*)(lds_hi + addr);
          #pragma unroll
          for (int dy = 0; dy < 3; ++dy) {
            int pt = sr - dy;
            if (pt < 0 || pt > 1) continue;  // compile-time
            int ptt = pt * 4 + c0i;
            acc[0][ptt] = __builtin_amdgcn_mfma_f32_16x16x32_bf16(Ah[dy][0], Bh, acc[0][ptt], 0, 0, 0);
            acc[1][ptt] = __builtin_amdgcn_mfma_f32_16x16x32_bf16(Ah[dy][1], Bh, acc[1][ptt], 0, 0, 0);
          }
        }
      }
    }
  }

  #pragma unroll
  for (int a = 0; a < 2; ++a) {
    int base = zl * 128 + wv * 32 + a * 16 + lg * 4;
    int cA = base >> 1;
    int cB = cA + 1;
    float muA = mu[b * C + cA], rsA = rstd[b * C + cA];
    float gbA = gbias[cA], bbA = bbias[cA], sA = sscale[b * C + cA];
    float muB = mu[b * C + cB], rsB = rstd[b * C + cB];
    float gbB = gbias[cB], bbB = bbias[cB], sB = sscale[b * C + cB];
    #pragma unroll
    for (int pt = 0; pt < 8; ++pt) {
      int px = (r0 + (pt >> 2)) * 64 + (pt & 3) * 16 + l15;
      float nvA = (pre[a][0][pt] - muA) * rsA;
      float vA = nvA * (1.f + acc[a][pt][0] + gbA) + acc[a][pt][1] + bbA;
      vA = (vA >= 0.f) ? vA : 0.2f * vA;
      vA *= sA;
      float nvB = (pre[a][1][pt] - muB) * rsB;
      float vB = nvB * (1.f + acc[a][pt][2] + gbB) + acc[a][pt][3] + bbB;
      vB = (vB >= 0.f) ? vB : 0.2f * vB;
      vB *= sB;
      short hA = f2bf(vA), hB = f2bf(vB);
      size_t o = ((size_t)b * HW + px) * C + cA;
      *(unsigned*)(out_hi + o) =
          (unsigned)(unsigned short)hA | ((unsigned)(unsigned short)hB << 16);
    }
  }
}

// ---------------- dual modconv, VGPR-capped: z<2 = modconv0 (3x3, input-hi, weight-hi, 64-ic rounds),
// z>=2 = 1x1 (input-hi, weight hi+lo). ----------------
__global__ __launch_bounds__(256, 4) void conv_mc_dual_kernel(
    const short* __restrict__ sp_hi,
    const short* __restrict__ p0h,
    const float* __restrict__ d0, float* __restrict__ bufH,
    const short* __restrict__ sp2_hi,
    const short* __restrict__ psh, const short* __restrict__ psl,
    const float* __restrict__ dss, float* __restrict__ outD) {
  const int b = blockIdx.x;
  const int r0 = blockIdx.y * 2;
  const int zz = blockIdx.z;
  const bool is1x1 = zz >= 2;
  const int zl = zz & 1;
  const int OCT16 = 16, ICC = 16, ICSTRIDE = 512;

  const int t = threadIdx.x;
  const int wv = t >> 6;
  const int lane = t & 63;
  const int l15 = lane & 15, lg = lane >> 4;
  const int PS = 2128;

  __shared__ __align__(16) short lds[8 * 2128];

  float4v acc[2][8];
  #pragma unroll
  for (int a = 0; a < 2; ++a)
    #pragma unroll
    for (int pt = 0; pt < 8; ++pt) acc[a][pt] = (float4v){0.f, 0.f, 0.f, 0.f};

  if (!is1x1) {
    for (int rnd = 0; rnd < 8; ++rnd) {
      __syncthreads();
      for (int idx = t; idx < 264 * 8; idx += 256) {
        int pos = idx >> 3, part = idx & 7;
        int srow = pos / 66;
        int scol = pos - srow * 66;
        int gy = r0 + srow - 1, gx = scol - 1;
        uint4v vh = {0u, 0u, 0u, 0u};
        if (gy >= 0 && gy < 64 && gx >= 0 && gx < 64)
          vh = *(const uint4v*)(sp_hi + ((size_t)b * HW + gy * 64 + gx) * ICSTRIDE
                                + rnd * 64 + part * 8);
        *(uint4v*)(lds + part * PS + pos * 8) = vh;
      }
      __syncthreads();

      #pragma unroll
      for (int sub = 0; sub < 2; ++sub) {
        const int icC = rnd * 2 + sub;
        #pragma unroll
        for (int dx = 0; dx < 3; ++dx) {
          short8v Ah[3][2];
          #pragma unroll
          for (int dy = 0; dy < 3; ++dy) {
            #pragma unroll
            for (int a = 0; a < 2; ++a) {
              size_t wi = ((((size_t)(dy * 3 + dx) * OCT16) + (zl * 8 + wv * 2 + a)) * ICC + icC) * 64 + lane;
              Ah[dy][a] = *(const short8v*)(p0h + wi * 8);
            }
          }
          #pragma unroll
          for (int c0i = 0; c0i < 4; ++c0i) {
            #pragma unroll
            for (int sr = 0; sr < 4; ++sr) {
              int pix = sr * 66 + c0i * 16 + dx + l15;
              int addr = (sub * 4 + lg) * PS + pix * 8;
              short8v Bh = *(const short8v*)(lds + addr);
              #pragma unroll
              for (int dy = 0; dy < 3; ++dy) {
                int pt = sr - dy;
                if (pt < 0 || pt > 1) continue;  // compile-time
                int ptt = pt * 4 + c0i;
                acc[0][ptt] = __builtin_amdgcn_mfma_f32_16x16x32_bf16(Ah[dy][0], Bh, acc[0][ptt], 0, 0, 0);
                acc[1][ptt] = __builtin_amdgcn_mfma_f32_16x16x32_bf16(Ah[dy][1], Bh, acc[1][ptt], 0, 0, 0);
              }
            }
          }
        }
      }
    }
  } else {
    for (int icC = 0; icC < ICC; ++icC) {
      __syncthreads();
      const int ic0 = icC * 32;
      for (int idx = t; idx < 132 * 4; idx += 256) {
        int pos = idx >> 2, part = idx & 3;
        int srow = pos / 66;
        int scol = pos - srow * 66;
        int gy = r0 + srow, gx = scol - 1;
        uint4v vh = {0u, 0u, 0u, 0u};
        if (gx >= 0 && gx < 64)
          vh = *(const uint4v*)(sp2_hi + ((size_t)b * HW + gy * 64 + gx) * ICSTRIDE + ic0 + part * 8);
        *(uint4v*)(lds + part * PS + pos * 8) = vh;
      }
      __syncthreads();

      short8v Ah[2], Al[2];
      #pragma unroll
      for (int a = 0; a < 2; ++a) {
        size_t wi = (((size_t)(zl * 8 + wv * 2 + a)) * ICC + icC) * 64 + lane;
        Ah[a] = *(const short8v*)(psh + wi * 8);
        Al[a] = *(const short8v*)(psl + wi * 8);
      }
      #pragma unroll
      for (int pt = 0; pt < 8; ++pt) {
        int pix = (pt >> 2) * 66 + (pt & 3) * 16 + 1 + l15;
        short8v Bh = *(const short8v*)(lds + lg * PS + pix * 8);
        acc[0][pt] = __builtin_amdgcn_mfma_f32_16x16x32_bf16(Ah[0], Bh, acc[0][pt], 0, 0, 0);
        acc[1][pt] = __builtin_amdgcn_mfma_f32_16x16x32_bf16(Ah[1], Bh, acc[1][pt], 0, 0, 0);
        acc[0][pt] = __builtin_amdgcn_mfma_f32_16x16x32_bf16(Al[0], Bh, acc[0][pt], 0, 0, 0);
        acc[1][pt] = __builtin_amdgcn_mfma_f32_16x16x32_bf16(Al[1], Bh, acc[1][pt], 0, 0, 0);
      }
    }
  }

  const float* dscale = is1x1 ? dss : d0;
  float* outF = is1x1 ? outD : bufH;
  #pragma unroll
  for (int a = 0; a < 2; ++a) {
    int ocbase = zl * 128 + wv * 32 + a * 16 + lg * 4;
    float ds[4];
    #pragma unroll
    for (int r = 0; r < 4; ++r) ds[r] = dscale[b * 256 + ocbase + r];
    #pragma unroll
    for (int pt = 0; pt < 8; ++pt) {
      int px = (r0 + (pt >> 2)) * 64 + (pt & 3) * 16 + l15;
      #pragma unroll
      for (int r = 0; r < 4; ++r) {
        size_t oi = ((size_t)b * 256 + ocbase + r) * HW + px;
        outF[oi] = acc[a][pt][r] * ds[r];
      }
    }
  }
}

extern "C" void kernel_launch(void* const* d_in, const int* in_sizes, int n_in,
                              void* d_out, int out_size, void* d_ws, size_t ws_size,
                              hipStream_t stream) {
  const float* x     = (const float*)d_in[0];
  const float* seg   = (const float*)d_in[1];
  const float* style = (const float*)d_in[2];
  const float* n0_sw = (const float*)d_in[3];
  const float* n0_sb = (const float*)d_in[4];
  const float* n0_gw = (const float*)d_in[5];
  const float* n0_gb = (const float*)d_in[6];
  const float* n0_bw = (const float*)d_in[7];
  const float* n0_bb = (const float*)d_in[8];
  const float* n1_sw = (const float*)d_in[9];
  const float* n1_sb = (const float*)d_in[10];
  const float* n1_gw = (const float*)d_in[11];
  const float* n1_gb = (const float*)d_in[12];
  const float* n1_bw = (const float*)d_in[13];
  const float* n1_bb = (const float*)d_in[14];
  const float* ns_sw = (const float*)d_in[15];
  const float* ns_sb = (const float*)d_in[16];
  const float* ns_gw = (const float*)d_in[17];
  const float* ns_gb = (const float*)d_in[18];
  const float* ns_bw = (const float*)d_in[19];
  const float* ns_bb = (const float*)d_in[20];
  const float* w0  = (const float*)d_in[21];
  const float* m0w = (const float*)d_in[22];
  const float* m0b = (const float*)d_in[23];
  const float* w1  = (const float*)d_in[24];
  const float* m1w = (const float*)d_in[25];
  const float* m1b = (const float*)d_in[26];
  const float* wss = (const float*)d_in[27];
  const float* msw = (const float*)d_in[28];
  const float* msb = (const float*)d_in[29];
  float* out = (float*)d_out;

  char* p = (char*)d_ws;
  auto allocF = [&](size_t n) { float* r = (float*)p; p += n * 4; return r; };
  auto allocS = [&](size_t n) { short* r = (short*)p; p += n * 2; return r; };

  float* mu_x   = allocF(4096);
  float* rstd_x = allocF(4096);
  float* mu_h   = allocF(2048);
  float* rstd_h = allocF(2048);
  float* s0  = allocF(4096);
  float* s1  = allocF(2048);
  float* ss  = allocF(4096);
  float* d0  = allocF(2048);
  float* d1  = allocF(2048);
  float* dss = allocF(2048);
  float* wsq0 = allocF(256 * 512);
  float* wsq1 = allocF(256 * 256);
  float* wsqs = allocF(256 * 512);
  float* sb_cat = allocF(384);
  float* bufH = allocF((size_t)BN * 256 * HW);
  short* actv_hi = allocS((size_t)BN * HW * 384);
  short* segT = allocS((size_t)BN * HW * 64);
  short* sp_hi = allocS((size_t)BN * HW * 512);
  short* sp2_hi = allocS((size_t)BN * HW * 512);
  short* p0h = allocS((size_t)256 * 512 * 9);
  short* p1h = allocS((size_t)256 * 256 * 9);
  short* p1l = allocS((size_t)256 * 256 * 9);
  short* psh = allocS((size_t)256 * 512);
  short* psl = allocS((size_t)256 * 512);
  short* pswh = allocS((size_t)9 * 24 * 2 * 64 * 8);
  short* pswl = allocS((size_t)9 * 24 * 2 * 64 * 8);
  short* pgsh = allocS((size_t)1024 * 128 * 9);
  short* pg0h = allocS((size_t)1024 * 128 * 9);
  short* pg1h = allocS((size_t)512 * 128 * 9);

  float cs0 = 1.0f / sqrtf(512.f * 9.f);
  float cs1 = 1.0f / sqrtf(256.f * 9.f);
  float css = 1.0f / sqrtf(512.f);

  // -------- small precompute (merged) --------
  stats_kernel<<<BN * 512, 256, 0, stream>>>(x, mu_x, rstd_x);
  modscale_all_kernel<<<40, 256, 0, stream>>>(style, m0w, m0b, m1w, m1b, msw, msb,
                                              s0, s1, ss);
  wsq_all_kernel<<<1280, 256, 0, stream>>>(w0, w1, wss, wsq0, wsq1, wsqs);
  demod_all_kernel<<<24, 256, 0, stream>>>(wsq0, s0, d0, wsq1, s1, d1, wsqs, ss, dss,
                                           cs0, cs1, css);

  // -------- seg transpose + bias concat --------
  seg_pack_kernel<<<(BN * HW) / 256, 256, 0, stream>>>(seg, segT);
  hipMemcpyAsync(sb_cat,       n0_sb, 128 * 4, hipMemcpyDeviceToDevice, stream);
  hipMemcpyAsync(sb_cat + 128, n1_sb, 128 * 4, hipMemcpyDeviceToDevice, stream);
  hipMemcpyAsync(sb_cat + 256, ns_sb, 128 * 4, hipMemcpyDeviceToDevice, stream);

  // -------- weight packing (merged) --------
  pack_sw_kernel<<<108, 256, 0, stream>>>(n0_sw, n1_sw, ns_sw, pswh, pswl);
  pack_w_all_kernel<<<2368, 256, 0, stream>>>(
      w0, w1, wss, ns_gw, ns_bw, n0_gw, n0_bw, n1_gw, n1_bw,
      p0h, p1h, p1l, psh, psl, pgsh, pg0h, pg1h);

  // -------- all 3 seg convs via MFMA (MODE=2) --------
  conv_mfma_kernel<64, 64, 1, 2, 0, 0, 1><<<dim3(BN, 32, 3), 256, 0, stream>>>(
      segT, nullptr, pswh, pswl, nullptr, nullptr, nullptr, nullptr, sb_cat,
      nullptr, nullptr, nullptr, actv_hi, nullptr, 24, 384, 0, 0);

  // -------- dual GB (hi-only out, single staging round): ns -> sp2_hi, n0 -> sp_hi --------
  conv_gb_dual_kernel<<<dim3(BN, 32, 16), 256, 0, stream>>>(
      actv_hi, pgsh, pg0h, x, mu_x, rstd_x,
      ns_gb, ns_bb, ss, n0_gb, n0_bb, s0, sp2_hi, sp_hi);

  // -------- dual modconv (VGPR<=128): modconv0 (hi*hi) + 1x1 (hi in, hi+lo w) --------
  conv_mc_dual_kernel<<<dim3(BN, 32, 4), 256, 0, stream>>>(
      sp_hi, p0h, d0, bufH,
      sp2_hi, psh, psl, dss, out);

  // -------- spade_n1 over bufH (hi-only out) -> modconv1 (input-hi, weight hi+lo, += into d_out) --------
  stats_kernel<<<BN * 256, 256, 0, stream>>>(bufH, mu_h, rstd_h);
  conv_gb1_kernel<<<dim3(BN, 32, 4), 256, 0, stream>>>(
      actv_hi, pg1h, bufH, mu_h, rstd_h, n1_gb, n1_bb, s1, sp_hi);
  conv_mfma_kernel<256, 256, 1, 0, 1, 0, 1><<<dim3(BN, 32, 2), 256, 0, stream>>>(
      sp_hi, nullptr, p1h, p1l, d1, nullptr, nullptr, nullptr, nullptr, nullptr,
      nullptr, out, nullptr, nullptr, 16, 0, 0, 0);
}